// Round 1
// baseline (2298.742 us; speedup 1.0000x reference)
//
#include <hip/hip_runtime.h>
#include <hip/hip_bf16.h>
#include <math.h>

// Problem dims
#define B_   256
#define N_   196
#define IN_  1024
#define D_   256
#define H_   8
#define HD_  32
#define NC_  1000
#define S0_  10
#define S1_  20
#define ROWS (B_*N_)      // 50176
#define CAT  (IN_+D_)     // 1280

// GEMM tiling
#define TM 64
#define TN 64
#define TKt 16

__device__ __forceinline__ float gelu_tanh(float x){
    // jax.nn.gelu default (approximate=True)
    float x3 = x*x*x;
    float inner = 0.7978845608028654f*(x + 0.044715f*x3);
    return 0.5f*x*(1.0f + tanhf(inner));
}

// C[M,N] = act(A[M,K] @ W[N,K]^T + bias[N]); all row-major; M%64==0, N%64==0, K%16==0
__global__ __launch_bounds__(256)
void gemm_f32(const float* __restrict__ A, const float* __restrict__ W,
              const float* __restrict__ bias, float* __restrict__ C,
              int M, int K, int Nn, int act)
{
    __shared__ __align__(16) float As[TKt][TM];
    __shared__ __align__(16) float Bs[TKt][TN];
    const int bm = blockIdx.x * TM;
    const int bn = blockIdx.y * TN;
    const int t  = threadIdx.x;
    const int lr = t >> 2;            // 0..63 load row
    const int lc = (t & 3) << 2;      // 0,4,8,12 load col
    const int tr = (t >> 4) << 2;     // 0..60 compute row base
    const int tc = (t & 15) << 2;     // 0..60 compute col base

    float acc[4][4];
    #pragma unroll
    for (int i=0;i<4;++i)
        #pragma unroll
        for (int j=0;j<4;++j) acc[i][j]=0.0f;

    const float* aptr = A + (size_t)(bm + lr)*K + lc;
    const float* wptr = W + (size_t)(bn + lr)*K + lc;

    for (int k0 = 0; k0 < K; k0 += TKt){
        float4 av = *(const float4*)(aptr + k0);
        float4 wv = *(const float4*)(wptr + k0);
        As[lc+0][lr]=av.x; As[lc+1][lr]=av.y; As[lc+2][lr]=av.z; As[lc+3][lr]=av.w;
        Bs[lc+0][lr]=wv.x; Bs[lc+1][lr]=wv.y; Bs[lc+2][lr]=wv.z; Bs[lc+3][lr]=wv.w;
        __syncthreads();
        #pragma unroll
        for (int kk=0; kk<TKt; ++kk){
            float4 a = *(const float4*)&As[kk][tr];
            float4 w = *(const float4*)&Bs[kk][tc];
            acc[0][0] += a.x*w.x; acc[0][1] += a.x*w.y; acc[0][2] += a.x*w.z; acc[0][3] += a.x*w.w;
            acc[1][0] += a.y*w.x; acc[1][1] += a.y*w.y; acc[1][2] += a.y*w.z; acc[1][3] += a.y*w.w;
            acc[2][0] += a.z*w.x; acc[2][1] += a.z*w.y; acc[2][2] += a.z*w.z; acc[2][3] += a.z*w.w;
            acc[3][0] += a.w*w.x; acc[3][1] += a.w*w.y; acc[3][2] += a.w*w.z; acc[3][3] += a.w*w.w;
        }
        __syncthreads();
    }
    #pragma unroll
    for (int i=0;i<4;++i){
        int row = bm + tr + i;
        float4 o;
        o.x = acc[i][0] + bias[bn+tc+0];
        o.y = acc[i][1] + bias[bn+tc+1];
        o.z = acc[i][2] + bias[bn+tc+2];
        o.w = acc[i][3] + bias[bn+tc+3];
        if (act){
            o.x = gelu_tanh(o.x); o.y = gelu_tanh(o.y);
            o.z = gelu_tanh(o.z); o.w = gelu_tanh(o.w);
        }
        *(float4*)(C + (size_t)row*Nn + bn + tc) = o;
    }
}

// fs = rowr * (concat(h,integ) @ Wfs^T - rowm * colsum(Wfs)) + bfs   (LN folded into epilogue)
__global__ __launch_bounds__(256)
void gemm_fs(const float* __restrict__ h, const float* __restrict__ integ,
             const float* __restrict__ W, const float* __restrict__ bias,
             const float* __restrict__ rowm, const float* __restrict__ rowr,
             const float* __restrict__ wsum, float* __restrict__ C)
{
    __shared__ __align__(16) float As[TKt][TM];
    __shared__ __align__(16) float Bs[TKt][TN];
    const int bm = blockIdx.x * TM;
    const int bn = blockIdx.y * TN;
    const int t  = threadIdx.x;
    const int lr = t >> 2;
    const int lc = (t & 3) << 2;
    const int tr = (t >> 4) << 2;
    const int tc = (t & 15) << 2;

    float acc[4][4];
    #pragma unroll
    for (int i=0;i<4;++i)
        #pragma unroll
        for (int j=0;j<4;++j) acc[i][j]=0.0f;

    const int arow = bm + lr;
    const float* wptr = W + (size_t)(bn + lr)*CAT + lc;

    for (int k0 = 0; k0 < CAT; k0 += TKt){
        int c = k0 + lc;
        float4 av = (c < IN_) ? *(const float4*)(h + (size_t)arow*IN_ + c)
                              : *(const float4*)(integ + (size_t)arow*D_ + (c - IN_));
        float4 wv = *(const float4*)(wptr + k0);
        As[lc+0][lr]=av.x; As[lc+1][lr]=av.y; As[lc+2][lr]=av.z; As[lc+3][lr]=av.w;
        Bs[lc+0][lr]=wv.x; Bs[lc+1][lr]=wv.y; Bs[lc+2][lr]=wv.z; Bs[lc+3][lr]=wv.w;
        __syncthreads();
        #pragma unroll
        for (int kk=0; kk<TKt; ++kk){
            float4 a = *(const float4*)&As[kk][tr];
            float4 w = *(const float4*)&Bs[kk][tc];
            acc[0][0] += a.x*w.x; acc[0][1] += a.x*w.y; acc[0][2] += a.x*w.z; acc[0][3] += a.x*w.w;
            acc[1][0] += a.y*w.x; acc[1][1] += a.y*w.y; acc[1][2] += a.y*w.z; acc[1][3] += a.y*w.w;
            acc[2][0] += a.z*w.x; acc[2][1] += a.z*w.y; acc[2][2] += a.z*w.z; acc[2][3] += a.z*w.w;
            acc[3][0] += a.w*w.x; acc[3][1] += a.w*w.y; acc[3][2] += a.w*w.z; acc[3][3] += a.w*w.w;
        }
        __syncthreads();
    }
    #pragma unroll
    for (int i=0;i<4;++i){
        int row = bm + tr + i;
        float mr = rowm[row], rr = rowr[row];
        float4 o;
        o.x = rr*(acc[i][0] - mr*wsum[bn+tc+0]) + bias[bn+tc+0];
        o.y = rr*(acc[i][1] - mr*wsum[bn+tc+1]) + bias[bn+tc+1];
        o.z = rr*(acc[i][2] - mr*wsum[bn+tc+2]) + bias[bn+tc+2];
        o.w = rr*(acc[i][3] - mr*wsum[bn+tc+3]) + bias[bn+tc+3];
        *(float4*)(C + (size_t)row*D_ + bn + tc) = o;
    }
}

// per-row mean & rstd of concat(h,integ) (1280 elems per row); one block per row
__global__ __launch_bounds__(256)
void rowstats_kernel(const float* __restrict__ h, const float* __restrict__ integ,
                     float* __restrict__ rowm, float* __restrict__ rowr)
{
    const int r = blockIdx.x;
    const int t = threadIdx.x;
    float s = 0.f, s2 = 0.f;
    for (int c = t; c < CAT; c += 256){
        float x = (c < IN_) ? h[(size_t)r*IN_ + c] : integ[(size_t)r*D_ + c - IN_];
        s += x; s2 += x*x;
    }
    #pragma unroll
    for (int off=32; off>0; off>>=1){ s += __shfl_down(s, off); s2 += __shfl_down(s2, off); }
    __shared__ float ss[4], ss2[4];
    int w = t >> 6;
    if ((t & 63) == 0){ ss[w]=s; ss2[w]=s2; }
    __syncthreads();
    if (t == 0){
        float S = ss[0]+ss[1]+ss[2]+ss[3];
        float S2 = ss2[0]+ss2[1]+ss2[2]+ss2[3];
        float m = S * (1.0f/CAT);
        float v = S2 * (1.0f/CAT) - m*m;
        rowm[r] = m;
        rowr[r] = rsqrtf(v + 1e-5f);
    }
}

__global__ __launch_bounds__(256)
void wsum_kernel(const float* __restrict__ Wfs, float* __restrict__ wsum)
{
    int d = threadIdx.x;
    const float* w = Wfs + (size_t)d*CAT;
    float s = 0.f;
    for (int c=0;c<CAT;++c) s += w[c];
    wsum[d] = s;
}

// attention: one block per (b, h); q/k/v layout [B*N, 256] with head at col h*32
__global__ __launch_bounds__(256)
void attn_kernel(const float* __restrict__ qb, const float* __restrict__ kb,
                 const float* __restrict__ vb, float* __restrict__ ao)
{
    const int b = blockIdx.x, hh = blockIdx.y;
    __shared__ __align__(16) float Ks[N_][HD_];
    __shared__ __align__(16) float Vs[N_][HD_];
    const int t = threadIdx.x;
    const size_t base = (size_t)b*N_*D_ + hh*HD_;
    for (int idx = t; idx < N_*8; idx += 256){
        int j = idx >> 3, d4 = (idx & 7) << 2;
        *(float4*)&Ks[j][d4] = *(const float4*)(kb + base + (size_t)j*D_ + d4);
        *(float4*)&Vs[j][d4] = *(const float4*)(vb + base + (size_t)j*D_ + d4);
    }
    __syncthreads();
    if (t < N_){
        float q[HD_];
        const float* qp = qb + base + (size_t)t*D_;
        const float scale = 0.17677669529663687f; // 32^-0.5
        #pragma unroll
        for (int d4=0; d4<HD_; d4+=4){
            float4 qv = *(const float4*)(qp + d4);
            q[d4]=qv.x*scale; q[d4+1]=qv.y*scale; q[d4+2]=qv.z*scale; q[d4+3]=qv.w*scale;
        }
        float m = -3.4e38f;
        for (int j=0;j<N_;++j){
            float s = 0.f;
            #pragma unroll
            for (int d=0; d<HD_; ++d) s += q[d]*Ks[j][d];
            m = fmaxf(m, s);
        }
        float acc[HD_];
        #pragma unroll
        for (int d=0; d<HD_; ++d) acc[d]=0.f;
        float sum = 0.f;
        for (int j=0;j<N_;++j){
            float s = 0.f;
            #pragma unroll
            for (int d=0; d<HD_; ++d) s += q[d]*Ks[j][d];
            float p = expf(s - m);
            sum += p;
            #pragma unroll
            for (int d=0; d<HD_; ++d) acc[d] += p*Vs[j][d];
        }
        float inv = 1.0f/sum;
        float* op = ao + base + (size_t)t*D_;
        #pragma unroll
        for (int d4=0; d4<HD_; d4+=4){
            float4 ov = { acc[d4]*inv, acc[d4+1]*inv, acc[d4+2]*inv, acc[d4+3]*inv };
            *(float4*)(op + d4) = ov;
        }
    }
}

// mean over tokens: dst[b,d] = mean_n src[b,n,d]
__global__ __launch_bounds__(256)
void mean_tokens(const float* __restrict__ src, float* __restrict__ dst)
{
    int b = blockIdx.x, d = threadIdx.x;
    const float* p = src + (size_t)b*N_*D_ + d;
    float s = 0.f;
    for (int n=0;n<N_;++n) s += p[(size_t)n*D_];
    dst[b*D_ + d] = s * (1.0f/N_);
}

// parent logits: LN(pooled @ Wpc^T + bpc) and argmax routing (pre-LN argmax == post-LN-softmax argmax)
__global__ __launch_bounds__(256)
void parent_kernel(const float* __restrict__ pooled, const float* __restrict__ Wpc,
                   const float* __restrict__ bpc, float* __restrict__ out, int* __restrict__ yhat)
{
    const int b = blockIdx.x, t = threadIdx.x;
    __shared__ __align__(16) float pl[D_];
    __shared__ float lg[NC_];
    pl[t] = pooled[b*D_ + t];
    __syncthreads();
    for (int c = t; c < NC_; c += 256){
        const float* w = Wpc + (size_t)c*D_;
        float s = 0.f;
        #pragma unroll 8
        for (int j=0;j<D_;++j) s += pl[j]*w[j];
        lg[c] = s + bpc[c];
    }
    __syncthreads();
    float s=0.f, s2=0.f, bmv=-3.4e38f; int bidx=0;
    for (int c=t;c<NC_;c+=256){
        float x = lg[c]; s += x; s2 += x*x;
        if (x > bmv){ bmv=x; bidx=c; }
    }
    #pragma unroll
    for (int off=32; off>0; off>>=1){
        s  += __shfl_down(s, off);
        s2 += __shfl_down(s2, off);
        float ov = __shfl_down(bmv, off); int oi = __shfl_down(bidx, off);
        if (ov > bmv || (ov == bmv && oi < bidx)){ bmv=ov; bidx=oi; }
    }
    __shared__ float rs[4], rs2[4], rmv[4]; __shared__ int ri[4];
    __shared__ float fm, fr; __shared__ int fi_unused;
    int w = t >> 6;
    if ((t & 63) == 0){ rs[w]=s; rs2[w]=s2; rmv[w]=bmv; ri[w]=bidx; }
    __syncthreads();
    if (t == 0){
        float S=0.f, S2=0.f, mv=-3.4e38f; int mi=0;
        for (int i=0;i<4;++i){
            S += rs[i]; S2 += rs2[i];
            if (rmv[i] > mv || (rmv[i] == mv && ri[i] < mi)){ mv=rmv[i]; mi=ri[i]; }
        }
        float mean = S*(1.0f/NC_);
        float var  = S2*(1.0f/NC_) - mean*mean;
        fm = mean; fr = rsqrtf(var + 1e-5f);
        yhat[b] = mi;
    }
    __syncthreads();
    for (int c=t;c<NC_;c+=256) out[(size_t)b*NC_ + c] = (lg[c]-fm)*fr;
}

// routed child classifiers + LN; one 64-thread block per sample
__global__ __launch_bounds__(64)
void child_kernel(const float* __restrict__ sp, const int* __restrict__ yhat,
                  const float* __restrict__ Wc0, const float* __restrict__ bc0,
                  const float* __restrict__ Wc1, const float* __restrict__ bc1,
                  float* __restrict__ out_c0, float* __restrict__ out_c1)
{
    const int b = blockIdx.x, t = threadIdx.x;
    __shared__ float spl[D_];
    for (int i=t;i<D_;i+=64) spl[i] = sp[b*D_ + i];
    __syncthreads();
    const int y = yhat[b];
    __shared__ float c0v[S0_], c1v[S1_];
    if (t < S0_){
        const float* w = Wc0 + (size_t)y*D_*S0_ + t;
        float s = 0.f;
        for (int d=0;d<D_;++d) s += spl[d]*w[(size_t)d*S0_];
        c0v[t] = s + bc0[y*S0_ + t];
    } else if (t < S0_+S1_){
        int k = t - S0_;
        const float* w = Wc1 + (size_t)y*D_*S1_ + k;
        float s = 0.f;
        for (int d=0;d<D_;++d) s += spl[d]*w[(size_t)d*S1_];
        c1v[k] = s + bc1[y*S1_ + k];
    }
    __syncthreads();
    __shared__ float st[4];
    if (t == 0){
        float m=0.f; for (int i=0;i<S0_;++i) m += c0v[i]; m *= (1.0f/S0_);
        float v=0.f; for (int i=0;i<S0_;++i){ float d=c0v[i]-m; v += d*d; } v *= (1.0f/S0_);
        st[0]=m; st[1]=rsqrtf(v+1e-5f);
        m=0.f; for (int i=0;i<S1_;++i) m += c1v[i]; m *= (1.0f/S1_);
        v=0.f; for (int i=0;i<S1_;++i){ float d=c1v[i]-m; v += d*d; } v *= (1.0f/S1_);
        st[2]=m; st[3]=rsqrtf(v+1e-5f);
    }
    __syncthreads();
    if (t < S0_) out_c0[b*S0_ + t] = (c0v[t]-st[0])*st[1];
    else if (t < S0_+S1_) out_c1[b*S1_ + (t-S0_)] = (c1v[t-S0_]-st[2])*st[3];
}

extern "C" void kernel_launch(void* const* d_in, const int* in_sizes, int n_in,
                              void* d_out, int out_size, void* d_ws, size_t ws_size,
                              hipStream_t stream)
{
    const float* h   = (const float*)d_in[0];
    const float* Wp  = (const float*)d_in[1];
    const float* bp  = (const float*)d_in[2];
    const float* Wsub= (const float*)d_in[3];
    const float* bs  = (const float*)d_in[4];
    const float* Wq  = (const float*)d_in[5];
    const float* bq  = (const float*)d_in[6];
    const float* Wk  = (const float*)d_in[7];
    const float* bk  = (const float*)d_in[8];
    const float* Wv  = (const float*)d_in[9];
    const float* bv  = (const float*)d_in[10];
    const float* Wo  = (const float*)d_in[11];
    const float* bo  = (const float*)d_in[12];
    const float* Wfs = (const float*)d_in[13];
    const float* bfs = (const float*)d_in[14];
    const float* Wpc = (const float*)d_in[15];
    const float* bpc = (const float*)d_in[16];
    const float* Wc0 = (const float*)d_in[17];
    const float* bc0 = (const float*)d_in[18];
    const float* Wc1 = (const float*)d_in[19];
    const float* bc1 = (const float*)d_in[20];

    float* out = (float*)d_out;
    float* out_pl = out;                         // [256,1000]
    float* out_c0 = out + 256000;                // [256,10]
    float* out_c1 = out + 258560;                // [256,20]
    float* out_fs = out + 263680;                // [256,196,256]
    float* out_se = out + 13108736;              // [256,196,256]

    float* ws = (float*)d_ws;
    const size_t RB = (size_t)ROWS * D_;         // 12845056
    float* buf0 = ws;            // pe -> later ao
    float* buf1 = ws + RB;       // q  -> later integ
    float* buf2 = ws + 2*RB;     // k
    float* buf3 = ws + 3*RB;     // v
    float* rowm = ws + 4*RB;
    float* rowr = rowm + ROWS;
    float* wsmb = rowr + ROWS;
    float* pooled = wsmb + D_;
    float* sp   = pooled + (size_t)B_*D_;
    int*   yhat = (int*)(sp + (size_t)B_*D_);

    dim3 g1(ROWS/TM, D_/TN);

    // projections + gelu
    gemm_f32<<<g1, 256, 0, stream>>>(h, Wp,   bp, buf0,   ROWS, IN_, D_, 1);   // pe
    gemm_f32<<<g1, 256, 0, stream>>>(h, Wsub, bs, out_se, ROWS, IN_, D_, 1);   // se (output 4)
    // q,k,v
    gemm_f32<<<g1, 256, 0, stream>>>(buf0,   Wq, bq, buf1, ROWS, D_, D_, 0);
    gemm_f32<<<g1, 256, 0, stream>>>(out_se, Wk, bk, buf2, ROWS, D_, D_, 0);
    gemm_f32<<<g1, 256, 0, stream>>>(out_se, Wv, bv, buf3, ROWS, D_, D_, 0);
    // attention -> ao (reuse buf0)
    attn_kernel<<<dim3(B_, H_), 256, 0, stream>>>(buf1, buf2, buf3, buf0);
    // integ = ao @ Wo^T + bo (reuse buf1)
    gemm_f32<<<g1, 256, 0, stream>>>(buf0, Wo, bo, buf1, ROWS, D_, D_, 0);
    // LN stats of concat(h, integ), colsum(Wfs), then fused LN+GEMM -> fs (output 3)
    rowstats_kernel<<<ROWS, 256, 0, stream>>>(h, buf1, rowm, rowr);
    wsum_kernel<<<1, 256, 0, stream>>>(Wfs, wsmb);
    gemm_fs<<<g1, 256, 0, stream>>>(h, buf1, Wfs, bfs, rowm, rowr, wsmb, out_fs);
    // pooled & sp
    mean_tokens<<<B_, 256, 0, stream>>>(out_fs, pooled);
    mean_tokens<<<B_, 256, 0, stream>>>(out_se, sp);
    // parent logits + routing (output 0)
    parent_kernel<<<B_, 256, 0, stream>>>(pooled, Wpc, bpc, out_pl, yhat);
    // routed child classifiers (outputs 1, 2)
    child_kernel<<<B_, 64, 0, stream>>>(sp, yhat, Wc0, bc0, Wc1, bc1, out_c0, out_c1);
}

// Round 2
// 1285.887 us; speedup vs baseline: 1.7877x; 1.7877x over previous
//
#include <hip/hip_runtime.h>
#include <hip/hip_bf16.h>
#include <math.h>

// Problem dims
#define B_   256
#define N_   196
#define IN_  1024
#define D_   256
#define H_   8
#define HD_  32
#define NC_  1000
#define S0_  10
#define S1_  20
#define ROWS (B_*N_)      // 50176
#define CAT  (IN_+D_)     // 1280

typedef unsigned short ushort_t;
typedef short bf16x8 __attribute__((ext_vector_type(8)));
typedef float f32x4  __attribute__((ext_vector_type(4)));
typedef ushort_t us4 __attribute__((ext_vector_type(4)));
typedef ushort_t us8 __attribute__((ext_vector_type(8)));

__device__ __forceinline__ ushort_t f2bf(float f){
    union { float f; unsigned int u; } x; x.f = f;
    unsigned int r = (x.u + 0x7fffu + ((x.u >> 16) & 1u)) >> 16;
    return (ushort_t)r;
}
__device__ __forceinline__ float bf2f(ushort_t h){
    union { unsigned int u; float f; } x; x.u = ((unsigned int)h) << 16;
    return x.f;
}
__device__ __forceinline__ float gelu_tanh(float x){
    float x3 = x*x*x;
    float inner = 0.7978845608028654f*(x + 0.044715f*x3);
    return 0.5f*x*(1.0f + tanhf(inner));
}

// ---------- weight split: hi/lo bf16 planes ----------
__global__ __launch_bounds__(256)
void split_kernel(const float* __restrict__ src, ushort_t* __restrict__ hi,
                  ushort_t* __restrict__ lo, int n)
{
    int i = blockIdx.x*256 + threadIdx.x;
    if (i < n){
        float v = src[i];
        ushort_t h = f2bf(v);
        hi[i] = h;
        lo[i] = f2bf(v - bf2f(h));
    }
}

// ---------- split-bf16 MFMA GEMM: C[M,256] = act(A[M,K] * W[256,K]^T + bias) ----------
// A f32 (split on the fly), W pre-split hi/lo. 3 MFMA per frag pair (hi*hi + hi*lo + lo*hi).
// BM=128, BN=128, BK=64; 4 waves (2x2), each 64x64 out.
#define LDK 72   // padded LDS row stride (ushorts)

template<int K, int ACT>
__global__ __launch_bounds__(256)
void gemm_split(const float* __restrict__ A, const ushort_t* __restrict__ Whi,
                const ushort_t* __restrict__ Wlo, const float* __restrict__ bias,
                float* __restrict__ C)
{
    __shared__ ushort_t Ah[128*LDK], Al[128*LDK], Bh[128*LDK], Bl[128*LDK];
    const int bm = blockIdx.x * 128;
    const int bn = blockIdx.y * 128;
    const int t  = threadIdx.x;
    const int lane = t & 63;
    const int wid  = t >> 6;
    const int wr = wid >> 1, wc = wid & 1;
    const int fr = lane & 15, fq = lane >> 4;

    f32x4 acc[4][4];
    #pragma unroll
    for (int i=0;i<4;++i)
        #pragma unroll
        for (int j=0;j<4;++j) acc[i][j] = (f32x4){0.f,0.f,0.f,0.f};

    const int sr = t >> 1;            // staging row 0..127
    const int sh = (t & 1) * 32;      // staging k-offset
    const float*    aptr  = A   + (size_t)(bm + sr)*K + sh;
    const ushort_t* bhptr = Whi + (size_t)(bn + sr)*K + sh;
    const ushort_t* blptr = Wlo + (size_t)(bn + sr)*K + sh;

    for (int k0 = 0; k0 < K; k0 += 64){
        // stage A (f32 -> hi/lo bf16)
        #pragma unroll
        for (int j=0;j<8;++j){
            float4 v = *(const float4*)(aptr + k0 + j*4);
            us4 hi, lo;
            hi.x = f2bf(v.x); lo.x = f2bf(v.x - bf2f(hi.x));
            hi.y = f2bf(v.y); lo.y = f2bf(v.y - bf2f(hi.y));
            hi.z = f2bf(v.z); lo.z = f2bf(v.z - bf2f(hi.z));
            hi.w = f2bf(v.w); lo.w = f2bf(v.w - bf2f(hi.w));
            *(us4*)&Ah[sr*LDK + sh + j*4] = hi;
            *(us4*)&Al[sr*LDK + sh + j*4] = lo;
        }
        // stage B (pre-split bf16 copy)
        #pragma unroll
        for (int j=0;j<4;++j){
            *(us8*)&Bh[sr*LDK + sh + j*8] = *(const us8*)(bhptr + k0 + j*8);
            *(us8*)&Bl[sr*LDK + sh + j*8] = *(const us8*)(blptr + k0 + j*8);
        }
        __syncthreads();
        #pragma unroll
        for (int ks=0; ks<64; ks+=32){
            bf16x8 ah[4], al[4], bh[4], bl[4];
            #pragma unroll
            for (int i=0;i<4;++i){
                int ar = (wr*64 + i*16 + fr)*LDK + ks + fq*8;
                ah[i] = *(const bf16x8*)&Ah[ar];
                al[i] = *(const bf16x8*)&Al[ar];
                int br = (wc*64 + i*16 + fr)*LDK + ks + fq*8;
                bh[i] = *(const bf16x8*)&Bh[br];
                bl[i] = *(const bf16x8*)&Bl[br];
            }
            #pragma unroll
            for (int i=0;i<4;++i)
                #pragma unroll
                for (int j=0;j<4;++j){
                    acc[i][j] = __builtin_amdgcn_mfma_f32_16x16x32_bf16(ah[i], bh[j], acc[i][j], 0,0,0);
                    acc[i][j] = __builtin_amdgcn_mfma_f32_16x16x32_bf16(ah[i], bl[j], acc[i][j], 0,0,0);
                    acc[i][j] = __builtin_amdgcn_mfma_f32_16x16x32_bf16(al[i], bh[j], acc[i][j], 0,0,0);
                }
        }
        __syncthreads();
    }
    // epilogue
    #pragma unroll
    for (int i=0;i<4;++i){
        #pragma unroll
        for (int j=0;j<4;++j){
            int col = bn + wc*64 + j*16 + fr;
            float bb = bias[col];
            #pragma unroll
            for (int r=0;r<4;++r){
                int row = bm + wr*64 + i*16 + fq*4 + r;
                float x = acc[i][j][r] + bb;
                if (ACT) x = gelu_tanh(x);
                C[(size_t)row*D_ + col] = x;
            }
        }
    }
}

// ---------- plain-bf16 MFMA GEMM for fs with LN folded ----------
// A = concat(h[.,1024], integ[.,256]) f32 -> bf16, W = WfsH. K=1280.
__global__ __launch_bounds__(256)
void gemm_fs_mfma(const float* __restrict__ h, const float* __restrict__ integ,
                  const ushort_t* __restrict__ Whi, const float* __restrict__ bias,
                  const float* __restrict__ rowm, const float* __restrict__ rowr,
                  const float* __restrict__ wsum, float* __restrict__ C)
{
    __shared__ ushort_t Ab[128*LDK], Bb[128*LDK];
    const int bm = blockIdx.x * 128;
    const int bn = blockIdx.y * 128;
    const int t  = threadIdx.x;
    const int lane = t & 63;
    const int wid  = t >> 6;
    const int wr = wid >> 1, wc = wid & 1;
    const int fr = lane & 15, fq = lane >> 4;

    f32x4 acc[4][4];
    #pragma unroll
    for (int i=0;i<4;++i)
        #pragma unroll
        for (int j=0;j<4;++j) acc[i][j] = (f32x4){0.f,0.f,0.f,0.f};

    const int sr = t >> 1;
    const int sh = (t & 1) * 32;
    const int arow = bm + sr;
    const ushort_t* bhptr = Whi + (size_t)(bn + sr)*CAT + sh;

    for (int k0 = 0; k0 < CAT; k0 += 64){
        #pragma unroll
        for (int j=0;j<8;++j){
            int c = k0 + sh + j*4;
            float4 v = (c < IN_) ? *(const float4*)(h + (size_t)arow*IN_ + c)
                                 : *(const float4*)(integ + (size_t)arow*D_ + (c - IN_));
            us4 hi;
            hi.x = f2bf(v.x); hi.y = f2bf(v.y); hi.z = f2bf(v.z); hi.w = f2bf(v.w);
            *(us4*)&Ab[sr*LDK + sh + j*4] = hi;
        }
        #pragma unroll
        for (int j=0;j<4;++j)
            *(us8*)&Bb[sr*LDK + sh + j*8] = *(const us8*)(bhptr + k0 + j*8);
        __syncthreads();
        #pragma unroll
        for (int ks=0; ks<64; ks+=32){
            bf16x8 ab[4], bb[4];
            #pragma unroll
            for (int i=0;i<4;++i){
                ab[i] = *(const bf16x8*)&Ab[(wr*64 + i*16 + fr)*LDK + ks + fq*8];
                bb[i] = *(const bf16x8*)&Bb[(wc*64 + i*16 + fr)*LDK + ks + fq*8];
            }
            #pragma unroll
            for (int i=0;i<4;++i)
                #pragma unroll
                for (int j=0;j<4;++j)
                    acc[i][j] = __builtin_amdgcn_mfma_f32_16x16x32_bf16(ab[i], bb[j], acc[i][j], 0,0,0);
        }
        __syncthreads();
    }
    #pragma unroll
    for (int i=0;i<4;++i){
        #pragma unroll
        for (int j=0;j<4;++j){
            int col = bn + wc*64 + j*16 + fr;
            float ws_ = wsum[col], bb = bias[col];
            #pragma unroll
            for (int r=0;r<4;++r){
                int row = bm + wr*64 + i*16 + fq*4 + r;
                float x = rowr[row]*(acc[i][j][r] - rowm[row]*ws_) + bb;
                C[(size_t)row*D_ + col] = x;
            }
        }
    }
}

// ---------- per-row LN stats of concat(h,integ) ----------
__global__ __launch_bounds__(256)
void rowstats_kernel(const float* __restrict__ h, const float* __restrict__ integ,
                     float* __restrict__ rowm, float* __restrict__ rowr)
{
    const int r = blockIdx.x;
    const int t = threadIdx.x;
    float s = 0.f, s2 = 0.f;
    for (int c = t; c < CAT; c += 256){
        float x = (c < IN_) ? h[(size_t)r*IN_ + c] : integ[(size_t)r*D_ + c - IN_];
        s += x; s2 += x*x;
    }
    #pragma unroll
    for (int off=32; off>0; off>>=1){ s += __shfl_down(s, off); s2 += __shfl_down(s2, off); }
    __shared__ float ss[4], ss2[4];
    int w = t >> 6;
    if ((t & 63) == 0){ ss[w]=s; ss2[w]=s2; }
    __syncthreads();
    if (t == 0){
        float S = ss[0]+ss[1]+ss[2]+ss[3];
        float S2 = ss2[0]+ss2[1]+ss2[2]+ss2[3];
        float m = S * (1.0f/CAT);
        float v = S2 * (1.0f/CAT) - m*m;
        rowm[r] = m;
        rowr[r] = rsqrtf(v + 1e-5f);
    }
}

__global__ __launch_bounds__(256)
void wsum_kernel(const float* __restrict__ Wfs, float* __restrict__ wsum)
{
    int d = threadIdx.x;
    const float* w = Wfs + (size_t)d*CAT;
    float s = 0.f;
    for (int c=0;c<CAT;++c) s += w[c];
    wsum[d] = s;
}

// ---------- attention (f32) ----------
__global__ __launch_bounds__(256)
void attn_kernel(const float* __restrict__ qb, const float* __restrict__ kb,
                 const float* __restrict__ vb, float* __restrict__ ao)
{
    const int b = blockIdx.x, hh = blockIdx.y;
    __shared__ __align__(16) float Ks[N_][HD_];
    __shared__ __align__(16) float Vs[N_][HD_];
    const int t = threadIdx.x;
    const size_t base = (size_t)b*N_*D_ + hh*HD_;
    for (int idx = t; idx < N_*8; idx += 256){
        int j = idx >> 3, d4 = (idx & 7) << 2;
        *(float4*)&Ks[j][d4] = *(const float4*)(kb + base + (size_t)j*D_ + d4);
        *(float4*)&Vs[j][d4] = *(const float4*)(vb + base + (size_t)j*D_ + d4);
    }
    __syncthreads();
    if (t < N_){
        float q[HD_];
        const float* qp = qb + base + (size_t)t*D_;
        const float scale = 0.17677669529663687f;
        #pragma unroll
        for (int d4=0; d4<HD_; d4+=4){
            float4 qv = *(const float4*)(qp + d4);
            q[d4]=qv.x*scale; q[d4+1]=qv.y*scale; q[d4+2]=qv.z*scale; q[d4+3]=qv.w*scale;
        }
        float m = -3.4e38f;
        for (int j=0;j<N_;++j){
            float s = 0.f;
            #pragma unroll
            for (int d=0; d<HD_; ++d) s += q[d]*Ks[j][d];
            m = fmaxf(m, s);
        }
        float acc[HD_];
        #pragma unroll
        for (int d=0; d<HD_; ++d) acc[d]=0.f;
        float sum = 0.f;
        for (int j=0;j<N_;++j){
            float s = 0.f;
            #pragma unroll
            for (int d=0; d<HD_; ++d) s += q[d]*Ks[j][d];
            float p = expf(s - m);
            sum += p;
            #pragma unroll
            for (int d=0; d<HD_; ++d) acc[d] += p*Vs[j][d];
        }
        float inv = 1.0f/sum;
        float* op = ao + base + (size_t)t*D_;
        #pragma unroll
        for (int d4=0; d4<HD_; d4+=4){
            float4 ov = { acc[d4]*inv, acc[d4+1]*inv, acc[d4+2]*inv, acc[d4+3]*inv };
            *(float4*)(op + d4) = ov;
        }
    }
}

// ---------- Abar[b,c] = mean_n rowr*concat ; mbar[b] = mean_n rowr*rowm ----------
__global__ __launch_bounds__(256)
void abar_kernel(const float* __restrict__ h, const float* __restrict__ integ,
                 const float* __restrict__ rowr, const float* __restrict__ rowm,
                 float* __restrict__ Abar, float* __restrict__ mbar)
{
    const int b = blockIdx.x, t = threadIdx.x;
    float acc[5] = {0.f,0.f,0.f,0.f,0.f};
    const float* hb = h + (size_t)b*N_*IN_;
    const float* ib = integ + (size_t)b*N_*D_;
    const float* rr = rowr + b*N_;
    for (int n=0;n<N_;++n){
        float s = rr[n];
        #pragma unroll
        for (int j=0;j<4;++j) acc[j] += s * hb[(size_t)n*IN_ + t + j*256];
        acc[4] += s * ib[(size_t)n*D_ + t];
    }
    #pragma unroll
    for (int j=0;j<4;++j) Abar[(size_t)b*CAT + t + j*256] = acc[j] * (1.f/N_);
    Abar[(size_t)b*CAT + IN_ + t] = acc[4] * (1.f/N_);
    if (t==0){
        float m=0.f; const float* rm = rowm + b*N_;
        for (int n=0;n<N_;++n) m += rr[n]*rm[n];
        mbar[b] = m*(1.f/N_);
    }
}

// ---------- pooled[b,d] = Abar[b]·Wfs[d] - mbar[b]*wsum[d] + bfs[d]  (f32 exact) ----------
__global__ __launch_bounds__(256)
void pooled_kernel(const float* __restrict__ Abar, const float* __restrict__ mbar,
                   const float* __restrict__ Wfs, const float* __restrict__ wsum,
                   const float* __restrict__ bfs, float* __restrict__ pooled)
{
    const int b = blockIdx.x, d = threadIdx.x;
    __shared__ float ab[CAT];
    for (int c=d;c<CAT;c+=256) ab[c] = Abar[(size_t)b*CAT + c];
    __syncthreads();
    const float* w = Wfs + (size_t)d*CAT;
    float s = 0.f;
    for (int c=0;c<CAT;c+=4){
        float4 wv = *(const float4*)(w+c);
        s += ab[c]*wv.x + ab[c+1]*wv.y + ab[c+2]*wv.z + ab[c+3]*wv.w;
    }
    pooled[b*D_ + d] = s - mbar[b]*wsum[d] + bfs[d];
}

// ---------- mean over tokens ----------
__global__ __launch_bounds__(256)
void mean_tokens(const float* __restrict__ src, float* __restrict__ dst)
{
    int b = blockIdx.x, d = threadIdx.x;
    const float* p = src + (size_t)b*N_*D_ + d;
    float s = 0.f;
    for (int n=0;n<N_;++n) s += p[(size_t)n*D_];
    dst[b*D_ + d] = s * (1.0f/N_);
}

// ---------- parent logits + routing ----------
__global__ __launch_bounds__(256)
void parent_kernel(const float* __restrict__ pooled, const float* __restrict__ Wpc,
                   const float* __restrict__ bpc, float* __restrict__ out, int* __restrict__ yhat)
{
    const int b = blockIdx.x, t = threadIdx.x;
    __shared__ __align__(16) float pl[D_];
    __shared__ float lg[NC_];
    pl[t] = pooled[b*D_ + t];
    __syncthreads();
    for (int c = t; c < NC_; c += 256){
        const float* w = Wpc + (size_t)c*D_;
        float s = 0.f;
        #pragma unroll 8
        for (int j=0;j<D_;++j) s += pl[j]*w[j];
        lg[c] = s + bpc[c];
    }
    __syncthreads();
    float s=0.f, s2=0.f, bmv=-3.4e38f; int bidx=0;
    for (int c=t;c<NC_;c+=256){
        float x = lg[c]; s += x; s2 += x*x;
        if (x > bmv){ bmv=x; bidx=c; }
    }
    #pragma unroll
    for (int off=32; off>0; off>>=1){
        s  += __shfl_down(s, off);
        s2 += __shfl_down(s2, off);
        float ov = __shfl_down(bmv, off); int oi = __shfl_down(bidx, off);
        if (ov > bmv || (ov == bmv && oi < bidx)){ bmv=ov; bidx=oi; }
    }
    __shared__ float rs[4], rs2[4], rmv[4]; __shared__ int ri[4];
    __shared__ float fm, fr_;
    int w = t >> 6;
    if ((t & 63) == 0){ rs[w]=s; rs2[w]=s2; rmv[w]=bmv; ri[w]=bidx; }
    __syncthreads();
    if (t == 0){
        float S=0.f, S2=0.f, mv=-3.4e38f; int mi=0;
        for (int i=0;i<4;++i){
            S += rs[i]; S2 += rs2[i];
            if (rmv[i] > mv || (rmv[i] == mv && ri[i] < mi)){ mv=rmv[i]; mi=ri[i]; }
        }
        float mean = S*(1.0f/NC_);
        float var  = S2*(1.0f/NC_) - mean*mean;
        fm = mean; fr_ = rsqrtf(var + 1e-5f);
        yhat[b] = mi;
    }
    __syncthreads();
    for (int c=t;c<NC_;c+=256) out[(size_t)b*NC_ + c] = (lg[c]-fm)*fr_;
}

// ---------- routed child classifiers ----------
__global__ __launch_bounds__(64)
void child_kernel(const float* __restrict__ sp, const int* __restrict__ yhat,
                  const float* __restrict__ Wc0, const float* __restrict__ bc0,
                  const float* __restrict__ Wc1, const float* __restrict__ bc1,
                  float* __restrict__ out_c0, float* __restrict__ out_c1)
{
    const int b = blockIdx.x, t = threadIdx.x;
    __shared__ float spl[D_];
    for (int i=t;i<D_;i+=64) spl[i] = sp[b*D_ + i];
    __syncthreads();
    const int y = yhat[b];
    __shared__ float c0v[S0_], c1v[S1_];
    if (t < S0_){
        const float* w = Wc0 + (size_t)y*D_*S0_ + t;
        float s = 0.f;
        for (int d=0;d<D_;++d) s += spl[d]*w[(size_t)d*S0_];
        c0v[t] = s + bc0[y*S0_ + t];
    } else if (t < S0_+S1_){
        int k = t - S0_;
        const float* w = Wc1 + (size_t)y*D_*S1_ + k;
        float s = 0.f;
        for (int d=0;d<D_;++d) s += spl[d]*w[(size_t)d*S1_];
        c1v[k] = s + bc1[y*S1_ + k];
    }
    __syncthreads();
    __shared__ float st[4];
    if (t == 0){
        float m=0.f; for (int i=0;i<S0_;++i) m += c0v[i]; m *= (1.0f/S0_);
        float v=0.f; for (int i=0;i<S0_;++i){ float d=c0v[i]-m; v += d*d; } v *= (1.0f/S0_);
        st[0]=m; st[1]=rsqrtf(v+1e-5f);
        m=0.f; for (int i=0;i<S1_;++i) m += c1v[i]; m *= (1.0f/S1_);
        v=0.f; for (int i=0;i<S1_;++i){ float d=c1v[i]-m; v += d*d; } v *= (1.0f/S1_);
        st[2]=m; st[3]=rsqrtf(v+1e-5f);
    }
    __syncthreads();
    if (t < S0_) out_c0[b*S0_ + t] = (c0v[t]-st[0])*st[1];
    else if (t < S0_+S1_) out_c1[b*S1_ + (t-S0_)] = (c1v[t-S0_]-st[2])*st[3];
}

extern "C" void kernel_launch(void* const* d_in, const int* in_sizes, int n_in,
                              void* d_out, int out_size, void* d_ws, size_t ws_size,
                              hipStream_t stream)
{
    const float* h   = (const float*)d_in[0];
    const float* Wp  = (const float*)d_in[1];
    const float* bp  = (const float*)d_in[2];
    const float* Wsub= (const float*)d_in[3];
    const float* bs  = (const float*)d_in[4];
    const float* Wq  = (const float*)d_in[5];
    const float* bq  = (const float*)d_in[6];
    const float* Wk  = (const float*)d_in[7];
    const float* bk  = (const float*)d_in[8];
    const float* Wv  = (const float*)d_in[9];
    const float* bv  = (const float*)d_in[10];
    const float* Wo  = (const float*)d_in[11];
    const float* bo  = (const float*)d_in[12];
    const float* Wfs = (const float*)d_in[13];
    const float* bfs = (const float*)d_in[14];
    const float* Wpc = (const float*)d_in[15];
    const float* bpc = (const float*)d_in[16];
    const float* Wc0 = (const float*)d_in[17];
    const float* bc0 = (const float*)d_in[18];
    const float* Wc1 = (const float*)d_in[19];
    const float* bc1 = (const float*)d_in[20];

    float* out = (float*)d_out;
    float* out_pl = out;                         // [256,1000]
    float* out_c0 = out + 256000;                // [256,10]
    float* out_c1 = out + 258560;                // [256,20]
    float* out_fs = out + 263680;                // [256,196,256]
    float* out_se = out + 13108736;              // [256,196,256]

    float* ws = (float*)d_ws;
    const size_t RB = (size_t)ROWS * D_;         // 12845056
    float* buf0 = ws;            // pe -> later ao
    float* buf1 = ws + RB;       // q  -> later integ
    float* buf2 = ws + 2*RB;     // k
    float* buf3 = ws + 3*RB;     // v
    float* p    = ws + 4*RB;
    float* rowm = p;                       // 50176
    float* rowr = rowm + ROWS;             // 50176
    float* wsmb = rowr + ROWS;             // 256
    float* pooled = wsmb + D_;             // 65536
    float* sp   = pooled + (size_t)B_*D_;  // 65536
    float* mbar = sp + (size_t)B_*D_;      // 256
    float* Abar = mbar + 256;              // 327680
    int*   yhat = (int*)(Abar + (size_t)B_*CAT);   // 256
    ushort_t* us = (ushort_t*)(yhat + 512);        // weight planes
    ushort_t* WpH = us;               ushort_t* WpL = WpH + 262144;
    ushort_t* WsH = WpL + 262144;     ushort_t* WsL = WsH + 262144;
    ushort_t* WqH = WsL + 262144;     ushort_t* WqL = WqH + 65536;
    ushort_t* WkH = WqL + 65536;      ushort_t* WkL = WkH + 65536;
    ushort_t* WvH = WkL + 65536;      ushort_t* WvL = WvH + 65536;
    ushort_t* WoH = WvL + 65536;      ushort_t* WoL = WoH + 65536;
    ushort_t* WfsH = WoL + 65536;     ushort_t* WfsL = WfsH + 327680;

    // split weights to bf16 hi/lo planes
    split_kernel<<<1024, 256, 0, stream>>>(Wp,   WpH,  WpL,  262144);
    split_kernel<<<1024, 256, 0, stream>>>(Wsub, WsH,  WsL,  262144);
    split_kernel<<<256,  256, 0, stream>>>(Wq,   WqH,  WqL,  65536);
    split_kernel<<<256,  256, 0, stream>>>(Wk,   WkH,  WkL,  65536);
    split_kernel<<<256,  256, 0, stream>>>(Wv,   WvH,  WvL,  65536);
    split_kernel<<<256,  256, 0, stream>>>(Wo,   WoH,  WoL,  65536);
    split_kernel<<<1280, 256, 0, stream>>>(Wfs,  WfsH, WfsL, 327680);

    dim3 g(ROWS/128, 2);
    // projections + gelu (split-bf16, ~f32 accuracy)
    gemm_split<IN_, 1><<<g, 256, 0, stream>>>(h, WpH, WpL, bp, buf0);     // pe
    gemm_split<IN_, 1><<<g, 256, 0, stream>>>(h, WsH, WsL, bs, out_se);   // se (output 4)
    // q,k,v
    gemm_split<D_, 0><<<g, 256, 0, stream>>>(buf0,   WqH, WqL, bq, buf1); // q
    gemm_split<D_, 0><<<g, 256, 0, stream>>>(out_se, WkH, WkL, bk, buf2); // k
    gemm_split<D_, 0><<<g, 256, 0, stream>>>(out_se, WvH, WvL, bv, buf3); // v
    // attention (f32) -> ao (reuse buf0)
    attn_kernel<<<dim3(B_, H_), 256, 0, stream>>>(buf1, buf2, buf3, buf0);
    // integ = ao @ Wo^T + bo (reuse buf1)
    gemm_split<D_, 0><<<g, 256, 0, stream>>>(buf0, WoH, WoL, bo, buf1);
    // LN stats + colsum(Wfs)
    rowstats_kernel<<<ROWS, 256, 0, stream>>>(h, buf1, rowm, rowr);
    wsum_kernel<<<1, 256, 0, stream>>>(Wfs, wsmb);
    // fs (plain bf16 MFMA, LN folded) -> output 3
    gemm_fs_mfma<<<g, 256, 0, stream>>>(h, buf1, WfsH, bfs, rowm, rowr, wsmb, out_fs);
    // exact f32 pooled via Abar identity (keeps argmax routing f32-accurate)
    abar_kernel<<<B_, 256, 0, stream>>>(h, buf1, rowr, rowm, Abar, mbar);
    pooled_kernel<<<B_, 256, 0, stream>>>(Abar, mbar, Wfs, wsmb, bfs, pooled);
    // sp from se
    mean_tokens<<<B_, 256, 0, stream>>>(out_se, sp);
    // parent logits + routing (output 0)
    parent_kernel<<<B_, 256, 0, stream>>>(pooled, Wpc, bpc, out_pl, yhat);
    // routed child classifiers (outputs 1, 2)
    child_kernel<<<B_, 64, 0, stream>>>(sp, yhat, Wc0, bc0, Wc1, bc1, out_c0, out_c1);
}

// Round 3
// 1032.010 us; speedup vs baseline: 2.2274x; 1.2460x over previous
//
#include <hip/hip_runtime.h>
#include <hip/hip_bf16.h>
#include <math.h>

// Problem dims
#define B_   256
#define N_   196
#define IN_  1024
#define D_   256
#define H_   8
#define HD_  32
#define NC_  1000
#define S0_  10
#define S1_  20
#define ROWS (B_*N_)      // 50176
#define CAT  (IN_+D_)     // 1280

typedef unsigned short ushort_t;
typedef short bf16x8 __attribute__((ext_vector_type(8)));
typedef float f32x4  __attribute__((ext_vector_type(4)));
typedef ushort_t us4 __attribute__((ext_vector_type(4)));
typedef ushort_t us8 __attribute__((ext_vector_type(8)));

__device__ __forceinline__ ushort_t f2bf(float f){
    union { float f; unsigned int u; } x; x.f = f;
    unsigned int r = (x.u + 0x7fffu + ((x.u >> 16) & 1u)) >> 16;
    return (ushort_t)r;
}
__device__ __forceinline__ float bf2f(ushort_t h){
    union { unsigned int u; float f; } x; x.u = ((unsigned int)h) << 16;
    return x.f;
}
__device__ __forceinline__ float gelu_tanh(float x){
    float x3 = x*x*x;
    float inner = 0.7978845608028654f*(x + 0.044715f*x3);
    return 0.5f*x*(1.0f + tanhf(inner));
}
__device__ __forceinline__ void split8(const float* f, bf16x8& hi, bf16x8& lo){
    #pragma unroll
    for (int j=0;j<8;++j){
        ushort_t h = f2bf(f[j]);
        hi[j] = (short)h;
        lo[j] = (short)f2bf(f[j] - bf2f(h));
    }
}

// ---------- weight split: hi/lo bf16 planes ----------
__global__ __launch_bounds__(256)
void split_kernel(const float* __restrict__ src, ushort_t* __restrict__ hi,
                  ushort_t* __restrict__ lo, int n)
{
    int i = blockIdx.x*256 + threadIdx.x;
    if (i < n){
        float v = src[i];
        ushort_t h = f2bf(v);
        hi[i] = h;
        lo[i] = f2bf(v - bf2f(h));
    }
}

// ---------- split-bf16 MFMA GEMM: C[M,256] = act(A[M,K] * W[256,K]^T + bias) ----------
#define LDK 72   // padded LDS row stride (ushorts)

template<int K, int ACT>
__global__ __launch_bounds__(256)
void gemm_split(const float* __restrict__ A, const ushort_t* __restrict__ Whi,
                const ushort_t* __restrict__ Wlo, const float* __restrict__ bias,
                float* __restrict__ C)
{
    __shared__ ushort_t Ah[128*LDK], Al[128*LDK], Bh[128*LDK], Bl[128*LDK];
    const int bm = blockIdx.x * 128;
    const int bn = blockIdx.y * 128;
    const int t  = threadIdx.x;
    const int lane = t & 63;
    const int wid  = t >> 6;
    const int wr = wid >> 1, wc = wid & 1;
    const int fr = lane & 15, fq = lane >> 4;

    f32x4 acc[4][4];
    #pragma unroll
    for (int i=0;i<4;++i)
        #pragma unroll
        for (int j=0;j<4;++j) acc[i][j] = (f32x4){0.f,0.f,0.f,0.f};

    const int sr = t >> 1;            // staging row 0..127
    const int sh = (t & 1) * 32;      // staging k-offset
    const float*    aptr  = A   + (size_t)(bm + sr)*K + sh;
    const ushort_t* bhptr = Whi + (size_t)(bn + sr)*K + sh;
    const ushort_t* blptr = Wlo + (size_t)(bn + sr)*K + sh;

    for (int k0 = 0; k0 < K; k0 += 64){
        #pragma unroll
        for (int j=0;j<8;++j){
            float4 v = *(const float4*)(aptr + k0 + j*4);
            us4 hi, lo;
            hi.x = f2bf(v.x); lo.x = f2bf(v.x - bf2f(hi.x));
            hi.y = f2bf(v.y); lo.y = f2bf(v.y - bf2f(hi.y));
            hi.z = f2bf(v.z); lo.z = f2bf(v.z - bf2f(hi.z));
            hi.w = f2bf(v.w); lo.w = f2bf(v.w - bf2f(hi.w));
            *(us4*)&Ah[sr*LDK + sh + j*4] = hi;
            *(us4*)&Al[sr*LDK + sh + j*4] = lo;
        }
        #pragma unroll
        for (int j=0;j<4;++j){
            *(us8*)&Bh[sr*LDK + sh + j*8] = *(const us8*)(bhptr + k0 + j*8);
            *(us8*)&Bl[sr*LDK + sh + j*8] = *(const us8*)(blptr + k0 + j*8);
        }
        __syncthreads();
        #pragma unroll
        for (int ks=0; ks<64; ks+=32){
            bf16x8 ah[4], al[4], bh[4], bl[4];
            #pragma unroll
            for (int i=0;i<4;++i){
                int ar = (wr*64 + i*16 + fr)*LDK + ks + fq*8;
                ah[i] = *(const bf16x8*)&Ah[ar];
                al[i] = *(const bf16x8*)&Al[ar];
                int br = (wc*64 + i*16 + fr)*LDK + ks + fq*8;
                bh[i] = *(const bf16x8*)&Bh[br];
                bl[i] = *(const bf16x8*)&Bl[br];
            }
            #pragma unroll
            for (int i=0;i<4;++i)
                #pragma unroll
                for (int j=0;j<4;++j){
                    acc[i][j] = __builtin_amdgcn_mfma_f32_16x16x32_bf16(ah[i], bh[j], acc[i][j], 0,0,0);
                    acc[i][j] = __builtin_amdgcn_mfma_f32_16x16x32_bf16(ah[i], bl[j], acc[i][j], 0,0,0);
                    acc[i][j] = __builtin_amdgcn_mfma_f32_16x16x32_bf16(al[i], bh[j], acc[i][j], 0,0,0);
                }
        }
        __syncthreads();
    }
    #pragma unroll
    for (int i=0;i<4;++i){
        #pragma unroll
        for (int j=0;j<4;++j){
            int col = bn + wc*64 + j*16 + fr;
            float bb = bias[col];
            #pragma unroll
            for (int r=0;r<4;++r){
                int row = bm + wr*64 + i*16 + fq*4 + r;
                float x = acc[i][j][r] + bb;
                if (ACT) x = gelu_tanh(x);
                C[(size_t)row*D_ + col] = x;
            }
        }
    }
}

// ---------- plain-bf16 MFMA GEMM for fs with LN folded ----------
__global__ __launch_bounds__(256)
void gemm_fs_mfma(const float* __restrict__ h, const float* __restrict__ integ,
                  const ushort_t* __restrict__ Whi, const float* __restrict__ bias,
                  const float* __restrict__ rowm, const float* __restrict__ rowr,
                  const float* __restrict__ wsum, float* __restrict__ C)
{
    __shared__ ushort_t Ab[128*LDK], Bb[128*LDK];
    const int bm = blockIdx.x * 128;
    const int bn = blockIdx.y * 128;
    const int t  = threadIdx.x;
    const int lane = t & 63;
    const int wid  = t >> 6;
    const int wr = wid >> 1, wc = wid & 1;
    const int fr = lane & 15, fq = lane >> 4;

    f32x4 acc[4][4];
    #pragma unroll
    for (int i=0;i<4;++i)
        #pragma unroll
        for (int j=0;j<4;++j) acc[i][j] = (f32x4){0.f,0.f,0.f,0.f};

    const int sr = t >> 1;
    const int sh = (t & 1) * 32;
    const int arow = bm + sr;
    const ushort_t* bhptr = Whi + (size_t)(bn + sr)*CAT + sh;

    for (int k0 = 0; k0 < CAT; k0 += 64){
        #pragma unroll
        for (int j=0;j<8;++j){
            int c = k0 + sh + j*4;
            float4 v = (c < IN_) ? *(const float4*)(h + (size_t)arow*IN_ + c)
                                 : *(const float4*)(integ + (size_t)arow*D_ + (c - IN_));
            us4 hi;
            hi.x = f2bf(v.x); hi.y = f2bf(v.y); hi.z = f2bf(v.z); hi.w = f2bf(v.w);
            *(us4*)&Ab[sr*LDK + sh + j*4] = hi;
        }
        #pragma unroll
        for (int j=0;j<4;++j)
            *(us8*)&Bb[sr*LDK + sh + j*8] = *(const us8*)(bhptr + k0 + j*8);
        __syncthreads();
        #pragma unroll
        for (int ks=0; ks<64; ks+=32){
            bf16x8 ab[4], bb[4];
            #pragma unroll
            for (int i=0;i<4;++i){
                ab[i] = *(const bf16x8*)&Ab[(wr*64 + i*16 + fr)*LDK + ks + fq*8];
                bb[i] = *(const bf16x8*)&Bb[(wc*64 + i*16 + fr)*LDK + ks + fq*8];
            }
            #pragma unroll
            for (int i=0;i<4;++i)
                #pragma unroll
                for (int j=0;j<4;++j)
                    acc[i][j] = __builtin_amdgcn_mfma_f32_16x16x32_bf16(ab[i], bb[j], acc[i][j], 0,0,0);
        }
        __syncthreads();
    }
    #pragma unroll
    for (int i=0;i<4;++i){
        #pragma unroll
        for (int j=0;j<4;++j){
            int col = bn + wc*64 + j*16 + fr;
            float ws_ = wsum[col], bb = bias[col];
            #pragma unroll
            for (int r=0;r<4;++r){
                int row = bm + wr*64 + i*16 + fq*4 + r;
                float x = rowr[row]*(acc[i][j][r] - rowm[row]*ws_) + bb;
                C[(size_t)row*D_ + col] = x;
            }
        }
    }
}

// ---------- per-row LN stats of concat(h,integ) ----------
__global__ __launch_bounds__(256)
void rowstats_kernel(const float* __restrict__ h, const float* __restrict__ integ,
                     float* __restrict__ rowm, float* __restrict__ rowr)
{
    const int r = blockIdx.x;
    const int t = threadIdx.x;
    float s = 0.f, s2 = 0.f;
    for (int c = t; c < CAT; c += 256){
        float x = (c < IN_) ? h[(size_t)r*IN_ + c] : integ[(size_t)r*D_ + c - IN_];
        s += x; s2 += x*x;
    }
    #pragma unroll
    for (int off=32; off>0; off>>=1){ s += __shfl_down(s, off); s2 += __shfl_down(s2, off); }
    __shared__ float ss[4], ss2[4];
    int w = t >> 6;
    if ((t & 63) == 0){ ss[w]=s; ss2[w]=s2; }
    __syncthreads();
    if (t == 0){
        float S = ss[0]+ss[1]+ss[2]+ss[3];
        float S2 = ss2[0]+ss2[1]+ss2[2]+ss2[3];
        float m = S * (1.0f/CAT);
        float v = S2 * (1.0f/CAT) - m*m;
        rowm[r] = m;
        rowr[r] = rsqrtf(v + 1e-5f);
    }
}

__global__ __launch_bounds__(256)
void wsum_kernel(const float* __restrict__ Wfs, float* __restrict__ wsum)
{
    int d = threadIdx.x;
    const float* w = Wfs + (size_t)d*CAT;
    float s = 0.f;
    for (int c=0;c<CAT;++c) s += w[c];
    wsum[d] = s;
}

// ---------- MFMA attention (split-bf16, swapped-operand, key-permuted V^T) ----------
// one block per (b,h); 4 waves; LDS: K hi/lo [208][40], V^T hi/lo [32][232]
#define KROWS 208
#define KLD   40
#define VLD   232

__global__ __launch_bounds__(256)
void attn_mfma(const float* __restrict__ qb, const float* __restrict__ kb,
               const float* __restrict__ vb, float* __restrict__ ao)
{
    __shared__ ushort_t Khi[KROWS*KLD], Klo[KROWS*KLD];
    __shared__ ushort_t Vthi[32*VLD], Vtlo[32*VLD];

    const int b = blockIdx.x, hh = blockIdx.y;
    const int t = threadIdx.x;
    const int lane = t & 63;
    const int wid  = t >> 6;
    const int fr = lane & 15;      // query col / A-row within tile
    const int fq = lane >> 4;      // k-slot group 0..3
    const size_t bbase = (size_t)b*N_*D_ + hh*HD_;

    // stage K (natural layout, split)
    for (int idx = t; idx < KROWS*4; idx += 256){
        int row = idx >> 2, c8 = (idx & 3) << 3;
        float f[8];
        if (row < N_){
            float4 a = *(const float4*)(kb + bbase + (size_t)row*D_ + c8);
            float4 c = *(const float4*)(kb + bbase + (size_t)row*D_ + c8 + 4);
            f[0]=a.x; f[1]=a.y; f[2]=a.z; f[3]=a.w; f[4]=c.x; f[5]=c.y; f[6]=c.z; f[7]=c.w;
        } else {
            #pragma unroll
            for (int j=0;j<8;++j) f[j]=0.f;
        }
        bf16x8 hi, lo; split8(f, hi, lo);
        *(bf16x8*)&Khi[row*KLD + c8] = hi;
        *(bf16x8*)&Klo[row*KLD + c8] = lo;
    }
    // stage V^T with key->slot permutation (keys padded to 224 slots)
    for (int idx = t; idx < 224*4; idx += 256){
        int key = idx >> 2, c8 = (idx & 3) << 3;
        float f[8];
        if (key < N_){
            float4 a = *(const float4*)(vb + bbase + (size_t)key*D_ + c8);
            float4 c = *(const float4*)(vb + bbase + (size_t)key*D_ + c8 + 4);
            f[0]=a.x; f[1]=a.y; f[2]=a.z; f[3]=a.w; f[4]=c.x; f[5]=c.y; f[6]=c.z; f[7]=c.w;
        } else {
            #pragma unroll
            for (int j=0;j<8;++j) f[j]=0.f;
        }
        int w = key & 31, cc = key >> 5;
        int slot;
        if (w < 16) slot = cc*32 + (w>>2)*8 + (w&3);
        else { int w2 = w-16; slot = cc*32 + (w2>>2)*8 + 4 + (w2&3); }
        #pragma unroll
        for (int j=0;j<8;++j){
            int dim = c8 + j;
            ushort_t hv = f2bf(f[j]);
            Vthi[dim*VLD + slot] = hv;
            Vtlo[dim*VLD + slot] = f2bf(f[j] - bf2f(hv));
        }
    }
    __syncthreads();

    const float scale = 0.17677669529663687f; // 32^-0.5
    for (int qt = wid; qt < 13; qt += 4){
        // Q^T B-frag: lane reads Q[qrow=qt*16+fr][dims fq*8..+7], scaled+split
        int qrow = qt*16 + fr; if (qrow > N_-1) qrow = N_-1;
        const float* qp = qb + bbase + (size_t)qrow*D_ + fq*8;
        float qf[8];
        {
            float4 a = *(const float4*)(qp);
            float4 c = *(const float4*)(qp + 4);
            qf[0]=a.x*scale; qf[1]=a.y*scale; qf[2]=a.z*scale; qf[3]=a.w*scale;
            qf[4]=c.x*scale; qf[5]=c.y*scale; qf[6]=c.z*scale; qf[7]=c.w*scale;
        }
        bf16x8 qh, ql; split8(qf, qh, ql);

        // scores: S^T tiles, D[key][query]
        f32x4 s[13];
        #pragma unroll
        for (int kt=0; kt<13; ++kt) s[kt] = (f32x4){0.f,0.f,0.f,0.f};
        #pragma unroll
        for (int kt=0; kt<13; ++kt){
            const bf16x8 kh = *(const bf16x8*)&Khi[(kt*16 + fr)*KLD + fq*8];
            const bf16x8 kl = *(const bf16x8*)&Klo[(kt*16 + fr)*KLD + fq*8];
            s[kt] = __builtin_amdgcn_mfma_f32_16x16x32_bf16(kh, qh, s[kt], 0,0,0);
            s[kt] = __builtin_amdgcn_mfma_f32_16x16x32_bf16(kh, ql, s[kt], 0,0,0);
            s[kt] = __builtin_amdgcn_mfma_f32_16x16x32_bf16(kl, qh, s[kt], 0,0,0);
        }
        // mask keys >= 196 (tile 12, key = 192 + fq*4 + r; valid only fq==0)
        if (fq > 0) s[12] = (f32x4){-1e30f,-1e30f,-1e30f,-1e30f};

        // wave-parallel softmax (row = query col fr; partners at xor 16,32)
        float m = -3.4e38f;
        #pragma unroll
        for (int kt=0; kt<13; ++kt)
            #pragma unroll
            for (int r=0;r<4;++r) m = fmaxf(m, s[kt][r]);
        m = fmaxf(m, __shfl_xor(m, 16));
        m = fmaxf(m, __shfl_xor(m, 32));
        float sum = 0.f;
        #pragma unroll
        for (int kt=0; kt<13; ++kt)
            #pragma unroll
            for (int r=0;r<4;++r){
                float p = __expf(s[kt][r] - m);
                s[kt][r] = p; sum += p;
            }
        sum += __shfl_xor(sum, 16);
        sum += __shfl_xor(sum, 32);
        const float inv = 1.0f / sum;

        // PV: O^T = V^T * P^T ; P-frag is the lane's own p-values (key-permuted V^T)
        f32x4 o0 = (f32x4){0.f,0.f,0.f,0.f};
        f32x4 o1 = (f32x4){0.f,0.f,0.f,0.f};
        #pragma unroll
        for (int c=0;c<7;++c){
            float pv[8];
            #pragma unroll
            for (int r=0;r<4;++r){
                pv[r]   = s[2*c][r];
                pv[4+r] = (c < 6) ? s[2*c+1][r] : 0.f;
            }
            bf16x8 ph, pl; split8(pv, ph, pl);
            const int coff = c*32 + fq*8;
            const bf16x8 v0h = *(const bf16x8*)&Vthi[(fr)*VLD + coff];
            const bf16x8 v0l = *(const bf16x8*)&Vtlo[(fr)*VLD + coff];
            const bf16x8 v1h = *(const bf16x8*)&Vthi[(16+fr)*VLD + coff];
            const bf16x8 v1l = *(const bf16x8*)&Vtlo[(16+fr)*VLD + coff];
            o0 = __builtin_amdgcn_mfma_f32_16x16x32_bf16(v0h, ph, o0, 0,0,0);
            o0 = __builtin_amdgcn_mfma_f32_16x16x32_bf16(v0h, pl, o0, 0,0,0);
            o0 = __builtin_amdgcn_mfma_f32_16x16x32_bf16(v0l, ph, o0, 0,0,0);
            o1 = __builtin_amdgcn_mfma_f32_16x16x32_bf16(v1h, ph, o1, 0,0,0);
            o1 = __builtin_amdgcn_mfma_f32_16x16x32_bf16(v1h, pl, o1, 0,0,0);
            o1 = __builtin_amdgcn_mfma_f32_16x16x32_bf16(v1l, ph, o1, 0,0,0);
        }
        // write O: row=(lane>>4)*4+r = dim, col=fr = query
        int tok = qt*16 + fr;
        if (tok < N_){
            float* op = ao + bbase + (size_t)tok*D_;
            #pragma unroll
            for (int r=0;r<4;++r){
                op[fq*4 + r]      = o0[r]*inv;
                op[16 + fq*4 + r] = o1[r]*inv;
            }
        }
    }
}

// ---------- Abar[b,c] = mean_n rowr*concat ; mbar[b] = mean_n rowr*rowm ----------
__global__ __launch_bounds__(256)
void abar_kernel(const float* __restrict__ h, const float* __restrict__ integ,
                 const float* __restrict__ rowr, const float* __restrict__ rowm,
                 float* __restrict__ Abar, float* __restrict__ mbar)
{
    const int b = blockIdx.x, t = threadIdx.x;
    float acc[5] = {0.f,0.f,0.f,0.f,0.f};
    const float* hb = h + (size_t)b*N_*IN_;
    const float* ib = integ + (size_t)b*N_*D_;
    const float* rr = rowr + b*N_;
    for (int n=0;n<N_;++n){
        float s = rr[n];
        #pragma unroll
        for (int j=0;j<4;++j) acc[j] += s * hb[(size_t)n*IN_ + t + j*256];
        acc[4] += s * ib[(size_t)n*D_ + t];
    }
    #pragma unroll
    for (int j=0;j<4;++j) Abar[(size_t)b*CAT + t + j*256] = acc[j] * (1.f/N_);
    Abar[(size_t)b*CAT + IN_ + t] = acc[4] * (1.f/N_);
    if (t==0){
        float m=0.f; const float* rm = rowm + b*N_;
        for (int n=0;n<N_;++n) m += rr[n]*rm[n];
        mbar[b] = m*(1.f/N_);
    }
}

// ---------- pooled[b,d] = Abar[b]·Wfs[d] - mbar[b]*wsum[d] + bfs[d]  (f32 exact) ----------
__global__ __launch_bounds__(256)
void pooled_kernel(const float* __restrict__ Abar, const float* __restrict__ mbar,
                   const float* __restrict__ Wfs, const float* __restrict__ wsum,
                   const float* __restrict__ bfs, float* __restrict__ pooled)
{
    const int b = blockIdx.x, d = threadIdx.x;
    __shared__ float ab[CAT];
    for (int c=d;c<CAT;c+=256) ab[c] = Abar[(size_t)b*CAT + c];
    __syncthreads();
    const float* w = Wfs + (size_t)d*CAT;
    float s = 0.f;
    for (int c=0;c<CAT;c+=4){
        float4 wv = *(const float4*)(w+c);
        s += ab[c]*wv.x + ab[c+1]*wv.y + ab[c+2]*wv.z + ab[c+3]*wv.w;
    }
    pooled[b*D_ + d] = s - mbar[b]*wsum[d] + bfs[d];
}

// ---------- mean over tokens ----------
__global__ __launch_bounds__(256)
void mean_tokens(const float* __restrict__ src, float* __restrict__ dst)
{
    int b = blockIdx.x, d = threadIdx.x;
    const float* p = src + (size_t)b*N_*D_ + d;
    float s = 0.f;
    for (int n=0;n<N_;++n) s += p[(size_t)n*D_];
    dst[b*D_ + d] = s * (1.0f/N_);
}

// ---------- parent logits + routing ----------
__global__ __launch_bounds__(256)
void parent_kernel(const float* __restrict__ pooled, const float* __restrict__ Wpc,
                   const float* __restrict__ bpc, float* __restrict__ out, int* __restrict__ yhat)
{
    const int b = blockIdx.x, t = threadIdx.x;
    __shared__ __align__(16) float pl[D_];
    __shared__ float lg[NC_];
    pl[t] = pooled[b*D_ + t];
    __syncthreads();
    for (int c = t; c < NC_; c += 256){
        const float* w = Wpc + (size_t)c*D_;
        float s = 0.f;
        #pragma unroll 8
        for (int j=0;j<D_;++j) s += pl[j]*w[j];
        lg[c] = s + bpc[c];
    }
    __syncthreads();
    float s=0.f, s2=0.f, bmv=-3.4e38f; int bidx=0;
    for (int c=t;c<NC_;c+=256){
        float x = lg[c]; s += x; s2 += x*x;
        if (x > bmv){ bmv=x; bidx=c; }
    }
    #pragma unroll
    for (int off=32; off>0; off>>=1){
        s  += __shfl_down(s, off);
        s2 += __shfl_down(s2, off);
        float ov = __shfl_down(bmv, off); int oi = __shfl_down(bidx, off);
        if (ov > bmv || (ov == bmv && oi < bidx)){ bmv=ov; bidx=oi; }
    }
    __shared__ float rs[4], rs2[4], rmv[4]; __shared__ int ri[4];
    __shared__ float fm, fr_;
    int w = t >> 6;
    if ((t & 63) == 0){ rs[w]=s; rs2[w]=s2; rmv[w]=bmv; ri[w]=bidx; }
    __syncthreads();
    if (t == 0){
        float S=0.f, S2=0.f, mv=-3.4e38f; int mi=0;
        for (int i=0;i<4;++i){
            S += rs[i]; S2 += rs2[i];
            if (rmv[i] > mv || (rmv[i] == mv && ri[i] < mi)){ mv=rmv[i]; mi=ri[i]; }
        }
        float mean = S*(1.0f/NC_);
        float var  = S2*(1.0f/NC_) - mean*mean;
        fm = mean; fr_ = rsqrtf(var + 1e-5f);
        yhat[b] = mi;
    }
    __syncthreads();
    for (int c=t;c<NC_;c+=256) out[(size_t)b*NC_ + c] = (lg[c]-fm)*fr_;
}

// ---------- routed child classifiers ----------
__global__ __launch_bounds__(64)
void child_kernel(const float* __restrict__ sp, const int* __restrict__ yhat,
                  const float* __restrict__ Wc0, const float* __restrict__ bc0,
                  const float* __restrict__ Wc1, const float* __restrict__ bc1,
                  float* __restrict__ out_c0, float* __restrict__ out_c1)
{
    const int b = blockIdx.x, t = threadIdx.x;
    __shared__ float spl[D_];
    for (int i=t;i<D_;i+=64) spl[i] = sp[b*D_ + i];
    __syncthreads();
    const int y = yhat[b];
    __shared__ float c0v[S0_], c1v[S1_];
    if (t < S0_){
        const float* w = Wc0 + (size_t)y*D_*S0_ + t;
        float s = 0.f;
        for (int d=0;d<D_;++d) s += spl[d]*w[(size_t)d*S0_];
        c0v[t] = s + bc0[y*S0_ + t];
    } else if (t < S0_+S1_){
        int k = t - S0_;
        const float* w = Wc1 + (size_t)y*D_*S1_ + k;
        float s = 0.f;
        for (int d=0;d<D_;++d) s += spl[d]*w[(size_t)d*S1_];
        c1v[k] = s + bc1[y*S1_ + k];
    }
    __syncthreads();
    __shared__ float st[4];
    if (t == 0){
        float m=0.f; for (int i=0;i<S0_;++i) m += c0v[i]; m *= (1.0f/S0_);
        float v=0.f; for (int i=0;i<S0_;++i){ float d=c0v[i]-m; v += d*d; } v *= (1.0f/S0_);
        st[0]=m; st[1]=rsqrtf(v+1e-5f);
        m=0.f; for (int i=0;i<S1_;++i) m += c1v[i]; m *= (1.0f/S1_);
        v=0.f; for (int i=0;i<S1_;++i){ float d=c1v[i]-m; v += d*d; } v *= (1.0f/S1_);
        st[2]=m; st[3]=rsqrtf(v+1e-5f);
    }
    __syncthreads();
    if (t < S0_) out_c0[b*S0_ + t] = (c0v[t]-st[0])*st[1];
    else if (t < S0_+S1_) out_c1[b*S1_ + (t-S0_)] = (c1v[t-S0_]-st[2])*st[3];
}

extern "C" void kernel_launch(void* const* d_in, const int* in_sizes, int n_in,
                              void* d_out, int out_size, void* d_ws, size_t ws_size,
                              hipStream_t stream)
{
    const float* h   = (const float*)d_in[0];
    const float* Wp  = (const float*)d_in[1];
    const float* bp  = (const float*)d_in[2];
    const float* Wsub= (const float*)d_in[3];
    const float* bs  = (const float*)d_in[4];
    const float* Wq  = (const float*)d_in[5];
    const float* bq  = (const float*)d_in[6];
    const float* Wk  = (const float*)d_in[7];
    const float* bk  = (const float*)d_in[8];
    const float* Wv  = (const float*)d_in[9];
    const float* bv  = (const float*)d_in[10];
    const float* Wo  = (const float*)d_in[11];
    const float* bo  = (const float*)d_in[12];
    const float* Wfs = (const float*)d_in[13];
    const float* bfs = (const float*)d_in[14];
    const float* Wpc = (const float*)d_in[15];
    const float* bpc = (const float*)d_in[16];
    const float* Wc0 = (const float*)d_in[17];
    const float* bc0 = (const float*)d_in[18];
    const float* Wc1 = (const float*)d_in[19];
    const float* bc1 = (const float*)d_in[20];

    float* out = (float*)d_out;
    float* out_pl = out;                         // [256,1000]
    float* out_c0 = out + 256000;                // [256,10]
    float* out_c1 = out + 258560;                // [256,20]
    float* out_fs = out + 263680;                // [256,196,256]
    float* out_se = out + 13108736;              // [256,196,256]

    float* ws = (float*)d_ws;
    const size_t RB = (size_t)ROWS * D_;         // 12845056
    float* buf0 = ws;            // pe -> later ao
    float* buf1 = ws + RB;       // q  -> later integ
    float* buf2 = ws + 2*RB;     // k
    float* buf3 = ws + 3*RB;     // v
    float* p    = ws + 4*RB;
    float* rowm = p;                       // 50176
    float* rowr = rowm + ROWS;             // 50176
    float* wsmb = rowr + ROWS;             // 256
    float* pooled = wsmb + D_;             // 65536
    float* sp   = pooled + (size_t)B_*D_;  // 65536
    float* mbar = sp + (size_t)B_*D_;      // 256
    float* Abar = mbar + 256;              // 327680
    int*   yhat = (int*)(Abar + (size_t)B_*CAT);   // 256
    ushort_t* us = (ushort_t*)(yhat + 512);        // weight planes
    ushort_t* WpH = us;               ushort_t* WpL = WpH + 262144;
    ushort_t* WsH = WpL + 262144;     ushort_t* WsL = WsH + 262144;
    ushort_t* WqH = WsL + 262144;     ushort_t* WqL = WqH + 65536;
    ushort_t* WkH = WqL + 65536;      ushort_t* WkL = WkH + 65536;
    ushort_t* WvH = WkL + 65536;      ushort_t* WvL = WvH + 65536;
    ushort_t* WoH = WvL + 65536;      ushort_t* WoL = WoH + 65536;
    ushort_t* WfsH = WoL + 65536;     ushort_t* WfsL = WfsH + 327680;

    // split weights to bf16 hi/lo planes
    split_kernel<<<1024, 256, 0, stream>>>(Wp,   WpH,  WpL,  262144);
    split_kernel<<<1024, 256, 0, stream>>>(Wsub, WsH,  WsL,  262144);
    split_kernel<<<256,  256, 0, stream>>>(Wq,   WqH,  WqL,  65536);
    split_kernel<<<256,  256, 0, stream>>>(Wk,   WkH,  WkL,  65536);
    split_kernel<<<256,  256, 0, stream>>>(Wv,   WvH,  WvL,  65536);
    split_kernel<<<256,  256, 0, stream>>>(Wo,   WoH,  WoL,  65536);
    split_kernel<<<1280, 256, 0, stream>>>(Wfs,  WfsH, WfsL, 327680);

    dim3 g(ROWS/128, 2);
    // projections + gelu (split-bf16, ~f32 accuracy)
    gemm_split<IN_, 1><<<g, 256, 0, stream>>>(h, WpH, WpL, bp, buf0);     // pe
    gemm_split<IN_, 1><<<g, 256, 0, stream>>>(h, WsH, WsL, bs, out_se);   // se (output 4)
    // q,k,v
    gemm_split<D_, 0><<<g, 256, 0, stream>>>(buf0,   WqH, WqL, bq, buf1); // q
    gemm_split<D_, 0><<<g, 256, 0, stream>>>(out_se, WkH, WkL, bk, buf2); // k
    gemm_split<D_, 0><<<g, 256, 0, stream>>>(out_se, WvH, WvL, bv, buf3); // v
    // attention (split-bf16 MFMA) -> ao (reuse buf0)
    attn_mfma<<<dim3(B_, H_), 256, 0, stream>>>(buf1, buf2, buf3, buf0);
    // integ = ao @ Wo^T + bo (reuse buf1)
    gemm_split<D_, 0><<<g, 256, 0, stream>>>(buf0, WoH, WoL, bo, buf1);
    // LN stats + colsum(Wfs)
    rowstats_kernel<<<ROWS, 256, 0, stream>>>(h, buf1, rowm, rowr);
    wsum_kernel<<<1, 256, 0, stream>>>(Wfs, wsmb);
    // fs (plain bf16 MFMA, LN folded) -> output 3
    gemm_fs_mfma<<<g, 256, 0, stream>>>(h, buf1, WfsH, bfs, rowm, rowr, wsmb, out_fs);
    // exact f32 pooled via Abar identity (keeps argmax routing f32-accurate)
    abar_kernel<<<B_, 256, 0, stream>>>(h, buf1, rowr, rowm, Abar, mbar);
    pooled_kernel<<<B_, 256, 0, stream>>>(Abar, mbar, Wfs, wsmb, bfs, pooled);
    // sp from se
    mean_tokens<<<B_, 256, 0, stream>>>(out_se, sp);
    // parent logits + routing (output 0)
    parent_kernel<<<B_, 256, 0, stream>>>(pooled, Wpc, bpc, out_pl, yhat);
    // routed child classifiers (outputs 1, 2)
    child_kernel<<<B_, 64, 0, stream>>>(sp, yhat, Wc0, bc0, Wc1, bc1, out_c0, out_c1);
}

// Round 4
// 1029.925 us; speedup vs baseline: 2.2319x; 1.0020x over previous
//
#include <hip/hip_runtime.h>
#include <hip/hip_bf16.h>
#include <math.h>

// Problem dims
#define B_   256
#define N_   196
#define IN_  1024
#define D_   256
#define H_   8
#define HD_  32
#define NC_  1000
#define S0_  10
#define S1_  20
#define ROWS (B_*N_)      // 50176
#define CAT  (IN_+D_)     // 1280

typedef unsigned short ushort_t;
typedef short bf16x8 __attribute__((ext_vector_type(8)));
typedef float f32x4  __attribute__((ext_vector_type(4)));
typedef ushort_t us4 __attribute__((ext_vector_type(4)));
typedef ushort_t us8 __attribute__((ext_vector_type(8)));

__device__ __forceinline__ ushort_t f2bf(float f){
    union { float f; unsigned int u; } x; x.f = f;
    unsigned int r = (x.u + 0x7fffu + ((x.u >> 16) & 1u)) >> 16;
    return (ushort_t)r;
}
__device__ __forceinline__ float bf2f(ushort_t h){
    union { unsigned int u; float f; } x; x.u = ((unsigned int)h) << 16;
    return x.f;
}
__device__ __forceinline__ float gelu_tanh(float x){
    float x3 = x*x*x;
    float inner = 0.7978845608028654f*(x + 0.044715f*x3);
    return 0.5f*x*(1.0f + tanhf(inner));
}
__device__ __forceinline__ void split8(const float* f, bf16x8& hi, bf16x8& lo){
    #pragma unroll
    for (int j=0;j<8;++j){
        ushort_t h = f2bf(f[j]);
        hi[j] = (short)h;
        lo[j] = (short)f2bf(f[j] - bf2f(h));
    }
}

// ---------- async global->LDS, 16B per lane; LDS dest is wave-uniform base ----------
typedef __attribute__((address_space(1))) const unsigned int gu32;
typedef __attribute__((address_space(3))) unsigned int lu32;
__device__ __forceinline__ void gload_lds16(const void* g, void* l){
    __builtin_amdgcn_global_load_lds((gu32*)g, (lu32*)l, 16, 0, 0);
}

// stage a 128x64-ushort tile (16KB), linear LDS dest, inverse-swizzled source.
// swizzle: LDS(row, slot') holds global (row, slot' ^ (row&7)); slots are 16B units.
__device__ __forceinline__ void stage64(const ushort_t* P, size_t rowbase, int ldk, int k0,
                                        ushort_t* lds, int t){
    const int w = t >> 6, l = t & 63;
    const int r8 = l >> 3;                 // row within 8-row segment; == row&7
    const int sl = (l & 7) ^ r8;           // inverse-swizzled source slot
    #pragma unroll
    for (int j=0;j<4;++j){
        int seg = w*4 + j;                 // 16 segments of 1KB (8 rows)
        const ushort_t* src = P + (rowbase + (size_t)(seg*8 + r8))*ldk + k0 + sl*8;
        gload_lds16(src, lds + seg*512);
    }
}
// stage a 128x32-ushort tile (8KB). swizzle: slot'(2b) holds global slot' ^ ((row>>1)&3).
__device__ __forceinline__ void stage32(const ushort_t* P, size_t rowbase, int ldk, int k0,
                                        ushort_t* lds, int t){
    const int w = t >> 6, l = t & 63;
    const int rr = l >> 2;                 // row within 16-row segment
    const int sl = (l & 3) ^ ((l >> 3) & 3);
    #pragma unroll
    for (int j=0;j<2;++j){
        int seg = w*2 + j;                 // 8 segments of 1KB (16 rows)
        const ushort_t* src = P + (rowbase + (size_t)(seg*16 + rr))*ldk + k0 + sl*8;
        gload_lds16(src, lds + seg*512);
    }
}
__device__ __forceinline__ bf16x8 frag64(const ushort_t* lds, int row, int kc8){
    return *(const bf16x8*)&lds[row*64 + ((kc8 ^ (row & 7)) << 3)];
}
__device__ __forceinline__ bf16x8 frag32(const ushort_t* lds, int row, int fq){
    return *(const bf16x8*)&lds[row*32 + ((fq ^ ((row >> 1) & 3)) << 3)];
}

// ---------- weight split: hi/lo bf16 planes ----------
__global__ __launch_bounds__(256)
void split_kernel(const float* __restrict__ src, ushort_t* __restrict__ hi,
                  ushort_t* __restrict__ lo, int n)
{
    int i = blockIdx.x*256 + threadIdx.x;
    if (i < n){
        float v = src[i];
        ushort_t h = f2bf(v);
        hi[i] = h;
        lo[i] = f2bf(v - bf2f(h));
    }
}

// ---------- shared epilogue ----------
// EPI: 0=gelu+split(pe)  1=gelu+f32+split(se)  2=scale+split(q)  3=split(k,v)
//      4=f32(integ)      5=LN-fold f32(fs)
template<int EPI>
__device__ __forceinline__ void epilogue(f32x4 (&acc)[4][4], int bm, int bn,
    int wr, int wc, int fr, int fq,
    const float* bias, float* cf32, ushort_t* chi, ushort_t* clo,
    const float* rowm, const float* rowr, const float* wsump)
{
    #pragma unroll
    for (int i=0;i<4;++i){
        #pragma unroll
        for (int j=0;j<4;++j){
            const int col = bn + wc*64 + j*16 + fr;
            #pragma unroll
            for (int r=0;r<4;++r){
                const int row = bm + wr*64 + i*16 + fq*4 + r;
                float x = acc[i][j][r];
                if (EPI == 5){
                    x = rowr[row]*(x - rowm[row]*wsump[col]) + bias[col];
                    cf32[(size_t)row*D_ + col] = x;
                } else {
                    x += bias[col];
                    if (EPI <= 1) x = gelu_tanh(x);
                    if (EPI == 2) x *= 0.17677669529663687f;
                    if (EPI == 1 || EPI == 4) cf32[(size_t)row*D_ + col] = x;
                    if (EPI != 4){
                        ushort_t hv = f2bf(x);
                        chi[(size_t)row*D_ + col] = hv;
                        clo[(size_t)row*D_ + col] = f2bf(x - bf2f(hv));
                    }
                }
            }
        }
    }
}

// ---------- plane-plane split GEMM (A,B bf16 hi/lo planes, K'=3K, BK=64) ----------
template<int KCH, int EPI>
__global__ __launch_bounds__(256)
void gemm_pp(const ushort_t* __restrict__ Ahi, const ushort_t* __restrict__ Alo,
             const ushort_t* __restrict__ Bhi, const ushort_t* __restrict__ Blo,
             const float* __restrict__ bias, float* __restrict__ cf32,
             ushort_t* __restrict__ chi, ushort_t* __restrict__ clo)
{
    __shared__ ushort_t As[128*64], Bs[128*64];
    const int bm = blockIdx.x*128, bn = blockIdx.y*128;
    const int t = threadIdx.x, lane = t & 63, wid = t >> 6;
    const int wr = wid >> 1, wc = wid & 1, fr = lane & 15, fq = lane >> 4;

    f32x4 acc[4][4];
    #pragma unroll
    for (int i=0;i<4;++i)
        #pragma unroll
        for (int j=0;j<4;++j) acc[i][j] = (f32x4){0.f,0.f,0.f,0.f};

    for (int s = 0; s < 3*KCH; ++s){
        const int term = s / KCH;
        const int kc   = s - term*KCH;
        const ushort_t* Ap = (term == 1) ? Alo : Ahi;
        const ushort_t* Bp = (term == 2) ? Blo : Bhi;
        stage64(Ap, bm, 256, kc*64, As, t);
        stage64(Bp, bn, 256, kc*64, Bs, t);
        __syncthreads();
        #pragma unroll
        for (int ks=0; ks<64; ks+=32){
            bf16x8 a[4], b[4];
            #pragma unroll
            for (int i=0;i<4;++i){
                a[i] = frag64(As, wr*64 + i*16 + fr, (ks>>3) + fq);
                b[i] = frag64(Bs, wc*64 + i*16 + fr, (ks>>3) + fq);
            }
            #pragma unroll
            for (int i=0;i<4;++i)
                #pragma unroll
                for (int j=0;j<4;++j)
                    acc[i][j] = __builtin_amdgcn_mfma_f32_16x16x32_bf16(a[i], b[j], acc[i][j], 0,0,0);
        }
        __syncthreads();
    }
    epilogue<EPI>(acc, bm, bn, wr, wc, fr, fq, bias, cf32, chi, clo, nullptr, nullptr, nullptr);
}

// ---------- f32-A convert GEMM (A f32 -> bf16 hi[/lo] in regs, B planes, BK=32) ----------
// A source: chunks [0,KCH1) from A1 (stride lda1), [KCH1,KCH) from A2 (stride 256)
template<int KCH, int KCH1, int NTERM, int EPI>
__global__ __launch_bounds__(256)
void gemm_cvt(const float* __restrict__ A1, const float* __restrict__ A2, int lda1,
              const ushort_t* __restrict__ Bhi, const ushort_t* __restrict__ Blo, int ldb,
              const float* __restrict__ bias, float* __restrict__ cf32,
              ushort_t* __restrict__ chi, ushort_t* __restrict__ clo,
              const float* __restrict__ rowm, const float* __restrict__ rowr,
              const float* __restrict__ wsump)
{
    __shared__ ushort_t Ah[128*32], Bh[128*32];
    __shared__ ushort_t Al[(NTERM==3)?128*32:8], Bl[(NTERM==3)?128*32:8];
    const int bm = blockIdx.x*128, bn = blockIdx.y*128;
    const int t = threadIdx.x, lane = t & 63, wid = t >> 6;
    const int wr = wid >> 1, wc = wid & 1, fr = lane & 15, fq = lane >> 4;
    const int row2 = t >> 1, half = t & 1;

    f32x4 acc[4][4];
    #pragma unroll
    for (int i=0;i<4;++i)
        #pragma unroll
        for (int j=0;j<4;++j) acc[i][j] = (f32x4){0.f,0.f,0.f,0.f};

    for (int kc = 0; kc < KCH; ++kc){
        // ---- A convert-stage (16 f32 per thread) ----
        const float* ap;
        if (kc < KCH1) ap = A1 + (size_t)(bm + row2)*lda1 + kc*32 + half*16;
        else           ap = A2 + (size_t)(bm + row2)*256  + (kc - KCH1)*32 + half*16;
        float4 va = *(const float4*)(ap);
        float4 vb = *(const float4*)(ap + 4);
        float4 vc = *(const float4*)(ap + 8);
        float4 vd = *(const float4*)(ap + 12);
        float f[16] = {va.x,va.y,va.z,va.w, vb.x,vb.y,vb.z,vb.w,
                       vc.x,vc.y,vc.z,vc.w, vd.x,vd.y,vd.z,vd.w};
        us8 h0, h1, l0, l1;
        #pragma unroll
        for (int j=0;j<8;++j){
            ushort_t hv = f2bf(f[j]);     h0[j] = hv;
            ushort_t hw = f2bf(f[8+j]);   h1[j] = hw;
            if (NTERM == 3){
                l0[j] = f2bf(f[j]   - bf2f(hv));
                l1[j] = f2bf(f[8+j] - bf2f(hw));
            }
        }
        const int sz = (row2 >> 1) & 3;
        const int s0 = (half*2) ^ sz, s1 = (half*2 + 1) ^ sz;
        *(us8*)&Ah[row2*32 + s0*8] = h0;
        *(us8*)&Ah[row2*32 + s1*8] = h1;
        if (NTERM == 3){
            *(us8*)&Al[row2*32 + s0*8] = l0;
            *(us8*)&Al[row2*32 + s1*8] = l1;
        }
        // ---- B stage ----
        stage32(Bhi, bn, ldb, kc*32, Bh, t);
        if (NTERM == 3) stage32(Blo, bn, ldb, kc*32, Bl, t);
        __syncthreads();
        #pragma unroll
        for (int term=0; term<NTERM; ++term){
            const ushort_t* At = (term == 1) ? Al : Ah;
            const ushort_t* Bt = (term == 2) ? Bl : Bh;
            bf16x8 a[4], b[4];
            #pragma unroll
            for (int i=0;i<4;++i){
                a[i] = frag32(At, wr*64 + i*16 + fr, fq);
                b[i] = frag32(Bt, wc*64 + i*16 + fr, fq);
            }
            #pragma unroll
            for (int i=0;i<4;++i)
                #pragma unroll
                for (int j=0;j<4;++j)
                    acc[i][j] = __builtin_amdgcn_mfma_f32_16x16x32_bf16(a[i], b[j], acc[i][j], 0,0,0);
        }
        __syncthreads();
    }
    epilogue<EPI>(acc, bm, bn, wr, wc, fr, fq, bias, cf32, chi, clo, rowm, rowr, wsump);
}

// ---------- per-row LN stats of concat(h,integ) ----------
__global__ __launch_bounds__(256)
void rowstats_kernel(const float* __restrict__ h, const float* __restrict__ integ,
                     float* __restrict__ rowm, float* __restrict__ rowr)
{
    const int r = blockIdx.x;
    const int t = threadIdx.x;
    float s = 0.f, s2 = 0.f;
    for (int c = t; c < CAT; c += 256){
        float x = (c < IN_) ? h[(size_t)r*IN_ + c] : integ[(size_t)r*D_ + c - IN_];
        s += x; s2 += x*x;
    }
    #pragma unroll
    for (int off=32; off>0; off>>=1){ s += __shfl_down(s, off); s2 += __shfl_down(s2, off); }
    __shared__ float ss[4], ss2[4];
    int w = t >> 6;
    if ((t & 63) == 0){ ss[w]=s; ss2[w]=s2; }
    __syncthreads();
    if (t == 0){
        float S = ss[0]+ss[1]+ss[2]+ss[3];
        float S2 = ss2[0]+ss2[1]+ss2[2]+ss2[3];
        float m = S * (1.0f/CAT);
        float v = S2 * (1.0f/CAT) - m*m;
        rowm[r] = m;
        rowr[r] = rsqrtf(v + 1e-5f);
    }
}

__global__ __launch_bounds__(256)
void wsum_kernel(const float* __restrict__ Wfs, float* __restrict__ wsum)
{
    int d = threadIdx.x;
    const float* w = Wfs + (size_t)d*CAT;
    float s = 0.f;
    for (int c=0;c<CAT;++c) s += w[c];
    wsum[d] = s;
}

// ---------- MFMA attention (split-bf16 planes in, planes out) ----------
#define KROWS 208
#define KLD   40
#define VLD   232

__global__ __launch_bounds__(256)
void attn_mfma(const ushort_t* __restrict__ qhi, const ushort_t* __restrict__ qlo,
               const ushort_t* __restrict__ khi, const ushort_t* __restrict__ klo,
               const ushort_t* __restrict__ vhi, const ushort_t* __restrict__ vlo,
               ushort_t* __restrict__ aohi, ushort_t* __restrict__ aolo)
{
    __shared__ ushort_t Khi[KROWS*KLD], Klo[KROWS*KLD];
    __shared__ ushort_t Vthi[32*VLD], Vtlo[32*VLD];

    const int b = blockIdx.x, hh = blockIdx.y;
    const int t = threadIdx.x;
    const int lane = t & 63;
    const int wid  = t >> 6;
    const int fr = lane & 15;
    const int fq = lane >> 4;
    const size_t bbase = (size_t)b*N_*D_ + hh*HD_;

    // stage K (plane copy)
    for (int idx = t; idx < KROWS*4; idx += 256){
        int row = idx >> 2, c8 = (idx & 3) << 3;
        us8 vh, vl;
        if (row < N_){
            vh = *(const us8*)(khi + bbase + (size_t)row*D_ + c8);
            vl = *(const us8*)(klo + bbase + (size_t)row*D_ + c8);
        } else {
            #pragma unroll
            for (int j=0;j<8;++j){ vh[j]=0; vl[j]=0; }
        }
        *(us8*)&Khi[row*KLD + c8] = vh;
        *(us8*)&Klo[row*KLD + c8] = vl;
    }
    // stage V^T with key->slot permutation (keys padded to 224 slots)
    for (int idx = t; idx < 224*4; idx += 256){
        int key = idx >> 2, c8 = (idx & 3) << 3;
        us8 vh, vl;
        if (key < N_){
            vh = *(const us8*)(vhi + bbase + (size_t)key*D_ + c8);
            vl = *(const us8*)(vlo + bbase + (size_t)key*D_ + c8);
        } else {
            #pragma unroll
            for (int j=0;j<8;++j){ vh[j]=0; vl[j]=0; }
        }
        int w = key & 31, cc = key >> 5;
        int slot;
        if (w < 16) slot = cc*32 + (w>>2)*8 + (w&3);
        else { int w2 = w-16; slot = cc*32 + (w2>>2)*8 + 4 + (w2&3); }
        #pragma unroll
        for (int j=0;j<8;++j){
            int dim = c8 + j;
            Vthi[dim*VLD + slot] = vh[j];
            Vtlo[dim*VLD + slot] = vl[j];
        }
    }
    __syncthreads();

    for (int qt = wid; qt < 13; qt += 4){
        int qrow = qt*16 + fr; if (qrow > N_-1) qrow = N_-1;
        const bf16x8 qh = *(const bf16x8*)(qhi + bbase + (size_t)qrow*D_ + fq*8);
        const bf16x8 ql = *(const bf16x8*)(qlo + bbase + (size_t)qrow*D_ + fq*8);

        f32x4 s[13];
        #pragma unroll
        for (int kt=0; kt<13; ++kt) s[kt] = (f32x4){0.f,0.f,0.f,0.f};
        #pragma unroll
        for (int kt=0; kt<13; ++kt){
            const bf16x8 kh = *(const bf16x8*)&Khi[(kt*16 + fr)*KLD + fq*8];
            const bf16x8 kl = *(const bf16x8*)&Klo[(kt*16 + fr)*KLD + fq*8];
            s[kt] = __builtin_amdgcn_mfma_f32_16x16x32_bf16(kh, qh, s[kt], 0,0,0);
            s[kt] = __builtin_amdgcn_mfma_f32_16x16x32_bf16(kh, ql, s[kt], 0,0,0);
            s[kt] = __builtin_amdgcn_mfma_f32_16x16x32_bf16(kl, qh, s[kt], 0,0,0);
        }
        if (fq > 0) s[12] = (f32x4){-1e30f,-1e30f,-1e30f,-1e30f};

        float m = -3.4e38f;
        #pragma unroll
        for (int kt=0; kt<13; ++kt)
            #pragma unroll
            for (int r=0;r<4;++r) m = fmaxf(m, s[kt][r]);
        m = fmaxf(m, __shfl_xor(m, 16));
        m = fmaxf(m, __shfl_xor(m, 32));
        float sum = 0.f;
        #pragma unroll
        for (int kt=0; kt<13; ++kt)
            #pragma unroll
            for (int r=0;r<4;++r){
                float p = __expf(s[kt][r] - m);
                s[kt][r] = p; sum += p;
            }
        sum += __shfl_xor(sum, 16);
        sum += __shfl_xor(sum, 32);
        const float inv = 1.0f / sum;

        f32x4 o0 = (f32x4){0.f,0.f,0.f,0.f};
        f32x4 o1 = (f32x4){0.f,0.f,0.f,0.f};
        #pragma unroll
        for (int c=0;c<7;++c){
            float pv[8];
            #pragma unroll
            for (int r=0;r<4;++r){
                pv[r]   = s[2*c][r];
                pv[4+r] = (c < 6) ? s[2*c+1][r] : 0.f;
            }
            bf16x8 ph, pl; split8(pv, ph, pl);
            const int coff = c*32 + fq*8;
            const bf16x8 v0h = *(const bf16x8*)&Vthi[(fr)*VLD + coff];
            const bf16x8 v0l = *(const bf16x8*)&Vtlo[(fr)*VLD + coff];
            const bf16x8 v1h = *(const bf16x8*)&Vthi[(16+fr)*VLD + coff];
            const bf16x8 v1l = *(const bf16x8*)&Vtlo[(16+fr)*VLD + coff];
            o0 = __builtin_amdgcn_mfma_f32_16x16x32_bf16(v0h, ph, o0, 0,0,0);
            o0 = __builtin_amdgcn_mfma_f32_16x16x32_bf16(v0h, pl, o0, 0,0,0);
            o0 = __builtin_amdgcn_mfma_f32_16x16x32_bf16(v0l, ph, o0, 0,0,0);
            o1 = __builtin_amdgcn_mfma_f32_16x16x32_bf16(v1h, ph, o1, 0,0,0);
            o1 = __builtin_amdgcn_mfma_f32_16x16x32_bf16(v1h, pl, o1, 0,0,0);
            o1 = __builtin_amdgcn_mfma_f32_16x16x32_bf16(v1l, ph, o1, 0,0,0);
        }
        int tok = qt*16 + fr;
        if (tok < N_){
            const size_t obase = bbase + (size_t)tok*D_;
            #pragma unroll
            for (int r=0;r<4;++r){
                float x0 = o0[r]*inv;
                float x1 = o1[r]*inv;
                ushort_t h0 = f2bf(x0), h1 = f2bf(x1);
                aohi[obase + fq*4 + r]      = h0;
                aolo[obase + fq*4 + r]      = f2bf(x0 - bf2f(h0));
                aohi[obase + 16 + fq*4 + r] = h1;
                aolo[obase + 16 + fq*4 + r] = f2bf(x1 - bf2f(h1));
            }
        }
    }
}

// ---------- Abar[b,c] = mean_n rowr*concat ; mbar[b] = mean_n rowr*rowm ----------
__global__ __launch_bounds__(256)
void abar_kernel(const float* __restrict__ h, const float* __restrict__ integ,
                 const float* __restrict__ rowr, const float* __restrict__ rowm,
                 float* __restrict__ Abar, float* __restrict__ mbar)
{
    const int b = blockIdx.x, t = threadIdx.x;
    float acc[5] = {0.f,0.f,0.f,0.f,0.f};
    const float* hb = h + (size_t)b*N_*IN_;
    const float* ib = integ + (size_t)b*N_*D_;
    const float* rr = rowr + b*N_;
    for (int n=0;n<N_;++n){
        float s = rr[n];
        #pragma unroll
        for (int j=0;j<4;++j) acc[j] += s * hb[(size_t)n*IN_ + t + j*256];
        acc[4] += s * ib[(size_t)n*D_ + t];
    }
    #pragma unroll
    for (int j=0;j<4;++j) Abar[(size_t)b*CAT + t + j*256] = acc[j] * (1.f/N_);
    Abar[(size_t)b*CAT + IN_ + t] = acc[4] * (1.f/N_);
    if (t==0){
        float m=0.f; const float* rm = rowm + b*N_;
        for (int n=0;n<N_;++n) m += rr[n]*rm[n];
        mbar[b] = m*(1.f/N_);
    }
}

// ---------- pooled[b,d] = Abar[b]·Wfs[d] - mbar[b]*wsum[d] + bfs[d]  (f32 exact) ----------
__global__ __launch_bounds__(256)
void pooled_kernel(const float* __restrict__ Abar, const float* __restrict__ mbar,
                   const float* __restrict__ Wfs, const float* __restrict__ wsum,
                   const float* __restrict__ bfs, float* __restrict__ pooled)
{
    const int b = blockIdx.x, d = threadIdx.x;
    __shared__ float ab[CAT];
    for (int c=d;c<CAT;c+=256) ab[c] = Abar[(size_t)b*CAT + c];
    __syncthreads();
    const float* w = Wfs + (size_t)d*CAT;
    float s = 0.f;
    for (int c=0;c<CAT;c+=4){
        float4 wv = *(const float4*)(w+c);
        s += ab[c]*wv.x + ab[c+1]*wv.y + ab[c+2]*wv.z + ab[c+3]*wv.w;
    }
    pooled[b*D_ + d] = s - mbar[b]*wsum[d] + bfs[d];
}

// ---------- mean over tokens ----------
__global__ __launch_bounds__(256)
void mean_tokens(const float* __restrict__ src, float* __restrict__ dst)
{
    int b = blockIdx.x, d = threadIdx.x;
    const float* p = src + (size_t)b*N_*D_ + d;
    float s = 0.f;
    for (int n=0;n<N_;++n) s += p[(size_t)n*D_];
    dst[b*D_ + d] = s * (1.0f/N_);
}

// ---------- parent logits + routing ----------
__global__ __launch_bounds__(256)
void parent_kernel(const float* __restrict__ pooled, const float* __restrict__ Wpc,
                   const float* __restrict__ bpc, float* __restrict__ out, int* __restrict__ yhat)
{
    const int b = blockIdx.x, t = threadIdx.x;
    __shared__ __align__(16) float pl[D_];
    __shared__ float lg[NC_];
    pl[t] = pooled[b*D_ + t];
    __syncthreads();
    for (int c = t; c < NC_; c += 256){
        const float* w = Wpc + (size_t)c*D_;
        float s = 0.f;
        #pragma unroll 8
        for (int j=0;j<D_;++j) s += pl[j]*w[j];
        lg[c] = s + bpc[c];
    }
    __syncthreads();
    float s=0.f, s2=0.f, bmv=-3.4e38f; int bidx=0;
    for (int c=t;c<NC_;c+=256){
        float x = lg[c]; s += x; s2 += x*x;
        if (x > bmv){ bmv=x; bidx=c; }
    }
    #pragma unroll
    for (int off=32; off>0; off>>=1){
        s  += __shfl_down(s, off);
        s2 += __shfl_down(s2, off);
        float ov = __shfl_down(bmv, off); int oi = __shfl_down(bidx, off);
        if (ov > bmv || (ov == bmv && oi < bidx)){ bmv=ov; bidx=oi; }
    }
    __shared__ float rs[4], rs2[4], rmv[4]; __shared__ int ri[4];
    __shared__ float fm, fr_;
    int w = t >> 6;
    if ((t & 63) == 0){ rs[w]=s; rs2[w]=s2; rmv[w]=bmv; ri[w]=bidx; }
    __syncthreads();
    if (t == 0){
        float S=0.f, S2=0.f, mv=-3.4e38f; int mi=0;
        for (int i=0;i<4;++i){
            S += rs[i]; S2 += rs2[i];
            if (rmv[i] > mv || (rmv[i] == mv && ri[i] < mi)){ mv=rmv[i]; mi=ri[i]; }
        }
        float mean = S*(1.0f/NC_);
        float var  = S2*(1.0f/NC_) - mean*mean;
        fm = mean; fr_ = rsqrtf(var + 1e-5f);
        yhat[b] = mi;
    }
    __syncthreads();
    for (int c=t;c<NC_;c+=256) out[(size_t)b*NC_ + c] = (lg[c]-fm)*fr_;
}

// ---------- routed child classifiers ----------
__global__ __launch_bounds__(64)
void child_kernel(const float* __restrict__ sp, const int* __restrict__ yhat,
                  const float* __restrict__ Wc0, const float* __restrict__ bc0,
                  const float* __restrict__ Wc1, const float* __restrict__ bc1,
                  float* __restrict__ out_c0, float* __restrict__ out_c1)
{
    const int b = blockIdx.x, t = threadIdx.x;
    __shared__ float spl[D_];
    for (int i=t;i<D_;i+=64) spl[i] = sp[b*D_ + i];
    __syncthreads();
    const int y = yhat[b];
    __shared__ float c0v[S0_], c1v[S1_];
    if (t < S0_){
        const float* w = Wc0 + (size_t)y*D_*S0_ + t;
        float s = 0.f;
        for (int d=0;d<D_;++d) s += spl[d]*w[(size_t)d*S0_];
        c0v[t] = s + bc0[y*S0_ + t];
    } else if (t < S0_+S1_){
        int k = t - S0_;
        const float* w = Wc1 + (size_t)y*D_*S1_ + k;
        float s = 0.f;
        for (int d=0;d<D_;++d) s += spl[d]*w[(size_t)d*S1_];
        c1v[k] = s + bc1[y*S1_ + k];
    }
    __syncthreads();
    __shared__ float st[4];
    if (t == 0){
        float m=0.f; for (int i=0;i<S0_;++i) m += c0v[i]; m *= (1.0f/S0_);
        float v=0.f; for (int i=0;i<S0_;++i){ float d=c0v[i]-m; v += d*d; } v *= (1.0f/S0_);
        st[0]=m; st[1]=rsqrtf(v+1e-5f);
        m=0.f; for (int i=0;i<S1_;++i) m += c1v[i]; m *= (1.0f/S1_);
        v=0.f; for (int i=0;i<S1_;++i){ float d=c1v[i]-m; v += d*d; } v *= (1.0f/S1_);
        st[2]=m; st[3]=rsqrtf(v+1e-5f);
    }
    __syncthreads();
    if (t < S0_) out_c0[b*S0_ + t] = (c0v[t]-st[0])*st[1];
    else if (t < S0_+S1_) out_c1[b*S1_ + (t-S0_)] = (c1v[t-S0_]-st[2])*st[3];
}

extern "C" void kernel_launch(void* const* d_in, const int* in_sizes, int n_in,
                              void* d_out, int out_size, void* d_ws, size_t ws_size,
                              hipStream_t stream)
{
    const float* h   = (const float*)d_in[0];
    const float* Wp  = (const float*)d_in[1];
    const float* bp  = (const float*)d_in[2];
    const float* Wsub= (const float*)d_in[3];
    const float* bs  = (const float*)d_in[4];
    const float* Wq  = (const float*)d_in[5];
    const float* bq  = (const float*)d_in[6];
    const float* Wk  = (const float*)d_in[7];
    const float* bk  = (const float*)d_in[8];
    const float* Wv  = (const float*)d_in[9];
    const float* bv  = (const float*)d_in[10];
    const float* Wo  = (const float*)d_in[11];
    const float* bo  = (const float*)d_in[12];
    const float* Wfs = (const float*)d_in[13];
    const float* bfs = (const float*)d_in[14];
    const float* Wpc = (const float*)d_in[15];
    const float* bpc = (const float*)d_in[16];
    const float* Wc0 = (const float*)d_in[17];
    const float* bc0 = (const float*)d_in[18];
    const float* Wc1 = (const float*)d_in[19];
    const float* bc1 = (const float*)d_in[20];

    float* out = (float*)d_out;
    float* out_pl = out;                         // [256,1000]
    float* out_c0 = out + 256000;                // [256,10]
    float* out_c1 = out + 258560;                // [256,20]
    float* out_fs = out + 263680;                // [256,196,256]
    float* out_se = out + 13108736;              // [256,196,256]

    // ---- workspace: 8 bf16 plane units (12.85M ushorts each) + misc + weight planes ----
    ushort_t* U = (ushort_t*)d_ws;
    const size_t UN = (size_t)ROWS * D_;         // 12,845,056
    ushort_t* U0 = U + 0*UN;   // pe_hi  -> k_hi
    ushort_t* U1 = U + 1*UN;   // pe_lo  -> k_lo
    ushort_t* U2 = U + 2*UN;   // se_hi  -> ao_hi
    ushort_t* U3 = U + 3*UN;   // se_lo  -> ao_lo
    ushort_t* U4 = U + 4*UN;   // q_hi   -> integ f32 (spans U4+U5)
    ushort_t* U5 = U + 5*UN;   // q_lo
    ushort_t* U6 = U + 6*UN;   // v_hi
    ushort_t* U7 = U + 7*UN;   // v_lo
    float* integ = (float*)U4;                   // after attention

    float* fmisc = (float*)(U + 8*UN);
    float* rowm = fmisc;                         // 50176
    float* rowr = rowm + ROWS;                   // 50176
    float* wsmb = rowr + ROWS;                   // 256
    float* pooled = wsmb + D_;                   // 65536
    float* sp   = pooled + (size_t)B_*D_;        // 65536
    float* mbar = sp + (size_t)B_*D_;            // 256
    float* Abar = mbar + 256;                    // 327680
    int*   yhat = (int*)(Abar + (size_t)B_*CAT); // 256
    ushort_t* wp = (ushort_t*)(yhat + 512);
    ushort_t* WpH = wp;               ushort_t* WpL = WpH + 262144;
    ushort_t* WsH = WpL + 262144;     ushort_t* WsL = WsH + 262144;
    ushort_t* WqH = WsL + 262144;     ushort_t* WqL = WqH + 65536;
    ushort_t* WkH = WqL + 65536;      ushort_t* WkL = WkH + 65536;
    ushort_t* WvH = WkL + 65536;      ushort_t* WvL = WvH + 65536;
    ushort_t* WoH = WvL + 65536;      ushort_t* WoL = WoH + 65536;
    ushort_t* WfsH = WoL + 65536;     ushort_t* WfsL = WfsH + 327680;

    // split weights to bf16 hi/lo planes
    split_kernel<<<1024, 256, 0, stream>>>(Wp,   WpH,  WpL,  262144);
    split_kernel<<<1024, 256, 0, stream>>>(Wsub, WsH,  WsL,  262144);
    split_kernel<<<256,  256, 0, stream>>>(Wq,   WqH,  WqL,  65536);
    split_kernel<<<256,  256, 0, stream>>>(Wk,   WkH,  WkL,  65536);
    split_kernel<<<256,  256, 0, stream>>>(Wv,   WvH,  WvL,  65536);
    split_kernel<<<256,  256, 0, stream>>>(Wo,   WoH,  WoL,  65536);
    split_kernel<<<1280, 256, 0, stream>>>(Wfs,  WfsH, WfsL, 327680);

    dim3 g(ROWS/128, 2);
    // pe = gelu(h@Wp^T+bp) -> planes U0,U1
    gemm_cvt<32,32,3,0><<<g,256,0,stream>>>(h, h, IN_, WpH, WpL, IN_, bp,
                                            nullptr, U0, U1, nullptr, nullptr, nullptr);
    // se = gelu(h@Ws^T+bs) -> out_se f32 + planes U2,U3
    gemm_cvt<32,32,3,1><<<g,256,0,stream>>>(h, h, IN_, WsH, WsL, IN_, bs,
                                            out_se, U2, U3, nullptr, nullptr, nullptr);
    // q = (pe@Wq^T+bq)*scale -> planes U4,U5
    gemm_pp<4,2><<<g,256,0,stream>>>(U0, U1, WqH, WqL, bq, nullptr, U4, U5);
    // k = se@Wk^T+bk -> planes U0,U1 (pe dead)
    gemm_pp<4,3><<<g,256,0,stream>>>(U2, U3, WkH, WkL, bk, nullptr, U0, U1);
    // v = se@Wv^T+bv -> planes U6,U7
    gemm_pp<4,3><<<g,256,0,stream>>>(U2, U3, WvH, WvL, bv, nullptr, U6, U7);
    // attention -> ao planes U2,U3 (se planes dead)
    attn_mfma<<<dim3(B_, H_), 256, 0, stream>>>(U4, U5, U0, U1, U6, U7, U2, U3);
    // integ = ao@Wo^T+bo -> f32 @ U4/U5 (q dead)
    gemm_pp<4,4><<<g,256,0,stream>>>(U2, U3, WoH, WoL, bo, integ, nullptr, nullptr);
    // LN stats + colsum(Wfs)
    rowstats_kernel<<<ROWS, 256, 0, stream>>>(h, integ, rowm, rowr);
    wsum_kernel<<<1, 256, 0, stream>>>(Wfs, wsmb);
    // fs (plain bf16, LN folded) -> out_fs
    gemm_cvt<40,32,1,5><<<g,256,0,stream>>>(h, integ, IN_, WfsH, WfsH, CAT, bfs,
                                            out_fs, nullptr, nullptr, rowm, rowr, wsmb);
    // exact f32 pooled via Abar identity
    abar_kernel<<<B_, 256, 0, stream>>>(h, integ, rowr, rowm, Abar, mbar);
    pooled_kernel<<<B_, 256, 0, stream>>>(Abar, mbar, Wfs, wsmb, bfs, pooled);
    // sp from se
    mean_tokens<<<B_, 256, 0, stream>>>(out_se, sp);
    // parent logits + routing
    parent_kernel<<<B_, 256, 0, stream>>>(pooled, Wpc, bpc, out_pl, yhat);
    // routed child classifiers
    child_kernel<<<B_, 64, 0, stream>>>(sp, yhat, Wc0, bc0, Wc1, bc1, out_c0, out_c1);
}

// Round 5
// 916.887 us; speedup vs baseline: 2.5071x; 1.1233x over previous
//
#include <hip/hip_runtime.h>
#include <hip/hip_bf16.h>
#include <math.h>

// Problem dims
#define B_   256
#define N_   196
#define IN_  1024
#define D_   256
#define H_   8
#define HD_  32
#define NC_  1000
#define S0_  10
#define S1_  20
#define ROWS (B_*N_)      // 50176
#define CAT  (IN_+D_)     // 1280

typedef unsigned short ushort_t;
typedef short bf16x8 __attribute__((ext_vector_type(8)));
typedef float f32x4  __attribute__((ext_vector_type(4)));
typedef ushort_t us4 __attribute__((ext_vector_type(4)));
typedef ushort_t us8 __attribute__((ext_vector_type(8)));

// native converts: compiler packs pairs into v_cvt_pk_bf16_f32
__device__ __forceinline__ ushort_t f2bf(float f){
    __hip_bfloat16 b = __float2bfloat16(f);
    ushort_t u; __builtin_memcpy(&u, &b, 2); return u;
}
__device__ __forceinline__ float bf2f(ushort_t h){
    union { unsigned int u; float f; } x; x.u = ((unsigned int)h) << 16;
    return x.f;
}
__device__ __forceinline__ float gelu_tanh(float x){
    float x3 = x*x*x;
    float inner = 0.7978845608028654f*(x + 0.044715f*x3);
    return 0.5f*x*(1.0f + tanhf(inner));
}
__device__ __forceinline__ void split8(const float* f, bf16x8& hi, bf16x8& lo){
    #pragma unroll
    for (int j=0;j<8;++j){
        ushort_t h = f2bf(f[j]);
        hi[j] = (short)h;
        lo[j] = (short)f2bf(f[j] - bf2f(h));
    }
}

// ---------- async global->LDS, 16B per lane ----------
typedef __attribute__((address_space(1))) const unsigned int gu32;
typedef __attribute__((address_space(3))) unsigned int lu32;
__device__ __forceinline__ void gload_lds16(const void* g, void* l){
    __builtin_amdgcn_global_load_lds((gu32*)g, (lu32*)l, 16, 0, 0);
}

// stage a 128x32-ushort tile (8KB), linear LDS dest, inverse-swizzled source.
// swizzle: LDS(row, slot') holds global (row, slot' ^ ((row>>1)&3)); slots = 16B units.
__device__ __forceinline__ void stage32(const ushort_t* P, size_t rowbase, int ldk, int k0,
                                        ushort_t* lds, int t){
    const int w = t >> 6, l = t & 63;
    const int rr = l >> 2;                 // row within 16-row segment
    const int sl = (l & 3) ^ ((l >> 3) & 3);
    #pragma unroll
    for (int j=0;j<2;++j){
        int seg = w*2 + j;                 // 8 segments of 1KB (16 rows)
        const ushort_t* src = P + (rowbase + (size_t)(seg*16 + rr))*ldk + k0 + sl*8;
        gload_lds16(src, lds + seg*512);
    }
}
__device__ __forceinline__ bf16x8 frag32(const ushort_t* lds, int row, int fq){
    return *(const bf16x8*)&lds[row*32 + ((fq ^ ((row >> 1) & 3)) << 3)];
}

// ---------- weight split: hi/lo bf16 planes ----------
__global__ __launch_bounds__(256)
void split_kernel(const float* __restrict__ src, ushort_t* __restrict__ hi,
                  ushort_t* __restrict__ lo, int n)
{
    int i = blockIdx.x*256 + threadIdx.x;
    if (i < n){
        float v = src[i];
        ushort_t h = f2bf(v);
        hi[i] = h;
        lo[i] = f2bf(v - bf2f(h));
    }
}

// ---------- fused pe+se: A=h f32 (reg convert), B=[Wp;Ws] planes, N=512 ----------
// grid (4, 392): bn = blockIdx.x*128, bm = blockIdx.y*128
__global__ __launch_bounds__(256)
void gemm_cvt3(const float* __restrict__ A,
               const ushort_t* __restrict__ BH, const ushort_t* __restrict__ BL,
               const float* __restrict__ bias1, const float* __restrict__ bias2,
               float* __restrict__ seF,
               ushort_t* __restrict__ peH, ushort_t* __restrict__ peL,
               ushort_t* __restrict__ seH, ushort_t* __restrict__ seL)
{
    __shared__ ushort_t Ah[128*32], Al[128*32], Bh[128*32], Bl[128*32];
    const int bn = blockIdx.x*128, bm = blockIdx.y*128;
    const int t = threadIdx.x, lane = t & 63, wid = t >> 6;
    const int wr = wid >> 1, wc = wid & 1, fr = lane & 15, fq = lane >> 4;
    const int row2 = t >> 1, half = t & 1;

    f32x4 acc[4][4];
    #pragma unroll
    for (int i=0;i<4;++i)
        #pragma unroll
        for (int j=0;j<4;++j) acc[i][j] = (f32x4){0.f,0.f,0.f,0.f};

    for (int kc = 0; kc < 32; ++kc){
        const float* ap = A + (size_t)(bm + row2)*IN_ + kc*32 + half*16;
        float4 va = *(const float4*)(ap);
        float4 vb = *(const float4*)(ap + 4);
        float4 vc = *(const float4*)(ap + 8);
        float4 vd = *(const float4*)(ap + 12);
        float f[16] = {va.x,va.y,va.z,va.w, vb.x,vb.y,vb.z,vb.w,
                       vc.x,vc.y,vc.z,vc.w, vd.x,vd.y,vd.z,vd.w};
        us8 h0, h1, l0, l1;
        #pragma unroll
        for (int j=0;j<8;++j){
            ushort_t hv = f2bf(f[j]);     h0[j] = hv;
            ushort_t hw = f2bf(f[8+j]);   h1[j] = hw;
            l0[j] = f2bf(f[j]   - bf2f(hv));
            l1[j] = f2bf(f[8+j] - bf2f(hw));
        }
        const int sz = (row2 >> 1) & 3;
        const int s0 = (half*2) ^ sz, s1 = (half*2 + 1) ^ sz;
        *(us8*)&Ah[row2*32 + s0*8] = h0;
        *(us8*)&Ah[row2*32 + s1*8] = h1;
        *(us8*)&Al[row2*32 + s0*8] = l0;
        *(us8*)&Al[row2*32 + s1*8] = l1;
        stage32(BH, bn, IN_, kc*32, Bh, t);
        stage32(BL, bn, IN_, kc*32, Bl, t);
        __syncthreads();
        #pragma unroll
        for (int term=0; term<3; ++term){
            const ushort_t* At = (term == 1) ? Al : Ah;
            const ushort_t* Bt = (term == 2) ? Bl : Bh;
            bf16x8 a[4], b[4];
            #pragma unroll
            for (int i=0;i<4;++i){
                a[i] = frag32(At, wr*64 + i*16 + fr, fq);
                b[i] = frag32(Bt, wc*64 + i*16 + fr, fq);
            }
            #pragma unroll
            for (int i=0;i<4;++i)
                #pragma unroll
                for (int j=0;j<4;++j)
                    acc[i][j] = __builtin_amdgcn_mfma_f32_16x16x32_bf16(a[i], b[j], acc[i][j], 0,0,0);
        }
        __syncthreads();
    }
    #pragma unroll
    for (int i=0;i<4;++i){
        #pragma unroll
        for (int j=0;j<4;++j){
            const int col = bn + wc*64 + j*16 + fr;
            #pragma unroll
            for (int r=0;r<4;++r){
                const int row = bm + wr*64 + i*16 + fq*4 + r;
                if (col < 256){
                    float x = gelu_tanh(acc[i][j][r] + bias1[col]);
                    ushort_t hv = f2bf(x);
                    peH[(size_t)row*D_ + col] = hv;
                    peL[(size_t)row*D_ + col] = f2bf(x - bf2f(hv));
                } else {
                    int c2 = col - 256;
                    float x = gelu_tanh(acc[i][j][r] + bias2[c2]);
                    seF[(size_t)row*D_ + c2] = x;
                    ushort_t hv = f2bf(x);
                    seH[(size_t)row*D_ + c2] = hv;
                    seL[(size_t)row*D_ + c2] = f2bf(x - bf2f(hv));
                }
            }
        }
    }
}

// ---------- 4-plane split GEMM (A,B planes, BK=32 chunks, 3 terms/chunk) ----------
// EPI: 1=q(scale+split->o1)  6=kv(col<256->o1 else o2)  4=integ(f32o)
template<int KCH, int EPI>
__global__ __launch_bounds__(256)
void gemm_4p(const ushort_t* __restrict__ AH, const ushort_t* __restrict__ AL,
             const ushort_t* __restrict__ BH, const ushort_t* __restrict__ BL,
             const float* __restrict__ bias1, const float* __restrict__ bias2,
             float* __restrict__ f32o,
             ushort_t* __restrict__ o1h, ushort_t* __restrict__ o1l,
             ushort_t* __restrict__ o2h, ushort_t* __restrict__ o2l)
{
    __shared__ ushort_t Ah[128*32], Al[128*32], Bh[128*32], Bl[128*32];
    const int bn = blockIdx.x*128, bm = blockIdx.y*128;
    const int t = threadIdx.x, lane = t & 63, wid = t >> 6;
    const int wr = wid >> 1, wc = wid & 1, fr = lane & 15, fq = lane >> 4;

    f32x4 acc[4][4];
    #pragma unroll
    for (int i=0;i<4;++i)
        #pragma unroll
        for (int j=0;j<4;++j) acc[i][j] = (f32x4){0.f,0.f,0.f,0.f};

    for (int kc = 0; kc < KCH; ++kc){
        stage32(AH, bm, 256, kc*32, Ah, t);
        stage32(AL, bm, 256, kc*32, Al, t);
        stage32(BH, bn, 256, kc*32, Bh, t);
        stage32(BL, bn, 256, kc*32, Bl, t);
        __syncthreads();
        #pragma unroll
        for (int term=0; term<3; ++term){
            const ushort_t* At = (term == 1) ? Al : Ah;
            const ushort_t* Bt = (term == 2) ? Bl : Bh;
            bf16x8 a[4], b[4];
            #pragma unroll
            for (int i=0;i<4;++i){
                a[i] = frag32(At, wr*64 + i*16 + fr, fq);
                b[i] = frag32(Bt, wc*64 + i*16 + fr, fq);
            }
            #pragma unroll
            for (int i=0;i<4;++i)
                #pragma unroll
                for (int j=0;j<4;++j)
                    acc[i][j] = __builtin_amdgcn_mfma_f32_16x16x32_bf16(a[i], b[j], acc[i][j], 0,0,0);
        }
        __syncthreads();
    }
    #pragma unroll
    for (int i=0;i<4;++i){
        #pragma unroll
        for (int j=0;j<4;++j){
            const int col = bn + wc*64 + j*16 + fr;
            #pragma unroll
            for (int r=0;r<4;++r){
                const int row = bm + wr*64 + i*16 + fq*4 + r;
                if (EPI == 1){
                    float x = (acc[i][j][r] + bias1[col]) * 0.17677669529663687f;
                    ushort_t hv = f2bf(x);
                    o1h[(size_t)row*D_ + col] = hv;
                    o1l[(size_t)row*D_ + col] = f2bf(x - bf2f(hv));
                } else if (EPI == 6){
                    if (col < 256){
                        float x = acc[i][j][r] + bias1[col];
                        ushort_t hv = f2bf(x);
                        o1h[(size_t)row*D_ + col] = hv;
                        o1l[(size_t)row*D_ + col] = f2bf(x - bf2f(hv));
                    } else {
                        int c2 = col - 256;
                        float x = acc[i][j][r] + bias2[c2];
                        ushort_t hv = f2bf(x);
                        o2h[(size_t)row*D_ + c2] = hv;
                        o2l[(size_t)row*D_ + c2] = f2bf(x - bf2f(hv));
                    }
                } else { // EPI == 4
                    f32o[(size_t)row*D_ + col] = acc[i][j][r] + bias1[col];
                }
            }
        }
    }
}

// ---------- fs GEMM: A=[h f32 | integ f32] convert hi-only, B=WfsH, LN folded ----------
// grid (2, 392)
__global__ __launch_bounds__(256)
void gemm_fs(const float* __restrict__ A1, const float* __restrict__ A2,
             const ushort_t* __restrict__ BH, const float* __restrict__ bias,
             const float* __restrict__ rowm, const float* __restrict__ rowr,
             const float* __restrict__ wsump, float* __restrict__ C)
{
    __shared__ ushort_t Ah[128*32], Bh[128*32];
    const int bn = blockIdx.x*128, bm = blockIdx.y*128;
    const int t = threadIdx.x, lane = t & 63, wid = t >> 6;
    const int wr = wid >> 1, wc = wid & 1, fr = lane & 15, fq = lane >> 4;
    const int row2 = t >> 1, half = t & 1;

    f32x4 acc[4][4];
    #pragma unroll
    for (int i=0;i<4;++i)
        #pragma unroll
        for (int j=0;j<4;++j) acc[i][j] = (f32x4){0.f,0.f,0.f,0.f};

    for (int kc = 0; kc < 40; ++kc){
        const float* ap = (kc < 32) ? A1 + (size_t)(bm + row2)*IN_ + kc*32 + half*16
                                    : A2 + (size_t)(bm + row2)*D_ + (kc-32)*32 + half*16;
        float4 va = *(const float4*)(ap);
        float4 vb = *(const float4*)(ap + 4);
        float4 vc = *(const float4*)(ap + 8);
        float4 vd = *(const float4*)(ap + 12);
        float f[16] = {va.x,va.y,va.z,va.w, vb.x,vb.y,vb.z,vb.w,
                       vc.x,vc.y,vc.z,vc.w, vd.x,vd.y,vd.z,vd.w};
        us8 h0, h1;
        #pragma unroll
        for (int j=0;j<8;++j){ h0[j] = f2bf(f[j]); h1[j] = f2bf(f[8+j]); }
        const int sz = (row2 >> 1) & 3;
        const int s0 = (half*2) ^ sz, s1 = (half*2 + 1) ^ sz;
        *(us8*)&Ah[row2*32 + s0*8] = h0;
        *(us8*)&Ah[row2*32 + s1*8] = h1;
        stage32(BH, bn, CAT, kc*32, Bh, t);
        __syncthreads();
        bf16x8 a[4], b[4];
        #pragma unroll
        for (int i=0;i<4;++i){
            a[i] = frag32(Ah, wr*64 + i*16 + fr, fq);
            b[i] = frag32(Bh, wc*64 + i*16 + fr, fq);
        }
        #pragma unroll
        for (int i=0;i<4;++i)
            #pragma unroll
            for (int j=0;j<4;++j)
                acc[i][j] = __builtin_amdgcn_mfma_f32_16x16x32_bf16(a[i], b[j], acc[i][j], 0,0,0);
        __syncthreads();
    }
    #pragma unroll
    for (int i=0;i<4;++i){
        #pragma unroll
        for (int j=0;j<4;++j){
            const int col = bn + wc*64 + j*16 + fr;
            float ws_ = wsump[col], bb = bias[col];
            #pragma unroll
            for (int r=0;r<4;++r){
                const int row = bm + wr*64 + i*16 + fq*4 + r;
                C[(size_t)row*D_ + col] = rowr[row]*(acc[i][j][r] - rowm[row]*ws_) + bb;
            }
        }
    }
}

// ---------- per-row LN stats of concat(h,integ); one wave per row ----------
__global__ __launch_bounds__(256)
void rowstats_kernel(const float* __restrict__ h, const float* __restrict__ integ,
                     float* __restrict__ rowm, float* __restrict__ rowr)
{
    const int r = blockIdx.x*4 + (threadIdx.x >> 6);
    const int l = threadIdx.x & 63;
    const float* hr = h + (size_t)r*IN_;
    float s = 0.f, s2 = 0.f;
    #pragma unroll
    for (int c0 = 0; c0 < IN_; c0 += 256){
        float4 v = *(const float4*)(hr + c0 + l*4);
        s += v.x+v.y+v.z+v.w;
        s2 += v.x*v.x + v.y*v.y + v.z*v.z + v.w*v.w;
    }
    {
        float4 v = *(const float4*)(integ + (size_t)r*D_ + l*4);
        s += v.x+v.y+v.z+v.w;
        s2 += v.x*v.x + v.y*v.y + v.z*v.z + v.w*v.w;
    }
    #pragma unroll
    for (int off=32; off>0; off>>=1){ s += __shfl_down(s, off); s2 += __shfl_down(s2, off); }
    if (l == 0){
        float m = s * (1.0f/CAT);
        float v = s2 * (1.0f/CAT) - m*m;
        rowm[r] = m;
        rowr[r] = rsqrtf(v + 1e-5f);
    }
}

// ---------- colsum(Wfs): one block per output d ----------
__global__ __launch_bounds__(64)
void wsum_kernel(const float* __restrict__ Wfs, float* __restrict__ wsum)
{
    const int d = blockIdx.x, l = threadIdx.x;
    const float* w = Wfs + (size_t)d*CAT;
    float s = 0.f;
    #pragma unroll
    for (int c0 = 0; c0 < CAT; c0 += 256){
        float4 v = *(const float4*)(w + c0 + l*4);
        s += v.x+v.y+v.z+v.w;
    }
    #pragma unroll
    for (int off=32; off>0; off>>=1) s += __shfl_down(s, off);
    if (l == 0) wsum[d] = s;
}

// ---------- MFMA attention (split-bf16 planes in, planes out) ----------
#define KROWS 208
#define KLD   40
#define VLD   232

__global__ __launch_bounds__(256)
void attn_mfma(const ushort_t* __restrict__ qhi, const ushort_t* __restrict__ qlo,
               const ushort_t* __restrict__ khi, const ushort_t* __restrict__ klo,
               const ushort_t* __restrict__ vhi, const ushort_t* __restrict__ vlo,
               ushort_t* __restrict__ aohi, ushort_t* __restrict__ aolo)
{
    __shared__ ushort_t Khi[KROWS*KLD], Klo[KROWS*KLD];
    __shared__ ushort_t Vthi[32*VLD], Vtlo[32*VLD];

    const int b = blockIdx.x, hh = blockIdx.y;
    const int t = threadIdx.x;
    const int lane = t & 63;
    const int wid  = t >> 6;
    const int fr = lane & 15;
    const int fq = lane >> 4;
    const size_t bbase = (size_t)b*N_*D_ + hh*HD_;

    for (int idx = t; idx < KROWS*4; idx += 256){
        int row = idx >> 2, c8 = (idx & 3) << 3;
        us8 vh, vl;
        if (row < N_){
            vh = *(const us8*)(khi + bbase + (size_t)row*D_ + c8);
            vl = *(const us8*)(klo + bbase + (size_t)row*D_ + c8);
        } else {
            #pragma unroll
            for (int j=0;j<8;++j){ vh[j]=0; vl[j]=0; }
        }
        *(us8*)&Khi[row*KLD + c8] = vh;
        *(us8*)&Klo[row*KLD + c8] = vl;
    }
    for (int idx = t; idx < 224*4; idx += 256){
        int key = idx >> 2, c8 = (idx & 3) << 3;
        us8 vh, vl;
        if (key < N_){
            vh = *(const us8*)(vhi + bbase + (size_t)key*D_ + c8);
            vl = *(const us8*)(vlo + bbase + (size_t)key*D_ + c8);
        } else {
            #pragma unroll
            for (int j=0;j<8;++j){ vh[j]=0; vl[j]=0; }
        }
        int w = key & 31, cc = key >> 5;
        int slot;
        if (w < 16) slot = cc*32 + (w>>2)*8 + (w&3);
        else { int w2 = w-16; slot = cc*32 + (w2>>2)*8 + 4 + (w2&3); }
        #pragma unroll
        for (int j=0;j<8;++j){
            int dim = c8 + j;
            Vthi[dim*VLD + slot] = vh[j];
            Vtlo[dim*VLD + slot] = vl[j];
        }
    }
    __syncthreads();

    for (int qt = wid; qt < 13; qt += 4){
        int qrow = qt*16 + fr; if (qrow > N_-1) qrow = N_-1;
        const bf16x8 qh = *(const bf16x8*)(qhi + bbase + (size_t)qrow*D_ + fq*8);
        const bf16x8 ql = *(const bf16x8*)(qlo + bbase + (size_t)qrow*D_ + fq*8);

        f32x4 s[13];
        #pragma unroll
        for (int kt=0; kt<13; ++kt) s[kt] = (f32x4){0.f,0.f,0.f,0.f};
        #pragma unroll
        for (int kt=0; kt<13; ++kt){
            const bf16x8 kh = *(const bf16x8*)&Khi[(kt*16 + fr)*KLD + fq*8];
            const bf16x8 kl = *(const bf16x8*)&Klo[(kt*16 + fr)*KLD + fq*8];
            s[kt] = __builtin_amdgcn_mfma_f32_16x16x32_bf16(kh, qh, s[kt], 0,0,0);
            s[kt] = __builtin_amdgcn_mfma_f32_16x16x32_bf16(kh, ql, s[kt], 0,0,0);
            s[kt] = __builtin_amdgcn_mfma_f32_16x16x32_bf16(kl, qh, s[kt], 0,0,0);
        }
        if (fq > 0) s[12] = (f32x4){-1e30f,-1e30f,-1e30f,-1e30f};

        float m = -3.4e38f;
        #pragma unroll
        for (int kt=0; kt<13; ++kt)
            #pragma unroll
            for (int r=0;r<4;++r) m = fmaxf(m, s[kt][r]);
        m = fmaxf(m, __shfl_xor(m, 16));
        m = fmaxf(m, __shfl_xor(m, 32));
        float sum = 0.f;
        #pragma unroll
        for (int kt=0; kt<13; ++kt)
            #pragma unroll
            for (int r=0;r<4;++r){
                float p = __expf(s[kt][r] - m);
                s[kt][r] = p; sum += p;
            }
        sum += __shfl_xor(sum, 16);
        sum += __shfl_xor(sum, 32);
        const float inv = 1.0f / sum;

        f32x4 o0 = (f32x4){0.f,0.f,0.f,0.f};
        f32x4 o1 = (f32x4){0.f,0.f,0.f,0.f};
        #pragma unroll
        for (int c=0;c<7;++c){
            float pv[8];
            #pragma unroll
            for (int r=0;r<4;++r){
                pv[r]   = s[2*c][r];
                pv[4+r] = (c < 6) ? s[2*c+1][r] : 0.f;
            }
            bf16x8 ph, pl; split8(pv, ph, pl);
            const int coff = c*32 + fq*8;
            const bf16x8 v0h = *(const bf16x8*)&Vthi[(fr)*VLD + coff];
            const bf16x8 v0l = *(const bf16x8*)&Vtlo[(fr)*VLD + coff];
            const bf16x8 v1h = *(const bf16x8*)&Vthi[(16+fr)*VLD + coff];
            const bf16x8 v1l = *(const bf16x8*)&Vtlo[(16+fr)*VLD + coff];
            o0 = __builtin_amdgcn_mfma_f32_16x16x32_bf16(v0h, ph, o0, 0,0,0);
            o0 = __builtin_amdgcn_mfma_f32_16x16x32_bf16(v0h, pl, o0, 0,0,0);
            o0 = __builtin_amdgcn_mfma_f32_16x16x32_bf16(v0l, ph, o0, 0,0,0);
            o1 = __builtin_amdgcn_mfma_f32_16x16x32_bf16(v1h, ph, o1, 0,0,0);
            o1 = __builtin_amdgcn_mfma_f32_16x16x32_bf16(v1h, pl, o1, 0,0,0);
            o1 = __builtin_amdgcn_mfma_f32_16x16x32_bf16(v1l, ph, o1, 0,0,0);
        }
        int tok = qt*16 + fr;
        if (tok < N_){
            const size_t obase = bbase + (size_t)tok*D_;
            #pragma unroll
            for (int r=0;r<4;++r){
                float x0 = o0[r]*inv;
                float x1 = o1[r]*inv;
                ushort_t h0 = f2bf(x0), h1 = f2bf(x1);
                aohi[obase + fq*4 + r]      = h0;
                aolo[obase + fq*4 + r]      = f2bf(x0 - bf2f(h0));
                aohi[obase + 16 + fq*4 + r] = h1;
                aolo[obase + 16 + fq*4 + r] = f2bf(x1 - bf2f(h1));
            }
        }
    }
}

// ---------- abar: 4-way token split, then reduce ----------
#define APLD 1344
__global__ __launch_bounds__(256)
void abar_part(const float* __restrict__ h, const float* __restrict__ integ,
               const float* __restrict__ rowr, const float* __restrict__ rowm,
               float* __restrict__ Apart)
{
    const int b = blockIdx.x, qq = blockIdx.y, t = threadIdx.x;
    const int n0 = qq*49;
    float acc[5] = {0.f,0.f,0.f,0.f,0.f};
    const float* hb = h + ((size_t)b*N_ + n0)*IN_;
    const float* ib = integ + ((size_t)b*N_ + n0)*D_;
    const float* rr = rowr + b*N_ + n0;
    for (int n=0;n<49;++n){
        float s = rr[n];
        #pragma unroll
        for (int j=0;j<4;++j) acc[j] += s * hb[(size_t)n*IN_ + t + j*256];
        acc[4] += s * ib[(size_t)n*D_ + t];
    }
    float* ap = Apart + ((size_t)b*4 + qq)*APLD;
    #pragma unroll
    for (int j=0;j<4;++j) ap[t + j*256] = acc[j];
    ap[IN_ + t] = acc[4];
    if (t == 0){
        float m = 0.f; const float* rm = rowm + b*N_ + n0;
        for (int n=0;n<49;++n) m += rr[n]*rm[n];
        ap[1280] = m;
    }
}

__global__ __launch_bounds__(256)
void abar_reduce(const float* __restrict__ Apart, float* __restrict__ Abar,
                 float* __restrict__ mbar)
{
    const int b = blockIdx.x, t = threadIdx.x;
    const float* ap = Apart + (size_t)b*4*APLD;
    for (int c = t; c < 1281; c += 256){
        float s = ap[c] + ap[APLD + c] + ap[2*APLD + c] + ap[3*APLD + c];
        if (c < 1280) Abar[(size_t)b*CAT + c] = s * (1.f/N_);
        else mbar[b] = s * (1.f/N_);
    }
}

// ---------- pooled[b,d] = Abar[b]·Wfs[d] - mbar[b]*wsum[d] + bfs[d]  (f32 exact) ----------
__global__ __launch_bounds__(256)
void pooled_kernel(const float* __restrict__ Abar, const float* __restrict__ mbar,
                   const float* __restrict__ Wfs, const float* __restrict__ wsum,
                   const float* __restrict__ bfs, float* __restrict__ pooled)
{
    const int b = blockIdx.x, d = threadIdx.x;
    __shared__ float ab[CAT];
    for (int c=d;c<CAT;c+=256) ab[c] = Abar[(size_t)b*CAT + c];
    __syncthreads();
    const float* w = Wfs + (size_t)d*CAT;
    float s = 0.f;
    for (int c=0;c<CAT;c+=4){
        float4 wv = *(const float4*)(w+c);
        s += ab[c]*wv.x + ab[c+1]*wv.y + ab[c+2]*wv.z + ab[c+3]*wv.w;
    }
    pooled[b*D_ + d] = s - mbar[b]*wsum[d] + bfs[d];
}

// ---------- mean over tokens ----------
__global__ __launch_bounds__(256)
void mean_tokens(const float* __restrict__ src, float* __restrict__ dst)
{
    int b = blockIdx.x, d = threadIdx.x;
    const float* p = src + (size_t)b*N_*D_ + d;
    float s = 0.f;
    for (int n=0;n<N_;++n) s += p[(size_t)n*D_];
    dst[b*D_ + d] = s * (1.0f/N_);
}

// ---------- parent logits + routing ----------
__global__ __launch_bounds__(256)
void parent_kernel(const float* __restrict__ pooled, const float* __restrict__ Wpc,
                   const float* __restrict__ bpc, float* __restrict__ out, int* __restrict__ yhat)
{
    const int b = blockIdx.x, t = threadIdx.x;
    __shared__ __align__(16) float pl[D_];
    __shared__ float lg[NC_];
    pl[t] = pooled[b*D_ + t];
    __syncthreads();
    for (int c = t; c < NC_; c += 256){
        const float4* w4 = (const float4*)(Wpc + (size_t)c*D_);
        float s = 0.f;
        #pragma unroll 16
        for (int j=0;j<64;++j){
            float4 wv = w4[j];
            s += pl[j*4]*wv.x + pl[j*4+1]*wv.y + pl[j*4+2]*wv.z + pl[j*4+3]*wv.w;
        }
        lg[c] = s + bpc[c];
    }
    __syncthreads();
    float s=0.f, s2=0.f, bmv=-3.4e38f; int bidx=0;
    for (int c=t;c<NC_;c+=256){
        float x = lg[c]; s += x; s2 += x*x;
        if (x > bmv){ bmv=x; bidx=c; }
    }
    #pragma unroll
    for (int off=32; off>0; off>>=1){
        s  += __shfl_down(s, off);
        s2 += __shfl_down(s2, off);
        float ov = __shfl_down(bmv, off); int oi = __shfl_down(bidx, off);
        if (ov > bmv || (ov == bmv && oi < bidx)){ bmv=ov; bidx=oi; }
    }
    __shared__ float rs[4], rs2[4], rmv[4]; __shared__ int ri[4];
    __shared__ float fm, fr_;
    int w = t >> 6;
    if ((t & 63) == 0){ rs[w]=s; rs2[w]=s2; rmv[w]=bmv; ri[w]=bidx; }
    __syncthreads();
    if (t == 0){
        float S=0.f, S2=0.f, mv=-3.4e38f; int mi=0;
        for (int i=0;i<4;++i){
            S += rs[i]; S2 += rs2[i];
            if (rmv[i] > mv || (rmv[i] == mv && ri[i] < mi)){ mv=rmv[i]; mi=ri[i]; }
        }
        float mean = S*(1.0f/NC_);
        float var  = S2*(1.0f/NC_) - mean*mean;
        fm = mean; fr_ = rsqrtf(var + 1e-5f);
        yhat[b] = mi;
    }
    __syncthreads();
    for (int c=t;c<NC_;c+=256) out[(size_t)b*NC_ + c] = (lg[c]-fm)*fr_;
}

// ---------- routed child classifiers ----------
__global__ __launch_bounds__(64)
void child_kernel(const float* __restrict__ sp, const int* __restrict__ yhat,
                  const float* __restrict__ Wc0, const float* __restrict__ bc0,
                  const float* __restrict__ Wc1, const float* __restrict__ bc1,
                  float* __restrict__ out_c0, float* __restrict__ out_c1)
{
    const int b = blockIdx.x, t = threadIdx.x;
    __shared__ float spl[D_];
    for (int i=t;i<D_;i+=64) spl[i] = sp[b*D_ + i];
    __syncthreads();
    const int y = yhat[b];
    __shared__ float c0v[S0_], c1v[S1_];
    if (t < S0_){
        const float* w = Wc0 + (size_t)y*D_*S0_ + t;
        float s = 0.f;
        for (int d=0;d<D_;++d) s += spl[d]*w[(size_t)d*S0_];
        c0v[t] = s + bc0[y*S0_ + t];
    } else if (t < S0_+S1_){
        int k = t - S0_;
        const float* w = Wc1 + (size_t)y*D_*S1_ + k;
        float s = 0.f;
        for (int d=0;d<D_;++d) s += spl[d]*w[(size_t)d*S1_];
        c1v[k] = s + bc1[y*S1_ + k];
    }
    __syncthreads();
    __shared__ float st[4];
    if (t == 0){
        float m=0.f; for (int i=0;i<S0_;++i) m += c0v[i]; m *= (1.0f/S0_);
        float v=0.f; for (int i=0;i<S0_;++i){ float d=c0v[i]-m; v += d*d; } v *= (1.0f/S0_);
        st[0]=m; st[1]=rsqrtf(v+1e-5f);
        m=0.f; for (int i=0;i<S1_;++i) m += c1v[i]; m *= (1.0f/S1_);
        v=0.f; for (int i=0;i<S1_;++i){ float d=c1v[i]-m; v += d*d; } v *= (1.0f/S1_);
        st[2]=m; st[3]=rsqrtf(v+1e-5f);
    }
    __syncthreads();
    if (t < S0_) out_c0[b*S0_ + t] = (c0v[t]-st[0])*st[1];
    else if (t < S0_+S1_) out_c1[b*S1_ + (t-S0_)] = (c1v[t-S0_]-st[2])*st[3];
}

extern "C" void kernel_launch(void* const* d_in, const int* in_sizes, int n_in,
                              void* d_out, int out_size, void* d_ws, size_t ws_size,
                              hipStream_t stream)
{
    const float* h   = (const float*)d_in[0];
    const float* Wp  = (const float*)d_in[1];
    const float* bp  = (const float*)d_in[2];
    const float* Wsub= (const float*)d_in[3];
    const float* bs  = (const float*)d_in[4];
    const float* Wq  = (const float*)d_in[5];
    const float* bq  = (const float*)d_in[6];
    const float* Wk  = (const float*)d_in[7];
    const float* bk  = (const float*)d_in[8];
    const float* Wv  = (const float*)d_in[9];
    const float* bv  = (const float*)d_in[10];
    const float* Wo  = (const float*)d_in[11];
    const float* bo  = (const float*)d_in[12];
    const float* Wfs = (const float*)d_in[13];
    const float* bfs = (const float*)d_in[14];
    const float* Wpc = (const float*)d_in[15];
    const float* bpc = (const float*)d_in[16];
    const float* Wc0 = (const float*)d_in[17];
    const float* bc0 = (const float*)d_in[18];
    const float* Wc1 = (const float*)d_in[19];
    const float* bc1 = (const float*)d_in[20];

    float* out = (float*)d_out;
    float* out_pl = out;                         // [256,1000]
    float* out_c0 = out + 256000;                // [256,10]
    float* out_c1 = out + 258560;                // [256,20]
    float* out_fs = out + 263680;                // [256,196,256]
    float* out_se = out + 13108736;              // [256,196,256]

    // ---- workspace ----
    ushort_t* U = (ushort_t*)d_ws;
    const size_t UN = (size_t)ROWS * D_;         // 12,845,056
    ushort_t* U0 = U + 0*UN;   // pe_hi  -> k_hi
    ushort_t* U1 = U + 1*UN;   // pe_lo  -> k_lo
    ushort_t* U2 = U + 2*UN;   // se_hi  -> ao_hi
    ushort_t* U3 = U + 3*UN;   // se_lo  -> ao_lo
    ushort_t* U4 = U + 4*UN;   // q_hi   -> integ f32 (spans U4+U5)
    ushort_t* U5 = U + 5*UN;   // q_lo
    ushort_t* U6 = U + 6*UN;   // v_hi
    ushort_t* U7 = U + 7*UN;   // v_lo
    float* integ = (float*)U4;

    float* fmisc = (float*)(U + 8*UN);
    float* rowm = fmisc;                          // 50176
    float* rowr = rowm + ROWS;                    // 50176
    float* wsmb = rowr + ROWS;                    // 256
    float* pooled = wsmb + D_;                    // 65536
    float* sp   = pooled + (size_t)B_*D_;         // 65536
    float* mbar = sp + (size_t)B_*D_;             // 256
    float* Abar = mbar + 256;                     // 327680
    float* Apart = Abar + (size_t)B_*CAT;         // 256*4*1344
    int*   yhat = (int*)(Apart + (size_t)B_*4*APLD);
    ushort_t* wp = (ushort_t*)(yhat + 512);
    ushort_t* WpsH = wp;               ushort_t* WpsL = WpsH + 524288;   // [512][1024]
    ushort_t* WqH  = WpsL + 524288;    ushort_t* WqL  = WqH + 65536;
    ushort_t* WkvH = WqL + 65536;      ushort_t* WkvL = WkvH + 131072;   // [512][256]
    ushort_t* WoH  = WkvL + 131072;    ushort_t* WoL  = WoH + 65536;
    ushort_t* WfsH = WoL + 65536;      ushort_t* WfsL = WfsH + 327680;

    // split weights to bf16 hi/lo planes (stacked where fused)
    split_kernel<<<1024, 256, 0, stream>>>(Wp,   WpsH,          WpsL,          262144);
    split_kernel<<<1024, 256, 0, stream>>>(Wsub, WpsH + 262144, WpsL + 262144, 262144);
    split_kernel<<<256,  256, 0, stream>>>(Wq,   WqH,  WqL,  65536);
    split_kernel<<<256,  256, 0, stream>>>(Wk,   WkvH,          WkvL,          65536);
    split_kernel<<<256,  256, 0, stream>>>(Wv,   WkvH + 65536,  WkvL + 65536,  65536);
    split_kernel<<<256,  256, 0, stream>>>(Wo,   WoH,  WoL,  65536);
    split_kernel<<<1280, 256, 0, stream>>>(Wfs,  WfsH, WfsL, 327680);
    wsum_kernel<<<256, 64, 0, stream>>>(Wfs, wsmb);

    // fused pe+se -> pe planes U0/U1, se f32 out_se + planes U2/U3
    gemm_cvt3<<<dim3(4,392), 256, 0, stream>>>(h, WpsH, WpsL, bp, bs,
                                               out_se, U0, U1, U2, U3);
    // q = (pe@Wq^T+bq)*scale -> planes U4/U5
    gemm_4p<8,1><<<dim3(2,392), 256, 0, stream>>>(U0, U1, WqH, WqL, bq, nullptr,
                                                  nullptr, U4, U5, nullptr, nullptr);
    // fused k+v from se planes -> k U0/U1 (pe dead), v U6/U7
    gemm_4p<8,6><<<dim3(4,392), 256, 0, stream>>>(U2, U3, WkvH, WkvL, bk, bv,
                                                  nullptr, U0, U1, U6, U7);
    // attention -> ao planes U2/U3 (se planes dead)
    attn_mfma<<<dim3(B_, H_), 256, 0, stream>>>(U4, U5, U0, U1, U6, U7, U2, U3);
    // integ = ao@Wo^T+bo -> f32 @ U4/U5 (q dead)
    gemm_4p<8,4><<<dim3(2,392), 256, 0, stream>>>(U2, U3, WoH, WoL, bo, nullptr,
                                                  integ, nullptr, nullptr, nullptr, nullptr);
    // LN stats over concat(h,integ)
    rowstats_kernel<<<ROWS/4, 256, 0, stream>>>(h, integ, rowm, rowr);
    // fs (plain bf16, LN folded) -> out_fs
    gemm_fs<<<dim3(2,392), 256, 0, stream>>>(h, integ, WfsH, bfs, rowm, rowr, wsmb, out_fs);
    // exact f32 pooled via Abar identity
    abar_part<<<dim3(B_,4), 256, 0, stream>>>(h, integ, rowr, rowm, Apart);
    abar_reduce<<<B_, 256, 0, stream>>>(Apart, Abar, mbar);
    pooled_kernel<<<B_, 256, 0, stream>>>(Abar, mbar, Wfs, wsmb, bfs, pooled);
    // sp from se
    mean_tokens<<<B_, 256, 0, stream>>>(out_se, sp);
    // parent logits + routing
    parent_kernel<<<B_, 256, 0, stream>>>(pooled, Wpc, bpc, out_pl, yhat);
    // routed child classifiers
    child_kernel<<<B_, 64, 0, stream>>>(sp, yhat, Wc0, bc0, Wc1, bc1, out_c0, out_c1);
}

// Round 7
// 831.933 us; speedup vs baseline: 2.7631x; 1.1021x over previous
//
#include <hip/hip_runtime.h>
#include <hip/hip_bf16.h>
#include <math.h>

// Problem dims
#define B_   256
#define N_   196
#define IN_  1024
#define D_   256
#define H_   8
#define HD_  32
#define NC_  1000
#define S0_  10
#define S1_  20
#define ROWS (B_*N_)      // 50176
#define CAT  (IN_+D_)     // 1280

typedef unsigned short ushort_t;
typedef short bf16x8 __attribute__((ext_vector_type(8)));
typedef float f32x4  __attribute__((ext_vector_type(4)));
typedef ushort_t us4 __attribute__((ext_vector_type(4)));
typedef ushort_t us8 __attribute__((ext_vector_type(8)));

__device__ __forceinline__ ushort_t f2bf(float f){
    __hip_bfloat16 b = __float2bfloat16(f);
    ushort_t u; __builtin_memcpy(&u, &b, 2); return u;
}
__device__ __forceinline__ float bf2f(ushort_t h){
    union { unsigned int u; float f; } x; x.u = ((unsigned int)h) << 16;
    return x.f;
}
__device__ __forceinline__ float gelu_tanh(float x){
    float x3 = x*x*x;
    float inner = 0.7978845608028654f*(x + 0.044715f*x3);
    return 0.5f*x*(1.0f + tanhf(inner));
}
__device__ __forceinline__ void split8(const float* f, bf16x8& hi, bf16x8& lo){
    #pragma unroll
    for (int j=0;j<8;++j){
        ushort_t h = f2bf(f[j]);
        hi[j] = (short)h;
        lo[j] = (short)f2bf(f[j] - bf2f(h));
    }
}

// ---------- async global->LDS, 16B per lane ----------
typedef __attribute__((address_space(1))) const unsigned int gu32;
typedef __attribute__((address_space(3))) unsigned int lu32;
__device__ __forceinline__ void gload_lds16b(const void* g, void* l){
    __builtin_amdgcn_global_load_lds((gu32*)g, (lu32*)l, 16, 0, 0);
}

// stage a 128x32-ushort tile (8KB), linear LDS dest, inverse-swizzled source.
// swizzle: LDS(row, slot') holds global (row, slot' ^ ((row>>1)&3)); slots = 16B units.
__device__ __forceinline__ void stage32(const ushort_t* P, size_t rowbase, int ldk, int k0,
                                        ushort_t* lds, int t){
    const int w = t >> 6, l = t & 63;
    const int rr = l >> 2;                 // row within 16-row segment
    const int sl = (l & 3) ^ ((l >> 3) & 3);
    #pragma unroll
    for (int j=0;j<2;++j){
        int seg = w*2 + j;                 // 8 segments of 1KB (16 rows)
        const ushort_t* src = P + (rowbase + (size_t)(seg*16 + rr))*ldk + k0 + sl*8;
        gload_lds16b(src, lds + seg*512);
    }
}
__device__ __forceinline__ bf16x8 frag32(const ushort_t* lds, int row, int fq){
    return *(const bf16x8*)&lds[row*32 + ((fq ^ ((row >> 1) & 3)) << 3)];
}

// ---------- weight split: hi/lo bf16 planes ----------
__global__ __launch_bounds__(256)
void split_kernel(const float* __restrict__ src, ushort_t* __restrict__ hi,
                  ushort_t* __restrict__ lo, int n)
{
    int i = blockIdx.x*256 + threadIdx.x;
    if (i < n){
        float v = src[i];
        ushort_t h = f2bf(v);
        hi[i] = h;
        lo[i] = f2bf(v - bf2f(h));
    }
}

// ---------- colsum(Wfs) ----------
__global__ __launch_bounds__(64)
void wsum_kernel(const float* __restrict__ Wfs, float* __restrict__ wsum)
{
    const int d = blockIdx.x, l = threadIdx.x;
    const float* w = Wfs + (size_t)d*CAT;
    float s = 0.f;
    #pragma unroll
    for (int c0 = 0; c0 < CAT; c0 += 256){
        float4 v = *(const float4*)(w + c0 + l*4);
        s += v.x+v.y+v.z+v.w;
    }
    #pragma unroll
    for (int off=32; off>0; off>>=1) s += __shfl_down(s, off);
    if (l == 0) wsum[d] = s;
}

// ---------- pipelined fused pe+se: A=h f32 (reg prefetch + convert), B=[Wp;Ws] planes ----------
// 1D grid 1568, XCD-stripe swizzle; NBN=4
__global__ __launch_bounds__(256)
void gemm_pese(const float* __restrict__ A,
               const ushort_t* __restrict__ BH, const ushort_t* __restrict__ BL,
               const float* __restrict__ bias1, const float* __restrict__ bias2,
               float* __restrict__ seF,
               ushort_t* __restrict__ peH, ushort_t* __restrict__ peL,
               ushort_t* __restrict__ seH, ushort_t* __restrict__ seL)
{
    __shared__ ushort_t S[2][4][128*32];
    const int nwg = gridDim.x, cpx = nwg >> 3, bid = blockIdx.x;
    const int wg = (bid & 7)*cpx + (bid >> 3);
    const int bn = (wg & 3)*128, bm = (wg >> 2)*128;
    const int t = threadIdx.x, lane = t & 63, wid = t >> 6;
    const int wr = wid >> 1, wc = wid & 1, fr = lane & 15, fq = lane >> 4;
    const int row2 = t >> 1, half = t & 1;

    f32x4 acc[4][4];
    #pragma unroll
    for (int i=0;i<4;++i)
        #pragma unroll
        for (int j=0;j<4;++j) acc[i][j] = (f32x4){0.f,0.f,0.f,0.f};

    const float* abase = A + (size_t)(bm + row2)*IN_ + half*16;
    float4 va[4], vb[4];

    auto loadA = [&](float4* v, int kc){
        const float* ap = abase + kc*32;
        v[0] = *(const float4*)(ap);
        v[1] = *(const float4*)(ap + 4);
        v[2] = *(const float4*)(ap + 8);
        v[3] = *(const float4*)(ap + 12);
    };
    auto cvtwrite = [&](int buf, const float4* v){
        float f[16];
        #pragma unroll
        for (int j=0;j<4;++j){ f[j*4]=v[j].x; f[j*4+1]=v[j].y; f[j*4+2]=v[j].z; f[j*4+3]=v[j].w; }
        us8 h0, h1, l0, l1;
        #pragma unroll
        for (int j=0;j<8;++j){
            ushort_t hv = f2bf(f[j]);     h0[j] = hv; l0[j] = f2bf(f[j]   - bf2f(hv));
            ushort_t hw = f2bf(f[8+j]);   h1[j] = hw; l1[j] = f2bf(f[8+j] - bf2f(hw));
        }
        const int sz = (row2 >> 1) & 3;
        const int s0 = (half*2) ^ sz, s1 = (half*2 + 1) ^ sz;
        *(us8*)&S[buf][0][row2*32 + s0*8] = h0;
        *(us8*)&S[buf][0][row2*32 + s1*8] = h1;
        *(us8*)&S[buf][1][row2*32 + s0*8] = l0;
        *(us8*)&S[buf][1][row2*32 + s1*8] = l1;
    };
    auto stageB = [&](int buf, int kc){
        stage32(BH, bn, IN_, kc*32, S[buf][2], t);
        stage32(BL, bn, IN_, kc*32, S[buf][3], t);
    };
    auto compute = [&](int buf){
        #pragma unroll
        for (int term=0; term<3; ++term){
            const ushort_t* At = S[buf][term==1 ? 1 : 0];
            const ushort_t* Bt = S[buf][term==2 ? 3 : 2];
            bf16x8 a[4], b[4];
            #pragma unroll
            for (int i=0;i<4;++i){
                a[i] = frag32(At, wr*64 + i*16 + fr, fq);
                b[i] = frag32(Bt, wc*64 + i*16 + fr, fq);
            }
            #pragma unroll
            for (int i=0;i<4;++i)
                #pragma unroll
                for (int j=0;j<4;++j)
                    acc[i][j] = __builtin_amdgcn_mfma_f32_16x16x32_bf16(a[i], b[j], acc[i][j], 0,0,0);
        }
    };

    // prologue: buf0 <- tile0; va <- A(1)
    loadA(va, 0); stageB(0, 0); cvtwrite(0, va);
    loadA(va, 1);
    __syncthreads();
    int cur = 0;
    for (int kc = 0; kc < 32; kc += 2){
        // even iter: va holds A(kc+1)
        if (kc+1 < 32) stageB(cur^1, kc+1);
        if (kc+2 < 32) loadA(vb, kc+2);
        compute(cur);
        if (kc+1 < 32) cvtwrite(cur^1, va);
        __syncthreads();
        cur ^= 1;
        // odd iter kc+1: vb holds A(kc+2)
        if (kc+2 < 32) stageB(cur^1, kc+2);
        if (kc+3 < 32) loadA(va, kc+3);
        compute(cur);
        if (kc+2 < 32) cvtwrite(cur^1, vb);
        __syncthreads();
        cur ^= 1;
    }
    // epilogue: col<256 -> pe planes, else se f32+planes (gelu both)
    #pragma unroll
    for (int i=0;i<4;++i){
        #pragma unroll
        for (int j=0;j<4;++j){
            const int col = bn + wc*64 + j*16 + fr;
            #pragma unroll
            for (int r=0;r<4;++r){
                const int row = bm + wr*64 + i*16 + fq*4 + r;
                if (col < 256){
                    float x = gelu_tanh(acc[i][j][r] + bias1[col]);
                    ushort_t hv = f2bf(x);
                    peH[(size_t)row*D_ + col] = hv;
                    peL[(size_t)row*D_ + col] = f2bf(x - bf2f(hv));
                } else {
                    int c2 = col - 256;
                    float x = gelu_tanh(acc[i][j][r] + bias2[c2]);
                    seF[(size_t)row*D_ + c2] = x;
                    ushort_t hv = f2bf(x);
                    seH[(size_t)row*D_ + c2] = hv;
                    seL[(size_t)row*D_ + c2] = f2bf(x - bf2f(hv));
                }
            }
        }
    }
}

// ---------- pipelined 4-plane GEMM ----------
// EPI: 1=q(scale+planes->o1)  6=kv(col<256->o1 else o2)  4=integ(f32o)
template<int KCH, int NBN, int EPI>
__global__ __launch_bounds__(256)
void gemm_plane(const ushort_t* __restrict__ AH, const ushort_t* __restrict__ AL,
                const ushort_t* __restrict__ BH, const ushort_t* __restrict__ BL,
                const float* __restrict__ bias1, const float* __restrict__ bias2,
                float* __restrict__ f32o,
                ushort_t* __restrict__ o1h, ushort_t* __restrict__ o1l,
                ushort_t* __restrict__ o2h, ushort_t* __restrict__ o2l)
{
    __shared__ ushort_t S[2][4][128*32];
    const int nwg = gridDim.x, cpx = nwg >> 3, bid = blockIdx.x;
    const int wg = (bid & 7)*cpx + (bid >> 3);
    const int bn = (wg % NBN)*128, bm = (wg / NBN)*128;
    const int t = threadIdx.x, lane = t & 63, wid = t >> 6;
    const int wr = wid >> 1, wc = wid & 1, fr = lane & 15, fq = lane >> 4;

    f32x4 acc[4][4];
    #pragma unroll
    for (int i=0;i<4;++i)
        #pragma unroll
        for (int j=0;j<4;++j) acc[i][j] = (f32x4){0.f,0.f,0.f,0.f};

    auto stage4 = [&](int buf, int kc){
        stage32(AH, bm, 256, kc*32, S[buf][0], t);
        stage32(AL, bm, 256, kc*32, S[buf][1], t);
        stage32(BH, bn, 256, kc*32, S[buf][2], t);
        stage32(BL, bn, 256, kc*32, S[buf][3], t);
    };
    auto compute = [&](int buf){
        #pragma unroll
        for (int term=0; term<3; ++term){
            const ushort_t* At = S[buf][term==1 ? 1 : 0];
            const ushort_t* Bt = S[buf][term==2 ? 3 : 2];
            bf16x8 a[4], b[4];
            #pragma unroll
            for (int i=0;i<4;++i){
                a[i] = frag32(At, wr*64 + i*16 + fr, fq);
                b[i] = frag32(Bt, wc*64 + i*16 + fr, fq);
            }
            #pragma unroll
            for (int i=0;i<4;++i)
                #pragma unroll
                for (int j=0;j<4;++j)
                    acc[i][j] = __builtin_amdgcn_mfma_f32_16x16x32_bf16(a[i], b[j], acc[i][j], 0,0,0);
        }
    };

    stage4(0, 0);
    __syncthreads();
    int cur = 0;
    #pragma unroll 2
    for (int kc = 0; kc < KCH; ++kc){
        if (kc+1 < KCH) stage4(cur^1, kc+1);
        compute(cur);
        __syncthreads();
        cur ^= 1;
    }
    #pragma unroll
    for (int i=0;i<4;++i){
        #pragma unroll
        for (int j=0;j<4;++j){
            const int col = bn + wc*64 + j*16 + fr;
            #pragma unroll
            for (int r=0;r<4;++r){
                const int row = bm + wr*64 + i*16 + fq*4 + r;
                if (EPI == 1){
                    float x = (acc[i][j][r] + bias1[col]) * 0.17677669529663687f;
                    ushort_t hv = f2bf(x);
                    o1h[(size_t)row*D_ + col] = hv;
                    o1l[(size_t)row*D_ + col] = f2bf(x - bf2f(hv));
                } else if (EPI == 6){
                    if (col < 256){
                        float x = acc[i][j][r] + bias1[col];
                        ushort_t hv = f2bf(x);
                        o1h[(size_t)row*D_ + col] = hv;
                        o1l[(size_t)row*D_ + col] = f2bf(x - bf2f(hv));
                    } else {
                        int c2 = col - 256;
                        float x = acc[i][j][r] + bias2[c2];
                        ushort_t hv = f2bf(x);
                        o2h[(size_t)row*D_ + c2] = hv;
                        o2l[(size_t)row*D_ + c2] = f2bf(x - bf2f(hv));
                    }
                } else { // EPI == 4
                    f32o[(size_t)row*D_ + col] = acc[i][j][r] + bias1[col];
                }
            }
        }
    }
}

// ---------- pipelined fs GEMM: A=[h|integ] f32 hi-only, B=WfsH, LN folded ----------
__global__ __launch_bounds__(256)
void gemm_fsk(const float* __restrict__ A1, const float* __restrict__ A2,
              const ushort_t* __restrict__ BH, const float* __restrict__ bias,
              const float* __restrict__ rowm, const float* __restrict__ rowr,
              const float* __restrict__ wsump, float* __restrict__ C)
{
    __shared__ ushort_t S[2][2][128*32];
    const int nwg = gridDim.x, cpx = nwg >> 3, bid = blockIdx.x;
    const int wg = (bid & 7)*cpx + (bid >> 3);
    const int bn = (wg & 1)*128, bm = (wg >> 1)*128;
    const int t = threadIdx.x, lane = t & 63, wid = t >> 6;
    const int wr = wid >> 1, wc = wid & 1, fr = lane & 15, fq = lane >> 4;
    const int row2 = t >> 1, half = t & 1;

    f32x4 acc[4][4];
    #pragma unroll
    for (int i=0;i<4;++i)
        #pragma unroll
        for (int j=0;j<4;++j) acc[i][j] = (f32x4){0.f,0.f,0.f,0.f};

    float4 va[4], vb[4];
    auto loadA = [&](float4* v, int kc){
        const float* ap = (kc < 32) ? A1 + (size_t)(bm + row2)*IN_ + kc*32 + half*16
                                    : A2 + (size_t)(bm + row2)*D_ + (kc-32)*32 + half*16;
        v[0] = *(const float4*)(ap);
        v[1] = *(const float4*)(ap + 4);
        v[2] = *(const float4*)(ap + 8);
        v[3] = *(const float4*)(ap + 12);
    };
    auto cvtwrite = [&](int buf, const float4* v){
        float f[16];
        #pragma unroll
        for (int j=0;j<4;++j){ f[j*4]=v[j].x; f[j*4+1]=v[j].y; f[j*4+2]=v[j].z; f[j*4+3]=v[j].w; }
        us8 h0, h1;
        #pragma unroll
        for (int j=0;j<8;++j){ h0[j] = f2bf(f[j]); h1[j] = f2bf(f[8+j]); }
        const int sz = (row2 >> 1) & 3;
        const int s0 = (half*2) ^ sz, s1 = (half*2 + 1) ^ sz;
        *(us8*)&S[buf][0][row2*32 + s0*8] = h0;
        *(us8*)&S[buf][0][row2*32 + s1*8] = h1;
    };
    auto stageB = [&](int buf, int kc){
        stage32(BH, bn, CAT, kc*32, S[buf][1], t);
    };
    auto compute = [&](int buf){
        bf16x8 a[4], b[4];
        #pragma unroll
        for (int i=0;i<4;++i){
            a[i] = frag32(S[buf][0], wr*64 + i*16 + fr, fq);
            b[i] = frag32(S[buf][1], wc*64 + i*16 + fr, fq);
        }
        #pragma unroll
        for (int i=0;i<4;++i)
            #pragma unroll
            for (int j=0;j<4;++j)
                acc[i][j] = __builtin_amdgcn_mfma_f32_16x16x32_bf16(a[i], b[j], acc[i][j], 0,0,0);
    };

    loadA(va, 0); stageB(0, 0); cvtwrite(0, va);
    loadA(va, 1);
    __syncthreads();
    int cur = 0;
    for (int kc = 0; kc < 40; kc += 2){
        if (kc+1 < 40) stageB(cur^1, kc+1);
        if (kc+2 < 40) loadA(vb, kc+2);
        compute(cur);
        if (kc+1 < 40) cvtwrite(cur^1, va);
        __syncthreads();
        cur ^= 1;
        if (kc+2 < 40) stageB(cur^1, kc+2);
        if (kc+3 < 40) loadA(va, kc+3);
        compute(cur);
        if (kc+2 < 40) cvtwrite(cur^1, vb);
        __syncthreads();
        cur ^= 1;
    }
    #pragma unroll
    for (int i=0;i<4;++i){
        #pragma unroll
        for (int j=0;j<4;++j){
            const int col = bn + wc*64 + j*16 + fr;
            float ws_ = wsump[col], bb = bias[col];
            #pragma unroll
            for (int r=0;r<4;++r){
                const int row = bm + wr*64 + i*16 + fq*4 + r;
                C[(size_t)row*D_ + col] = rowr[row]*(acc[i][j][r] - rowm[row]*ws_) + bb;
            }
        }
    }
}

// ---------- MFMA attention (split-bf16 planes in, planes out) ----------
#define KROWS 208
#define KLD   40
#define VLD   232

__global__ __launch_bounds__(256)
void attn_mfma(const ushort_t* __restrict__ qhi, const ushort_t* __restrict__ qlo,
               const ushort_t* __restrict__ khi, const ushort_t* __restrict__ klo,
               const ushort_t* __restrict__ vhi, const ushort_t* __restrict__ vlo,
               ushort_t* __restrict__ aohi, ushort_t* __restrict__ aolo)
{
    __shared__ ushort_t Khi[KROWS*KLD], Klo[KROWS*KLD];
    __shared__ ushort_t Vthi[32*VLD], Vtlo[32*VLD];

    const int b = blockIdx.x, hh = blockIdx.y;
    const int t = threadIdx.x;
    const int lane = t & 63;
    const int wid  = t >> 6;
    const int fr = lane & 15;
    const int fq = lane >> 4;
    const size_t bbase = (size_t)b*N_*D_ + hh*HD_;

    for (int idx = t; idx < KROWS*4; idx += 256){
        int row = idx >> 2, c8 = (idx & 3) << 3;
        us8 vh, vl;
        if (row < N_){
            vh = *(const us8*)(khi + bbase + (size_t)row*D_ + c8);
            vl = *(const us8*)(klo + bbase + (size_t)row*D_ + c8);
        } else {
            #pragma unroll
            for (int j=0;j<8;++j){ vh[j]=0; vl[j]=0; }
        }
        *(us8*)&Khi[row*KLD + c8] = vh;
        *(us8*)&Klo[row*KLD + c8] = vl;
    }
    for (int idx = t; idx < 224*4; idx += 256){
        int key = idx >> 2, c8 = (idx & 3) << 3;
        us8 vh, vl;
        if (key < N_){
            vh = *(const us8*)(vhi + bbase + (size_t)key*D_ + c8);
            vl = *(const us8*)(vlo + bbase + (size_t)key*D_ + c8);
        } else {
            #pragma unroll
            for (int j=0;j<8;++j){ vh[j]=0; vl[j]=0; }
        }
        int w = key & 31, cc = key >> 5;
        int slot;
        if (w < 16) slot = cc*32 + (w>>2)*8 + (w&3);
        else { int w2 = w-16; slot = cc*32 + (w2>>2)*8 + 4 + (w2&3); }
        #pragma unroll
        for (int j=0;j<8;++j){
            int dim = c8 + j;
            Vthi[dim*VLD + slot] = vh[j];
            Vtlo[dim*VLD + slot] = vl[j];
        }
    }
    __syncthreads();

    for (int qt = wid; qt < 13; qt += 4){
        int qrow = qt*16 + fr; if (qrow > N_-1) qrow = N_-1;
        const bf16x8 qh = *(const bf16x8*)(qhi + bbase + (size_t)qrow*D_ + fq*8);
        const bf16x8 ql = *(const bf16x8*)(qlo + bbase + (size_t)qrow*D_ + fq*8);

        f32x4 s[13];
        #pragma unroll
        for (int kt=0; kt<13; ++kt) s[kt] = (f32x4){0.f,0.f,0.f,0.f};
        #pragma unroll
        for (int kt=0; kt<13; ++kt){
            const bf16x8 kh = *(const bf16x8*)&Khi[(kt*16 + fr)*KLD + fq*8];
            const bf16x8 kl = *(const bf16x8*)&Klo[(kt*16 + fr)*KLD + fq*8];
            s[kt] = __builtin_amdgcn_mfma_f32_16x16x32_bf16(kh, qh, s[kt], 0,0,0);
            s[kt] = __builtin_amdgcn_mfma_f32_16x16x32_bf16(kh, ql, s[kt], 0,0,0);
            s[kt] = __builtin_amdgcn_mfma_f32_16x16x32_bf16(kl, qh, s[kt], 0,0,0);
        }
        if (fq > 0) s[12] = (f32x4){-1e30f,-1e30f,-1e30f,-1e30f};

        float m = -3.4e38f;
        #pragma unroll
        for (int kt=0; kt<13; ++kt)
            #pragma unroll
            for (int r=0;r<4;++r) m = fmaxf(m, s[kt][r]);
        m = fmaxf(m, __shfl_xor(m, 16));
        m = fmaxf(m, __shfl_xor(m, 32));
        float sum = 0.f;
        #pragma unroll
        for (int kt=0; kt<13; ++kt)
            #pragma unroll
            for (int r=0;r<4;++r){
                float p = __expf(s[kt][r] - m);
                s[kt][r] = p; sum += p;
            }
        sum += __shfl_xor(sum, 16);
        sum += __shfl_xor(sum, 32);
        const float inv = 1.0f / sum;

        f32x4 o0 = (f32x4){0.f,0.f,0.f,0.f};
        f32x4 o1 = (f32x4){0.f,0.f,0.f,0.f};
        #pragma unroll
        for (int c=0;c<7;++c){
            float pv[8];
            #pragma unroll
            for (int r=0;r<4;++r){
                pv[r]   = s[2*c][r];
                pv[4+r] = (c < 6) ? s[2*c+1][r] : 0.f;
            }
            bf16x8 ph, pl; split8(pv, ph, pl);
            const int coff = c*32 + fq*8;
            const bf16x8 v0h = *(const bf16x8*)&Vthi[(fr)*VLD + coff];
            const bf16x8 v0l = *(const bf16x8*)&Vtlo[(fr)*VLD + coff];
            const bf16x8 v1h = *(const bf16x8*)&Vthi[(16+fr)*VLD + coff];
            const bf16x8 v1l = *(const bf16x8*)&Vtlo[(16+fr)*VLD + coff];
            o0 = __builtin_amdgcn_mfma_f32_16x16x32_bf16(v0h, ph, o0, 0,0,0);
            o0 = __builtin_amdgcn_mfma_f32_16x16x32_bf16(v0h, pl, o0, 0,0,0);
            o0 = __builtin_amdgcn_mfma_f32_16x16x32_bf16(v0l, ph, o0, 0,0,0);
            o1 = __builtin_amdgcn_mfma_f32_16x16x32_bf16(v1h, ph, o1, 0,0,0);
            o1 = __builtin_amdgcn_mfma_f32_16x16x32_bf16(v1h, pl, o1, 0,0,0);
            o1 = __builtin_amdgcn_mfma_f32_16x16x32_bf16(v1l, ph, o1, 0,0,0);
        }
        int tok = qt*16 + fr;
        if (tok < N_){
            const size_t obase = bbase + (size_t)tok*D_;
            #pragma unroll
            for (int r=0;r<4;++r){
                float x0 = o0[r]*inv;
                float x1 = o1[r]*inv;
                ushort_t h0 = f2bf(x0), h1 = f2bf(x1);
                aohi[obase + fq*4 + r]      = h0;
                aolo[obase + fq*4 + r]      = f2bf(x0 - bf2f(h0));
                aohi[obase + 16 + fq*4 + r] = h1;
                aolo[obase + 16 + fq*4 + r] = f2bf(x1 - bf2f(h1));
            }
        }
    }
}

// ---------- fused rowstats + abar partial: one read of h+integ ----------
#define APLD 1344
__global__ __launch_bounds__(256)
void abar_part(const float* __restrict__ h, const float* __restrict__ integ,
               float* __restrict__ rowm, float* __restrict__ rowr,
               float* __restrict__ Apart)
{
    const int b = blockIdx.x, qq = blockIdx.y, t = threadIdx.x;
    const int lane = t & 63, w = t >> 6;
    const int n0 = qq*49;
    __shared__ float ss[4], ss2[4];
    float acc[5] = {0.f,0.f,0.f,0.f,0.f};
    float mracc = 0.f;
    for (int n=0; n<49; ++n){
        const int row = b*N_ + n0 + n;
        float e[5];
        const float* hr = h + (size_t)row*IN_;
        #pragma unroll
        for (int j=0;j<4;++j) e[j] = hr[t + j*256];
        e[4] = integ[(size_t)row*D_ + t];
        float s  = e[0]+e[1]+e[2]+e[3]+e[4];
        float s2 = e[0]*e[0]+e[1]*e[1]+e[2]*e[2]+e[3]*e[3]+e[4]*e[4];
        #pragma unroll
        for (int off=32; off>0; off>>=1){ s += __shfl_down(s,off); s2 += __shfl_down(s2,off); }
        if (lane == 0){ ss[w] = s; ss2[w] = s2; }
        __syncthreads();
        float S1 = ss[0]+ss[1]+ss[2]+ss[3];
        float S2 = ss2[0]+ss2[1]+ss2[2]+ss2[3];
        float m  = S1 * (1.0f/CAT);
        float rr = rsqrtf(S2 * (1.0f/CAT) - m*m + 1e-5f);
        if (t == 0){ rowm[row] = m; rowr[row] = rr; }
        #pragma unroll
        for (int j=0;j<5;++j) acc[j] += rr*e[j];
        mracc += rr*m;
        __syncthreads();
    }
    float* ap = Apart + ((size_t)b*4 + qq)*APLD;
    #pragma unroll
    for (int j=0;j<4;++j) ap[t + j*256] = acc[j];
    ap[IN_ + t] = acc[4];
    if (t == 0) ap[1280] = mracc;
}

__global__ __launch_bounds__(256)
void abar_reduce(const float* __restrict__ Apart, float* __restrict__ Abar,
                 float* __restrict__ mbar)
{
    const int b = blockIdx.x, t = threadIdx.x;
    const float* ap = Apart + (size_t)b*4*APLD;
    for (int c = t; c < 1281; c += 256){
        float s = ap[c] + ap[APLD + c] + ap[2*APLD + c] + ap[3*APLD + c];
        if (c < 1280) Abar[(size_t)b*CAT + c] = s * (1.f/N_);
        else mbar[b] = s * (1.f/N_);
    }
}

// ---------- pooled[b,d] = Abar[b]·Wfs[d] - mbar[b]*wsum[d] + bfs[d]  (f32 exact) ----------
__global__ __launch_bounds__(256)
void pooled_kernel(const float* __restrict__ Abar, const float* __restrict__ mbar,
                   const float* __restrict__ Wfs, const float* __restrict__ wsum,
                   const float* __restrict__ bfs, float* __restrict__ pooled)
{
    const int b = blockIdx.x, d = threadIdx.x;
    __shared__ float ab[CAT];
    for (int c=d;c<CAT;c+=256) ab[c] = Abar[(size_t)b*CAT + c];
    __syncthreads();
    const float* w = Wfs + (size_t)d*CAT;
    float s = 0.f;
    for (int c=0;c<CAT;c+=4){
        float4 wv = *(const float4*)(w+c);
        s += ab[c]*wv.x + ab[c+1]*wv.y + ab[c+2]*wv.z + ab[c+3]*wv.w;
    }
    pooled[b*D_ + d] = s - mbar[b]*wsum[d] + bfs[d];
}

// ---------- mean over tokens ----------
__global__ __launch_bounds__(256)
void mean_tokens(const float* __restrict__ src, float* __restrict__ dst)
{
    int b = blockIdx.x, d = threadIdx.x;
    const float* p = src + (size_t)b*N_*D_ + d;
    float s = 0.f;
    for (int n=0;n<N_;++n) s += p[(size_t)n*D_];
    dst[b*D_ + d] = s * (1.0f/N_);
}

// ---------- parent logits + routing ----------
__global__ __launch_bounds__(256)
void parent_kernel(const float* __restrict__ pooled, const float* __restrict__ Wpc,
                   const float* __restrict__ bpc, float* __restrict__ out, int* __restrict__ yhat)
{
    const int b = blockIdx.x, t = threadIdx.x;
    __shared__ __align__(16) float pl[D_];
    __shared__ float lg[NC_];
    pl[t] = pooled[b*D_ + t];
    __syncthreads();
    for (int c = t; c < NC_; c += 256){
        const float4* w4 = (const float4*)(Wpc + (size_t)c*D_);
        float s = 0.f;
        #pragma unroll 16
        for (int j=0;j<64;++j){
            float4 wv = w4[j];
            s += pl[j*4]*wv.x + pl[j*4+1]*wv.y + pl[j*4+2]*wv.z + pl[j*4+3]*wv.w;
        }
        lg[c] = s + bpc[c];
    }
    __syncthreads();
    float s=0.f, s2=0.f, bmv=-3.4e38f; int bidx=0;
    for (int c=t;c<NC_;c+=256){
        float x = lg[c]; s += x; s2 += x*x;
        if (x > bmv){ bmv=x; bidx=c; }
    }
    #pragma unroll
    for (int off=32; off>0; off>>=1){
        s  += __shfl_down(s, off);
        s2 += __shfl_down(s2, off);
        float ov = __shfl_down(bmv, off); int oi = __shfl_down(bidx, off);
        if (ov > bmv || (ov == bmv && oi < bidx)){ bmv=ov; bidx=oi; }
    }
    __shared__ float rs[4], rs2[4], rmv[4]; __shared__ int ri[4];
    __shared__ float fm, fr_;
    int w = t >> 6;
    if ((t & 63) == 0){ rs[w]=s; rs2[w]=s2; rmv[w]=bmv; ri[w]=bidx; }
    __syncthreads();
    if (t == 0){
        float S=0.f, S2=0.f, mv=-3.4e38f; int mi=0;
        for (int i=0;i<4;++i){
            S += rs[i]; S2 += rs2[i];
            if (rmv[i] > mv || (rmv[i] == mv && ri[i] < mi)){ mv=rmv[i]; mi=ri[i]; }
        }
        float mean = S*(1.0f/NC_);
        float var  = S2*(1.0f/NC_) - mean*mean;
        fm = mean; fr_ = rsqrtf(var + 1e-5f);
        yhat[b] = mi;
    }
    __syncthreads();
    for (int c=t;c<NC_;c+=256) out[(size_t)b*NC_ + c] = (lg[c]-fm)*fr_;
}

// ---------- routed child classifiers ----------
__global__ __launch_bounds__(64)
void child_kernel(const float* __restrict__ sp, const int* __restrict__ yhat,
                  const float* __restrict__ Wc0, const float* __restrict__ bc0,
                  const float* __restrict__ Wc1, const float* __restrict__ bc1,
                  float* __restrict__ out_c0, float* __restrict__ out_c1)
{
    const int b = blockIdx.x, t = threadIdx.x;
    __shared__ float spl[D_];
    for (int i=t;i<D_;i+=64) spl[i] = sp[b*D_ + i];
    __syncthreads();
    const int y = yhat[b];
    __shared__ float c0v[S0_], c1v[S1_];
    if (t < S0_){
        const float* w = Wc0 + (size_t)y*D_*S0_ + t;
        float s = 0.f;
        for (int d=0;d<D_;++d) s += spl[d]*w[(size_t)d*S0_];
        c0v[t] = s + bc0[y*S0_ + t];
    } else if (t < S0_+S1_){
        int k = t - S0_;
        const float* w = Wc1 + (size_t)y*D_*S1_ + k;
        float s = 0.f;
        for (int d=0;d<D_;++d) s += spl[d]*w[(size_t)d*S1_];
        c1v[k] = s + bc1[y*S1_ + k];
    }
    __syncthreads();
    __shared__ float st[4];
    if (t == 0){
        float m=0.f; for (int i=0;i<S0_;++i) m += c0v[i]; m *= (1.0f/S0_);
        float v=0.f; for (int i=0;i<S0_;++i){ float d=c0v[i]-m; v += d*d; } v *= (1.0f/S0_);
        st[0]=m; st[1]=rsqrtf(v+1e-5f);
        m=0.f; for (int i=0;i<S1_;++i) m += c1v[i]; m *= (1.0f/S1_);
        v=0.f; for (int i=0;i<S1_;++i){ float d=c1v[i]-m; v += d*d; } v *= (1.0f/S1_);
        st[2]=m; st[3]=rsqrtf(v+1e-5f);
    }
    __syncthreads();
    if (t < S0_) out_c0[b*S0_ + t] = (c0v[t]-st[0])*st[1];
    else if (t < S0_+S1_) out_c1[b*S1_ + (t-S0_)] = (c1v[t-S0_]-st[2])*st[3];
}

extern "C" void kernel_launch(void* const* d_in, const int* in_sizes, int n_in,
                              void* d_out, int out_size, void* d_ws, size_t ws_size,
                              hipStream_t stream)
{
    const float* h   = (const float*)d_in[0];
    const float* Wp  = (const float*)d_in[1];
    const float* bp  = (const float*)d_in[2];
    const float* Wsub= (const float*)d_in[3];
    const float* bs  = (const float*)d_in[4];
    const float* Wq  = (const float*)d_in[5];
    const float* bq  = (const float*)d_in[6];
    const float* Wk  = (const float*)d_in[7];
    const float* bk  = (const float*)d_in[8];
    const float* Wv  = (const float*)d_in[9];
    const float* bv  = (const float*)d_in[10];
    const float* Wo  = (const float*)d_in[11];
    const float* bo  = (const float*)d_in[12];
    const float* Wfs = (const float*)d_in[13];
    const float* bfs = (const float*)d_in[14];
    const float* Wpc = (const float*)d_in[15];
    const float* bpc = (const float*)d_in[16];
    const float* Wc0 = (const float*)d_in[17];
    const float* bc0 = (const float*)d_in[18];
    const float* Wc1 = (const float*)d_in[19];
    const float* bc1 = (const float*)d_in[20];

    float* out = (float*)d_out;
    float* out_pl = out;                         // [256,1000]
    float* out_c0 = out + 256000;                // [256,10]
    float* out_c1 = out + 258560;                // [256,20]
    float* out_fs = out + 263680;                // [256,196,256]
    float* out_se = out + 13108736;              // [256,196,256]

    // ---- workspace ----
    ushort_t* U = (ushort_t*)d_ws;
    const size_t UN = (size_t)ROWS * D_;         // 12,845,056
    ushort_t* U0 = U + 0*UN;   // pe_hi  -> k_hi
    ushort_t* U1 = U + 1*UN;   // pe_lo  -> k_lo
    ushort_t* U2 = U + 2*UN;   // se_hi  -> ao_hi
    ushort_t* U3 = U + 3*UN;   // se_lo  -> ao_lo
    ushort_t* U4 = U + 4*UN;   // q_hi   -> integ f32 (spans U4+U5)
    ushort_t* U5 = U + 5*UN;   // q_lo
    ushort_t* U6 = U + 6*UN;   // v_hi
    ushort_t* U7 = U + 7*UN;   // v_lo
    float* integ = (float*)U4;

    float* fmisc = (float*)(U + 8*UN);
    float* rowm = fmisc;                          // 50176
    float* rowr = rowm + ROWS;                    // 50176
    float* wsmb = rowr + ROWS;                    // 256
    float* pooled = wsmb + D_;                    // 65536
    float* sp   = pooled + (size_t)B_*D_;         // 65536
    float* mbar = sp + (size_t)B_*D_;             // 256
    float* Abar = mbar + 256;                     // 327680
    float* Apart = Abar + (size_t)B_*CAT;         // 256*4*1344
    int*   yhat = (int*)(Apart + (size_t)B_*4*APLD);
    ushort_t* wp = (ushort_t*)(yhat + 512);
    ushort_t* WpsH = wp;               ushort_t* WpsL = WpsH + 524288;   // [512][1024]
    ushort_t* WqH  = WpsL + 524288;    ushort_t* WqL  = WqH + 65536;
    ushort_t* WkvH = WqL + 65536;      ushort_t* WkvL = WkvH + 131072;   // [512][256]
    ushort_t* WoH  = WkvL + 131072;    ushort_t* WoL  = WoH + 65536;
    ushort_t* WfsH = WoL + 65536;      ushort_t* WfsL = WfsH + 327680;

    // split weights to bf16 hi/lo planes (stacked where fused)
    split_kernel<<<1024, 256, 0, stream>>>(Wp,   WpsH,          WpsL,          262144);
    split_kernel<<<1024, 256, 0, stream>>>(Wsub, WpsH + 262144, WpsL + 262144, 262144);
    split_kernel<<<256,  256, 0, stream>>>(Wq,   WqH,  WqL,  65536);
    split_kernel<<<256,  256, 0, stream>>>(Wk,   WkvH,          WkvL,          65536);
    split_kernel<<<256,  256, 0, stream>>>(Wv,   WkvH + 65536,  WkvL + 65536,  65536);
    split_kernel<<<256,  256, 0, stream>>>(Wo,   WoH,  WoL,  65536);
    split_kernel<<<1280, 256, 0, stream>>>(Wfs,  WfsH, WfsL, 327680);
    wsum_kernel<<<256, 64, 0, stream>>>(Wfs, wsmb);

    // fused pe+se (pipelined convert GEMM) -> pe planes U0/U1, se f32 out_se + planes U2/U3
    gemm_pese<<<1568, 256, 0, stream>>>(h, WpsH, WpsL, bp, bs, out_se, U0, U1, U2, U3);
    // q = (pe@Wq^T+bq)*scale -> planes U4/U5
    gemm_plane<8,2,1><<<784, 256, 0, stream>>>(U0, U1, WqH, WqL, bq, nullptr,
                                               nullptr, U4, U5, nullptr, nullptr);
    // fused k+v from se planes -> k U0/U1 (pe dead), v U6/U7
    gemm_plane<8,4,6><<<1568, 256, 0, stream>>>(U2, U3, WkvH, WkvL, bk, bv,
                                                nullptr, U0, U1, U6, U7);
    // attention -> ao planes U2/U3 (se planes dead)
    attn_mfma<<<dim3(B_, H_), 256, 0, stream>>>(U4, U5, U0, U1, U6, U7, U2, U3);
    // integ = ao@Wo^T+bo -> f32 @ U4/U5 (q dead)
    gemm_plane<8,2,4><<<784, 256, 0, stream>>>(U2, U3, WoH, WoL, bo, nullptr,
                                               integ, nullptr, nullptr, nullptr, nullptr);
    // fused LN stats + abar partial (one read of h+integ)
    abar_part<<<dim3(B_,4), 256, 0, stream>>>(h, integ, rowm, rowr, Apart);
    // fs (pipelined, bf16 hi, LN folded) -> out_fs
    gemm_fsk<<<784, 256, 0, stream>>>(h, integ, WfsH, bfs, rowm, rowr, wsmb, out_fs);
    // exact f32 pooled via Abar identity
    abar_reduce<<<B_, 256, 0, stream>>>(Apart, Abar, mbar);
    pooled_kernel<<<B_, 256, 0, stream>>>(Abar, mbar, Wfs, wsmb, bfs, pooled);
    // sp from se
    mean_tokens<<<B_, 256, 0, stream>>>(out_se, sp);
    // parent logits + routing
    parent_kernel<<<B_, 256, 0, stream>>>(pooled, Wpc, bpc, out_pl, yhat);
    // routed child classifiers
    child_kernel<<<B_, 64, 0, stream>>>(sp, yhat, Wc0, bc0, Wc1, bc1, out_c0, out_c1);
}

// Round 8
// 678.949 us; speedup vs baseline: 3.3857x; 1.2253x over previous
//
#include <hip/hip_runtime.h>
#include <hip/hip_bf16.h>
#include <math.h>

// Problem dims
#define B_   256
#define N_   196
#define IN_  1024
#define D_   256
#define H_   8
#define HD_  32
#define NC_  1000
#define S0_  10
#define S1_  20
#define ROWS (B_*N_)      // 50176
#define CAT  (IN_+D_)     // 1280

typedef unsigned short ushort_t;
typedef short bf16x8 __attribute__((ext_vector_type(8)));
typedef float f32x4  __attribute__((ext_vector_type(4)));
typedef ushort_t us8 __attribute__((ext_vector_type(8)));

__device__ __forceinline__ ushort_t f2bf(float f){
    __hip_bfloat16 b = __float2bfloat16(f);
    ushort_t u; __builtin_memcpy(&u, &b, 2); return u;
}
__device__ __forceinline__ float gelu_tanh(float x){
    float x3 = x*x*x;
    float inner = 0.7978845608028654f*(x + 0.044715f*x3);
    return 0.5f*x*(1.0f + tanhf(inner));
}

// ---------- async global->LDS, 16B per lane ----------
typedef __attribute__((address_space(1))) const unsigned int gu32;
typedef __attribute__((address_space(3))) unsigned int lu32;
__device__ __forceinline__ void gload_lds16b(const void* g, void* l){
    __builtin_amdgcn_global_load_lds((gu32*)g, (lu32*)l, 16, 0, 0);
}

// stage a 128x32-ushort tile (8KB), linear LDS dest, inverse-swizzled source.
// swizzle: LDS(row, slot') holds global (row, slot' ^ ((row>>1)&3)); slots = 16B units.
__device__ __forceinline__ void stage32(const ushort_t* P, size_t rowbase, int ldk, int k0,
                                        ushort_t* lds, int t){
    const int w = t >> 6, l = t & 63;
    const int rr = l >> 2;                 // row within 16-row segment
    const int sl = (l & 3) ^ ((l >> 3) & 3);
    #pragma unroll
    for (int j=0;j<2;++j){
        int seg = w*2 + j;                 // 8 segments of 1KB (16 rows)
        const ushort_t* src = P + (rowbase + (size_t)(seg*16 + rr))*ldk + k0 + sl*8;
        gload_lds16b(src, lds + seg*512);
    }
}
__device__ __forceinline__ bf16x8 frag32(const ushort_t* lds, int row, int fq){
    return *(const bf16x8*)&lds[row*32 + ((fq ^ ((row >> 1) & 3)) << 3)];
}

// ---------- f32 -> bf16 convert ----------
__global__ __launch_bounds__(256)
void cvt_kernel(const float* __restrict__ src, ushort_t* __restrict__ hi, int n)
{
    int i = blockIdx.x*256 + threadIdx.x;
    if (i < n) hi[i] = f2bf(src[i]);
}

// ---------- colsum(Wfs) ----------
__global__ __launch_bounds__(64)
void wsum_kernel(const float* __restrict__ Wfs, float* __restrict__ wsum)
{
    const int d = blockIdx.x, l = threadIdx.x;
    const float* w = Wfs + (size_t)d*CAT;
    float s = 0.f;
    #pragma unroll
    for (int c0 = 0; c0 < CAT; c0 += 256){
        float4 v = *(const float4*)(w + c0 + l*4);
        s += v.x+v.y+v.z+v.w;
    }
    #pragma unroll
    for (int off=32; off>0; off>>=1) s += __shfl_down(s, off);
    if (l == 0) wsum[d] = s;
}

// ---------- pipelined fused pe+se: A=h f32 (reg prefetch + convert), B=[Wp;Ws] bf16 ----------
// 1D grid 1568, XCD-stripe swizzle; NBN=4
__global__ __launch_bounds__(256)
void gemm_pese(const float* __restrict__ A,
               const ushort_t* __restrict__ BH,
               const float* __restrict__ bias1, const float* __restrict__ bias2,
               float* __restrict__ seF,
               ushort_t* __restrict__ peH, ushort_t* __restrict__ seH)
{
    __shared__ ushort_t S[2][2][128*32];
    const int nwg = gridDim.x, cpx = nwg >> 3, bid = blockIdx.x;
    const int wg = (bid & 7)*cpx + (bid >> 3);
    const int bn = (wg & 3)*128, bm = (wg >> 2)*128;
    const int t = threadIdx.x, lane = t & 63, wid = t >> 6;
    const int wr = wid >> 1, wc = wid & 1, fr = lane & 15, fq = lane >> 4;
    const int row2 = t >> 1, half = t & 1;

    f32x4 acc[4][4];
    #pragma unroll
    for (int i=0;i<4;++i)
        #pragma unroll
        for (int j=0;j<4;++j) acc[i][j] = (f32x4){0.f,0.f,0.f,0.f};

    const float* abase = A + (size_t)(bm + row2)*IN_ + half*16;
    float4 va[4], vb[4];

    auto loadA = [&](float4* v, int kc){
        const float* ap = abase + kc*32;
        v[0] = *(const float4*)(ap);
        v[1] = *(const float4*)(ap + 4);
        v[2] = *(const float4*)(ap + 8);
        v[3] = *(const float4*)(ap + 12);
    };
    auto cvtwrite = [&](int buf, const float4* v){
        float f[16];
        #pragma unroll
        for (int j=0;j<4;++j){ f[j*4]=v[j].x; f[j*4+1]=v[j].y; f[j*4+2]=v[j].z; f[j*4+3]=v[j].w; }
        us8 h0, h1;
        #pragma unroll
        for (int j=0;j<8;++j){ h0[j] = f2bf(f[j]); h1[j] = f2bf(f[8+j]); }
        const int sz = (row2 >> 1) & 3;
        const int s0 = (half*2) ^ sz, s1 = (half*2 + 1) ^ sz;
        *(us8*)&S[buf][0][row2*32 + s0*8] = h0;
        *(us8*)&S[buf][0][row2*32 + s1*8] = h1;
    };
    auto stageB = [&](int buf, int kc){
        stage32(BH, bn, IN_, kc*32, S[buf][1], t);
    };
    auto compute = [&](int buf){
        bf16x8 a[4], b[4];
        #pragma unroll
        for (int i=0;i<4;++i){
            a[i] = frag32(S[buf][0], wr*64 + i*16 + fr, fq);
            b[i] = frag32(S[buf][1], wc*64 + i*16 + fr, fq);
        }
        #pragma unroll
        for (int i=0;i<4;++i)
            #pragma unroll
            for (int j=0;j<4;++j)
                acc[i][j] = __builtin_amdgcn_mfma_f32_16x16x32_bf16(a[i], b[j], acc[i][j], 0,0,0);
    };

    // prologue
    loadA(va, 0); stageB(0, 0); cvtwrite(0, va);
    loadA(va, 1);
    __syncthreads();
    int cur = 0;
    for (int kc = 0; kc < 32; kc += 2){
        if (kc+1 < 32) stageB(cur^1, kc+1);
        if (kc+2 < 32) loadA(vb, kc+2);
        compute(cur);
        if (kc+1 < 32) cvtwrite(cur^1, va);
        __syncthreads();
        cur ^= 1;
        if (kc+2 < 32) stageB(cur^1, kc+2);
        if (kc+3 < 32) loadA(va, kc+3);
        compute(cur);
        if (kc+2 < 32) cvtwrite(cur^1, vb);
        __syncthreads();
        cur ^= 1;
    }
    // epilogue: col<256 -> pe bf16, else se f32+bf16 (gelu both)
    #pragma unroll
    for (int i=0;i<4;++i){
        #pragma unroll
        for (int j=0;j<4;++j){
            const int col = bn + wc*64 + j*16 + fr;
            #pragma unroll
            for (int r=0;r<4;++r){
                const int row = bm + wr*64 + i*16 + fq*4 + r;
                if (col < 256){
                    float x = gelu_tanh(acc[i][j][r] + bias1[col]);
                    peH[(size_t)row*D_ + col] = f2bf(x);
                } else {
                    int c2 = col - 256;
                    float x = gelu_tanh(acc[i][j][r] + bias2[c2]);
                    seF[(size_t)row*D_ + c2] = x;
                    seH[(size_t)row*D_ + c2] = f2bf(x);
                }
            }
        }
    }
}

// ---------- pipelined bf16 plane GEMM ----------
// EPI: 1=q(scale->o1)  6=kv(col<256->o1 else o2)  4=integ(f32o)
template<int KCH, int NBN, int EPI>
__global__ __launch_bounds__(256)
void gemm_plane(const ushort_t* __restrict__ AH,
                const ushort_t* __restrict__ BH,
                const float* __restrict__ bias1, const float* __restrict__ bias2,
                float* __restrict__ f32o,
                ushort_t* __restrict__ o1h, ushort_t* __restrict__ o2h)
{
    __shared__ ushort_t S[2][2][128*32];
    const int nwg = gridDim.x, cpx = nwg >> 3, bid = blockIdx.x;
    const int wg = (bid & 7)*cpx + (bid >> 3);
    const int bn = (wg % NBN)*128, bm = (wg / NBN)*128;
    const int t = threadIdx.x, lane = t & 63, wid = t >> 6;
    const int wr = wid >> 1, wc = wid & 1, fr = lane & 15, fq = lane >> 4;

    f32x4 acc[4][4];
    #pragma unroll
    for (int i=0;i<4;++i)
        #pragma unroll
        for (int j=0;j<4;++j) acc[i][j] = (f32x4){0.f,0.f,0.f,0.f};

    auto stage2 = [&](int buf, int kc){
        stage32(AH, bm, 256, kc*32, S[buf][0], t);
        stage32(BH, bn, 256, kc*32, S[buf][1], t);
    };
    auto compute = [&](int buf){
        bf16x8 a[4], b[4];
        #pragma unroll
        for (int i=0;i<4;++i){
            a[i] = frag32(S[buf][0], wr*64 + i*16 + fr, fq);
            b[i] = frag32(S[buf][1], wc*64 + i*16 + fr, fq);
        }
        #pragma unroll
        for (int i=0;i<4;++i)
            #pragma unroll
            for (int j=0;j<4;++j)
                acc[i][j] = __builtin_amdgcn_mfma_f32_16x16x32_bf16(a[i], b[j], acc[i][j], 0,0,0);
    };

    stage2(0, 0);
    __syncthreads();
    int cur = 0;
    #pragma unroll 2
    for (int kc = 0; kc < KCH; ++kc){
        if (kc+1 < KCH) stage2(cur^1, kc+1);
        compute(cur);
        __syncthreads();
        cur ^= 1;
    }
    #pragma unroll
    for (int i=0;i<4;++i){
        #pragma unroll
        for (int j=0;j<4;++j){
            const int col = bn + wc*64 + j*16 + fr;
            #pragma unroll
            for (int r=0;r<4;++r){
                const int row = bm + wr*64 + i*16 + fq*4 + r;
                if (EPI == 1){
                    float x = (acc[i][j][r] + bias1[col]) * 0.17677669529663687f;
                    o1h[(size_t)row*D_ + col] = f2bf(x);
                } else if (EPI == 6){
                    if (col < 256){
                        o1h[(size_t)row*D_ + col] = f2bf(acc[i][j][r] + bias1[col]);
                    } else {
                        o2h[(size_t)row*D_ + (col-256)] = f2bf(acc[i][j][r] + bias2[col-256]);
                    }
                } else { // EPI == 4
                    f32o[(size_t)row*D_ + col] = acc[i][j][r] + bias1[col];
                }
            }
        }
    }
}

// ---------- pipelined fs GEMM: A=[h|integ] f32 -> bf16, B=WfsH, LN folded ----------
__global__ __launch_bounds__(256)
void gemm_fsk(const float* __restrict__ A1, const float* __restrict__ A2,
              const ushort_t* __restrict__ BH, const float* __restrict__ bias,
              const float* __restrict__ rowm, const float* __restrict__ rowr,
              const float* __restrict__ wsump, float* __restrict__ C)
{
    __shared__ ushort_t S[2][2][128*32];
    const int nwg = gridDim.x, cpx = nwg >> 3, bid = blockIdx.x;
    const int wg = (bid & 7)*cpx + (bid >> 3);
    const int bn = (wg & 1)*128, bm = (wg >> 1)*128;
    const int t = threadIdx.x, lane = t & 63, wid = t >> 6;
    const int wr = wid >> 1, wc = wid & 1, fr = lane & 15, fq = lane >> 4;
    const int row2 = t >> 1, half = t & 1;

    f32x4 acc[4][4];
    #pragma unroll
    for (int i=0;i<4;++i)
        #pragma unroll
        for (int j=0;j<4;++j) acc[i][j] = (f32x4){0.f,0.f,0.f,0.f};

    float4 va[4], vb[4];
    auto loadA = [&](float4* v, int kc){
        const float* ap = (kc < 32) ? A1 + (size_t)(bm + row2)*IN_ + kc*32 + half*16
                                    : A2 + (size_t)(bm + row2)*D_ + (kc-32)*32 + half*16;
        v[0] = *(const float4*)(ap);
        v[1] = *(const float4*)(ap + 4);
        v[2] = *(const float4*)(ap + 8);
        v[3] = *(const float4*)(ap + 12);
    };
    auto cvtwrite = [&](int buf, const float4* v){
        float f[16];
        #pragma unroll
        for (int j=0;j<4;++j){ f[j*4]=v[j].x; f[j*4+1]=v[j].y; f[j*4+2]=v[j].z; f[j*4+3]=v[j].w; }
        us8 h0, h1;
        #pragma unroll
        for (int j=0;j<8;++j){ h0[j] = f2bf(f[j]); h1[j] = f2bf(f[8+j]); }
        const int sz = (row2 >> 1) & 3;
        const int s0 = (half*2) ^ sz, s1 = (half*2 + 1) ^ sz;
        *(us8*)&S[buf][0][row2*32 + s0*8] = h0;
        *(us8*)&S[buf][0][row2*32 + s1*8] = h1;
    };
    auto stageB = [&](int buf, int kc){
        stage32(BH, bn, CAT, kc*32, S[buf][1], t);
    };
    auto compute = [&](int buf){
        bf16x8 a[4], b[4];
        #pragma unroll
        for (int i=0;i<4;++i){
            a[i] = frag32(S[buf][0], wr*64 + i*16 + fr, fq);
            b[i] = frag32(S[buf][1], wc*64 + i*16 + fr, fq);
        }
        #pragma unroll
        for (int i=0;i<4;++i)
            #pragma unroll
            for (int j=0;j<4;++j)
                acc[i][j] = __builtin_amdgcn_mfma_f32_16x16x32_bf16(a[i], b[j], acc[i][j], 0,0,0);
    };

    loadA(va, 0); stageB(0, 0); cvtwrite(0, va);
    loadA(va, 1);
    __syncthreads();
    int cur = 0;
    for (int kc = 0; kc < 40; kc += 2){
        if (kc+1 < 40) stageB(cur^1, kc+1);
        if (kc+2 < 40) loadA(vb, kc+2);
        compute(cur);
        if (kc+1 < 40) cvtwrite(cur^1, va);
        __syncthreads();
        cur ^= 1;
        if (kc+2 < 40) stageB(cur^1, kc+2);
        if (kc+3 < 40) loadA(va, kc+3);
        compute(cur);
        if (kc+2 < 40) cvtwrite(cur^1, vb);
        __syncthreads();
        cur ^= 1;
    }
    #pragma unroll
    for (int i=0;i<4;++i){
        #pragma unroll
        for (int j=0;j<4;++j){
            const int col = bn + wc*64 + j*16 + fr;
            float ws_ = wsump[col], bb = bias[col];
            #pragma unroll
            for (int r=0;r<4;++r){
                const int row = bm + wr*64 + i*16 + fq*4 + r;
                C[(size_t)row*D_ + col] = rowr[row]*(acc[i][j][r] - rowm[row]*ws_) + bb;
            }
        }
    }
}

// ---------- MFMA attention (bf16 in, bf16 out) ----------
#define KROWS 208
#define KLD   40
#define VLD   232

__global__ __launch_bounds__(256)
void attn_mfma(const ushort_t* __restrict__ qhi,
               const ushort_t* __restrict__ khi,
               const ushort_t* __restrict__ vhi,
               ushort_t* __restrict__ aohi)
{
    __shared__ ushort_t Khi[KROWS*KLD];
    __shared__ ushort_t Vthi[32*VLD];

    const int b = blockIdx.x, hh = blockIdx.y;
    const int t = threadIdx.x;
    const int lane = t & 63;
    const int wid  = t >> 6;
    const int fr = lane & 15;
    const int fq = lane >> 4;
    const size_t bbase = (size_t)b*N_*D_ + hh*HD_;

    for (int idx = t; idx < KROWS*4; idx += 256){
        int row = idx >> 2, c8 = (idx & 3) << 3;
        us8 vh;
        if (row < N_){
            vh = *(const us8*)(khi + bbase + (size_t)row*D_ + c8);
        } else {
            #pragma unroll
            for (int j=0;j<8;++j) vh[j]=0;
        }
        *(us8*)&Khi[row*KLD + c8] = vh;
    }
    for (int idx = t; idx < 224*4; idx += 256){
        int key = idx >> 2, c8 = (idx & 3) << 3;
        us8 vh;
        if (key < N_){
            vh = *(const us8*)(vhi + bbase + (size_t)key*D_ + c8);
        } else {
            #pragma unroll
            for (int j=0;j<8;++j) vh[j]=0;
        }
        int w = key & 31, cc = key >> 5;
        int slot;
        if (w < 16) slot = cc*32 + (w>>2)*8 + (w&3);
        else { int w2 = w-16; slot = cc*32 + (w2>>2)*8 + 4 + (w2&3); }
        #pragma unroll
        for (int j=0;j<8;++j)
            Vthi[(c8 + j)*VLD + slot] = vh[j];
    }
    __syncthreads();

    for (int qt = wid; qt < 13; qt += 4){
        int qrow = qt*16 + fr; if (qrow > N_-1) qrow = N_-1;
        const bf16x8 qh = *(const bf16x8*)(qhi + bbase + (size_t)qrow*D_ + fq*8);

        f32x4 s[13];
        #pragma unroll
        for (int kt=0; kt<13; ++kt) s[kt] = (f32x4){0.f,0.f,0.f,0.f};
        #pragma unroll
        for (int kt=0; kt<13; ++kt){
            const bf16x8 kh = *(const bf16x8*)&Khi[(kt*16 + fr)*KLD + fq*8];
            s[kt] = __builtin_amdgcn_mfma_f32_16x16x32_bf16(kh, qh, s[kt], 0,0,0);
        }
        if (fq > 0) s[12] = (f32x4){-1e30f,-1e30f,-1e30f,-1e30f};

        float m = -3.4e38f;
        #pragma unroll
        for (int kt=0; kt<13; ++kt)
            #pragma unroll
            for (int r=0;r<4;++r) m = fmaxf(m, s[kt][r]);
        m = fmaxf(m, __shfl_xor(m, 16));
        m = fmaxf(m, __shfl_xor(m, 32));
        float sum = 0.f;
        #pragma unroll
        for (int kt=0; kt<13; ++kt)
            #pragma unroll
            for (int r=0;r<4;++r){
                float p = __expf(s[kt][r] - m);
                s[kt][r] = p; sum += p;
            }
        sum += __shfl_xor(sum, 16);
        sum += __shfl_xor(sum, 32);
        const float inv = 1.0f / sum;

        f32x4 o0 = (f32x4){0.f,0.f,0.f,0.f};
        f32x4 o1 = (f32x4){0.f,0.f,0.f,0.f};
        #pragma unroll
        for (int c=0;c<7;++c){
            bf16x8 ph;
            #pragma unroll
            for (int r=0;r<4;++r){
                ph[r]   = (short)f2bf(s[2*c][r]);
                ph[4+r] = (short)((c < 6) ? f2bf(s[2*c+1][r]) : 0);
            }
            const int coff = c*32 + fq*8;
            const bf16x8 v0h = *(const bf16x8*)&Vthi[(fr)*VLD + coff];
            const bf16x8 v1h = *(const bf16x8*)&Vthi[(16+fr)*VLD + coff];
            o0 = __builtin_amdgcn_mfma_f32_16x16x32_bf16(v0h, ph, o0, 0,0,0);
            o1 = __builtin_amdgcn_mfma_f32_16x16x32_bf16(v1h, ph, o1, 0,0,0);
        }
        int tok = qt*16 + fr;
        if (tok < N_){
            const size_t obase = bbase + (size_t)tok*D_;
            #pragma unroll
            for (int r=0;r<4;++r){
                aohi[obase + fq*4 + r]      = f2bf(o0[r]*inv);
                aohi[obase + 16 + fq*4 + r] = f2bf(o1[r]*inv);
            }
        }
    }
}

// ---------- fused rowstats + abar partial: one read of h+integ ----------
#define APLD 1344
__global__ __launch_bounds__(256)
void abar_part(const float* __restrict__ h, const float* __restrict__ integ,
               float* __restrict__ rowm, float* __restrict__ rowr,
               float* __restrict__ Apart)
{
    const int b = blockIdx.x, qq = blockIdx.y, t = threadIdx.x;
    const int lane = t & 63, w = t >> 6;
    const int n0 = qq*49;
    __shared__ float ss[4], ss2[4];
    float acc[5] = {0.f,0.f,0.f,0.f,0.f};
    float mracc = 0.f;
    for (int n=0; n<49; ++n){
        const int row = b*N_ + n0 + n;
        float e[5];
        const float* hr = h + (size_t)row*IN_;
        #pragma unroll
        for (int j=0;j<4;++j) e[j] = hr[t + j*256];
        e[4] = integ[(size_t)row*D_ + t];
        float s  = e[0]+e[1]+e[2]+e[3]+e[4];
        float s2 = e[0]*e[0]+e[1]*e[1]+e[2]*e[2]+e[3]*e[3]+e[4]*e[4];
        #pragma unroll
        for (int off=32; off>0; off>>=1){ s += __shfl_down(s,off); s2 += __shfl_down(s2,off); }
        if (lane == 0){ ss[w] = s; ss2[w] = s2; }
        __syncthreads();
        float S1 = ss[0]+ss[1]+ss[2]+ss[3];
        float S2 = ss2[0]+ss2[1]+ss2[2]+ss2[3];
        float m  = S1 * (1.0f/CAT);
        float rr = rsqrtf(S2 * (1.0f/CAT) - m*m + 1e-5f);
        if (t == 0){ rowm[row] = m; rowr[row] = rr; }
        #pragma unroll
        for (int j=0;j<5;++j) acc[j] += rr*e[j];
        mracc += rr*m;
        __syncthreads();
    }
    float* ap = Apart + ((size_t)b*4 + qq)*APLD;
    #pragma unroll
    for (int j=0;j<4;++j) ap[t + j*256] = acc[j];
    ap[IN_ + t] = acc[4];
    if (t == 0) ap[1280] = mracc;
}

__global__ __launch_bounds__(256)
void abar_reduce(const float* __restrict__ Apart, float* __restrict__ Abar,
                 float* __restrict__ mbar)
{
    const int b = blockIdx.x, t = threadIdx.x;
    const float* ap = Apart + (size_t)b*4*APLD;
    for (int c = t; c < 1281; c += 256){
        float s = ap[c] + ap[APLD + c] + ap[2*APLD + c] + ap[3*APLD + c];
        if (c < 1280) Abar[(size_t)b*CAT + c] = s * (1.f/N_);
        else mbar[b] = s * (1.f/N_);
    }
}

// ---------- pooled[b,d] = Abar[b]·Wfs[d] - mbar[b]*wsum[d] + bfs[d]  (f32 exact) ----------
__global__ __launch_bounds__(256)
void pooled_kernel(const float* __restrict__ Abar, const float* __restrict__ mbar,
                   const float* __restrict__ Wfs, const float* __restrict__ wsum,
                   const float* __restrict__ bfs, float* __restrict__ pooled)
{
    const int b = blockIdx.x, d = threadIdx.x;
    __shared__ float ab[CAT];
    for (int c=d;c<CAT;c+=256) ab[c] = Abar[(size_t)b*CAT + c];
    __syncthreads();
    const float* w = Wfs + (size_t)d*CAT;
    float s = 0.f;
    for (int c=0;c<CAT;c+=4){
        float4 wv = *(const float4*)(w+c);
        s += ab[c]*wv.x + ab[c+1]*wv.y + ab[c+2]*wv.z + ab[c+3]*wv.w;
    }
    pooled[b*D_ + d] = s - mbar[b]*wsum[d] + bfs[d];
}

// ---------- mean over tokens ----------
__global__ __launch_bounds__(256)
void mean_tokens(const float* __restrict__ src, float* __restrict__ dst)
{
    int b = blockIdx.x, d = threadIdx.x;
    const float* p = src + (size_t)b*N_*D_ + d;
    float s = 0.f;
    for (int n=0;n<N_;++n) s += p[(size_t)n*D_];
    dst[b*D_ + d] = s * (1.0f/N_);
}

// ---------- parent logits + routing ----------
__global__ __launch_bounds__(256)
void parent_kernel(const float* __restrict__ pooled, const float* __restrict__ Wpc,
                   const float* __restrict__ bpc, float* __restrict__ out, int* __restrict__ yhat)
{
    const int b = blockIdx.x, t = threadIdx.x;
    __shared__ __align__(16) float pl[D_];
    __shared__ float lg[NC_];
    pl[t] = pooled[b*D_ + t];
    __syncthreads();
    for (int c = t; c < NC_; c += 256){
        const float4* w4 = (const float4*)(Wpc + (size_t)c*D_);
        float s = 0.f;
        #pragma unroll 16
        for (int j=0;j<64;++j){
            float4 wv = w4[j];
            s += pl[j*4]*wv.x + pl[j*4+1]*wv.y + pl[j*4+2]*wv.z + pl[j*4+3]*wv.w;
        }
        lg[c] = s + bpc[c];
    }
    __syncthreads();
    float s=0.f, s2=0.f, bmv=-3.4e38f; int bidx=0;
    for (int c=t;c<NC_;c+=256){
        float x = lg[c]; s += x; s2 += x*x;
        if (x > bmv){ bmv=x; bidx=c; }
    }
    #pragma unroll
    for (int off=32; off>0; off>>=1){
        s  += __shfl_down(s, off);
        s2 += __shfl_down(s2, off);
        float ov = __shfl_down(bmv, off); int oi = __shfl_down(bidx, off);
        if (ov > bmv || (ov == bmv && oi < bidx)){ bmv=ov; bidx=oi; }
    }
    __shared__ float rs[4], rs2[4], rmv[4]; __shared__ int ri[4];
    __shared__ float fm, fr_;
    int w = t >> 6;
    if ((t & 63) == 0){ rs[w]=s; rs2[w]=s2; rmv[w]=bmv; ri[w]=bidx; }
    __syncthreads();
    if (t == 0){
        float S=0.f, S2=0.f, mv=-3.4e38f; int mi=0;
        for (int i=0;i<4;++i){
            S += rs[i]; S2 += rs2[i];
            if (rmv[i] > mv || (rmv[i] == mv && ri[i] < mi)){ mv=rmv[i]; mi=ri[i]; }
        }
        float mean = S*(1.0f/NC_);
        float var  = S2*(1.0f/NC_) - mean*mean;
        fm = mean; fr_ = rsqrtf(var + 1e-5f);
        yhat[b] = mi;
    }
    __syncthreads();
    for (int c=t;c<NC_;c+=256) out[(size_t)b*NC_ + c] = (lg[c]-fm)*fr_;
}

// ---------- routed child classifiers ----------
__global__ __launch_bounds__(64)
void child_kernel(const float* __restrict__ sp, const int* __restrict__ yhat,
                  const float* __restrict__ Wc0, const float* __restrict__ bc0,
                  const float* __restrict__ Wc1, const float* __restrict__ bc1,
                  float* __restrict__ out_c0, float* __restrict__ out_c1)
{
    const int b = blockIdx.x, t = threadIdx.x;
    __shared__ float spl[D_];
    for (int i=t;i<D_;i+=64) spl[i] = sp[b*D_ + i];
    __syncthreads();
    const int y = yhat[b];
    __shared__ float c0v[S0_], c1v[S1_];
    if (t < S0_){
        const float* w = Wc0 + (size_t)y*D_*S0_ + t;
        float s = 0.f;
        for (int d=0;d<D_;++d) s += spl[d]*w[(size_t)d*S0_];
        c0v[t] = s + bc0[y*S0_ + t];
    } else if (t < S0_+S1_){
        int k = t - S0_;
        const float* w = Wc1 + (size_t)y*D_*S1_ + k;
        float s = 0.f;
        for (int d=0;d<D_;++d) s += spl[d]*w[(size_t)d*S1_];
        c1v[k] = s + bc1[y*S1_ + k];
    }
    __syncthreads();
    __shared__ float st[4];
    if (t == 0){
        float m=0.f; for (int i=0;i<S0_;++i) m += c0v[i]; m *= (1.0f/S0_);
        float v=0.f; for (int i=0;i<S0_;++i){ float d=c0v[i]-m; v += d*d; } v *= (1.0f/S0_);
        st[0]=m; st[1]=rsqrtf(v+1e-5f);
        m=0.f; for (int i=0;i<S1_;++i) m += c1v[i]; m *= (1.0f/S1_);
        v=0.f; for (int i=0;i<S1_;++i){ float d=c1v[i]-m; v += d*d; } v *= (1.0f/S1_);
        st[2]=m; st[3]=rsqrtf(v+1e-5f);
    }
    __syncthreads();
    if (t < S0_) out_c0[b*S0_ + t] = (c0v[t]-st[0])*st[1];
    else if (t < S0_+S1_) out_c1[b*S1_ + (t-S0_)] = (c1v[t-S0_]-st[2])*st[3];
}

extern "C" void kernel_launch(void* const* d_in, const int* in_sizes, int n_in,
                              void* d_out, int out_size, void* d_ws, size_t ws_size,
                              hipStream_t stream)
{
    const float* h   = (const float*)d_in[0];
    const float* Wp  = (const float*)d_in[1];
    const float* bp  = (const float*)d_in[2];
    const float* Wsub= (const float*)d_in[3];
    const float* bs  = (const float*)d_in[4];
    const float* Wq  = (const float*)d_in[5];
    const float* bq  = (const float*)d_in[6];
    const float* Wk  = (const float*)d_in[7];
    const float* bk  = (const float*)d_in[8];
    const float* Wv  = (const float*)d_in[9];
    const float* bv  = (const float*)d_in[10];
    const float* Wo  = (const float*)d_in[11];
    const float* bo  = (const float*)d_in[12];
    const float* Wfs = (const float*)d_in[13];
    const float* bfs = (const float*)d_in[14];
    const float* Wpc = (const float*)d_in[15];
    const float* bpc = (const float*)d_in[16];
    const float* Wc0 = (const float*)d_in[17];
    const float* bc0 = (const float*)d_in[18];
    const float* Wc1 = (const float*)d_in[19];
    const float* bc1 = (const float*)d_in[20];

    float* out = (float*)d_out;
    float* out_pl = out;                         // [256,1000]
    float* out_c0 = out + 256000;                // [256,10]
    float* out_c1 = out + 258560;                // [256,20]
    float* out_fs = out + 263680;                // [256,196,256]
    float* out_se = out + 13108736;              // [256,196,256]

    // ---- workspace ----
    ushort_t* U = (ushort_t*)d_ws;
    const size_t UN = (size_t)ROWS * D_;         // 12,845,056
    ushort_t* U0 = U + 0*UN;   // pe bf16
    ushort_t* U1 = U + 1*UN;   // se bf16
    ushort_t* U2 = U + 2*UN;   // q bf16
    ushort_t* U3 = U + 3*UN;   // k bf16
    ushort_t* U4 = U + 4*UN;   // v bf16
    ushort_t* U5 = U + 5*UN;   // ao bf16
    float* integ = (float*)(U + 6*UN);           // f32, spans 2 UN

    float* fmisc = (float*)(U + 8*UN);
    float* rowm = fmisc;                          // 50176
    float* rowr = rowm + ROWS;                    // 50176
    float* wsmb = rowr + ROWS;                    // 256
    float* pooled = wsmb + D_;                    // 65536
    float* sp   = pooled + (size_t)B_*D_;         // 65536
    float* mbar = sp + (size_t)B_*D_;             // 256
    float* Abar = mbar + 256;                     // 327680
    float* Apart = Abar + (size_t)B_*CAT;         // 256*4*1344
    int*   yhat = (int*)(Apart + (size_t)B_*4*APLD);
    ushort_t* wp = (ushort_t*)(yhat + 512);
    ushort_t* WpsH = wp;               // [512][1024]
    ushort_t* WqH  = WpsH + 524288;
    ushort_t* WkvH = WqH + 65536;      // [512][256]
    ushort_t* WoH  = WkvH + 131072;
    ushort_t* WfsH = WoH + 65536;      // [256][1280]

    // convert weights to bf16 (stacked where fused)
    cvt_kernel<<<1024, 256, 0, stream>>>(Wp,   WpsH,          262144);
    cvt_kernel<<<1024, 256, 0, stream>>>(Wsub, WpsH + 262144, 262144);
    cvt_kernel<<<256,  256, 0, stream>>>(Wq,   WqH,  65536);
    cvt_kernel<<<256,  256, 0, stream>>>(Wk,   WkvH,          65536);
    cvt_kernel<<<256,  256, 0, stream>>>(Wv,   WkvH + 65536,  65536);
    cvt_kernel<<<256,  256, 0, stream>>>(Wo,   WoH,  65536);
    cvt_kernel<<<1280, 256, 0, stream>>>(Wfs,  WfsH, 327680);
    wsum_kernel<<<256, 64, 0, stream>>>(Wfs, wsmb);

    // fused pe+se -> pe U0, se f32 out_se + bf16 U1
    gemm_pese<<<1568, 256, 0, stream>>>(h, WpsH, bp, bs, out_se, U0, U1);
    // q = (pe@Wq^T+bq)*scale -> U2
    gemm_plane<8,2,1><<<784, 256, 0, stream>>>(U0, WqH, bq, nullptr,
                                               nullptr, U2, nullptr);
    // fused k+v from se -> k U3, v U4
    gemm_plane<8,4,6><<<1568, 256, 0, stream>>>(U1, WkvH, bk, bv,
                                                nullptr, U3, U4);
    // attention -> ao U5
    attn_mfma<<<dim3(B_, H_), 256, 0, stream>>>(U2, U3, U4, U5);
    // integ = ao@Wo^T+bo -> f32
    gemm_plane<8,2,4><<<784, 256, 0, stream>>>(U5, WoH, bo, nullptr,
                                               integ, nullptr, nullptr);
    // fused LN stats + abar partial (one read of h+integ)
    abar_part<<<dim3(B_,4), 256, 0, stream>>>(h, integ, rowm, rowr, Apart);
    // fs (pipelined, bf16, LN folded) -> out_fs
    gemm_fsk<<<784, 256, 0, stream>>>(h, integ, WfsH, bfs, rowm, rowr, wsmb, out_fs);
    // exact f32 pooled via Abar identity
    abar_reduce<<<B_, 256, 0, stream>>>(Apart, Abar, mbar);
    pooled_kernel<<<B_, 256, 0, stream>>>(Abar, mbar, Wfs, wsmb, bfs, pooled);
    // sp from se
    mean_tokens<<<B_, 256, 0, stream>>>(out_se, sp);
    // parent logits + routing
    parent_kernel<<<B_, 256, 0, stream>>>(pooled, Wpc, bpc, out_pl, yhat);
    // routed child classifiers
    child_kernel<<<B_, 64, 0, stream>>>(sp, yhat, Wc0, bc0, Wc1, bc1, out_c0, out_c1);
}